// Round 4
// baseline (294.072 us; speedup 1.0000x reference)
//
#include <hip/hip_runtime.h>
#include <math.h>

#define CIN   32
#define COUT  64
#define DD    20
#define PD    22        // padded dim
#define PSP   (PD*PD*PD)   // 10648
#define NSP   8000      // 20*20*20
#define BB    2
#define EPSN  1e-5f
#define SLOPE 0.01f

#define SPLITS 10
#define KPS    (NSP / SPLITS)   // 800
#define NKT    (KPS / 32)       // 25 k-tiles of 32
#define QPB    125              // q-tile pairs per batch (2 waves/block, 32 q-rows each)

#define COG 8                   // conv: output channels per thread
#define OG  8                   // qkv: output channels per thread

typedef float  f32x16 __attribute__((ext_vector_type(16)));
typedef short  short8 __attribute__((ext_vector_type(8)));

__device__ __forceinline__ unsigned short f2bf_rne(float x) {
    unsigned u = __float_as_uint(x);
    unsigned r = (u + 0x7FFFu + ((u >> 16) & 1u)) >> 16;
    return (unsigned short)r;
}
__device__ __forceinline__ float bf2f(unsigned short h) {
    return __uint_as_float(((unsigned)h) << 16);
}
__device__ __forceinline__ short8 ld_frag(const unsigned short* p) {
    uint4 t = *reinterpret_cast<const uint4*>(p);
    return __builtin_bit_cast(short8, t);
}

// ---------------- zero-pad x into [B][CIN][22][22][22] ----------------
__global__ void pad_k(const float* __restrict__ x, float* __restrict__ xp) {
    int idx = blockIdx.x * blockDim.x + threadIdx.x;
    if (idx >= BB * CIN * PSP) return;
    int pw = idx % PD;
    int ph = (idx / PD) % PD;
    int pd = (idx / (PD * PD)) % PD;
    int bc = idx / PSP;
    float v = 0.f;
    if (pw >= 1 && pw <= DD && ph >= 1 && ph <= DD && pd >= 1 && pd <= DD)
        v = x[(size_t)bc * NSP + ((size_t)(pd - 1) * DD + (ph - 1)) * DD + (pw - 1)];
    xp[idx] = v;
}

// ---------------- Conv3d k=3 s=1 SAME + bias (padded input, reg-blocked) ----------------
__global__ __launch_bounds__(256) void conv3d_k(const float* __restrict__ xp,
                                                const float* __restrict__ w,
                                                const float* __restrict__ bias,
                                                float* __restrict__ y) {
    int blk = blockIdx.x;
    int vb  = blk & 31;
    int cg  = (blk >> 5) & 7;       // uniform co-group
    int b   = blk >> 8;
    int vox = vb * 256 + threadIdx.x;
    bool valid = vox < NSP;
    int v  = valid ? vox : 0;
    int w_ = v % DD;
    int h_ = (v / DD) % DD;
    int d_ = v / (DD * DD);
    int pvox = ((d_ + 1) * PD + (h_ + 1)) * PD + (w_ + 1);
    const float* xb = xp + (size_t)b * CIN * PSP + pvox;

    float acc[COG];
    #pragma unroll
    for (int j = 0; j < COG; ++j) acc[j] = 0.f;

    for (int ci = 0; ci < CIN; ++ci) {
        const float* xc = xb + (size_t)ci * PSP;
        float xv[27];
        #pragma unroll
        for (int kd = 0; kd < 3; ++kd)
            #pragma unroll
            for (int kh = 0; kh < 3; ++kh)
                #pragma unroll
                for (int kw = 0; kw < 3; ++kw)
                    xv[(kd * 3 + kh) * 3 + kw] =
                        xc[(kd - 1) * (PD * PD) + (kh - 1) * PD + (kw - 1)];
        #pragma unroll
        for (int j = 0; j < COG; ++j) {
            int co = cg * COG + j;                       // uniform
            const float* wr = w + ((size_t)co * CIN + ci) * 27;
            float a = acc[j];
            #pragma unroll
            for (int t = 0; t < 27; ++t) a += xv[t] * wr[t];
            acc[j] = a;
        }
    }
    if (valid) {
        #pragma unroll
        for (int j = 0; j < COG; ++j) {
            int co = cg * COG + j;
            y[((size_t)b * COUT + co) * NSP + vox] = acc[j] + bias[co];
        }
    }
}

// ---------------- InstanceNorm stats: one block per (b,c) ----------------
__global__ void instnorm_stats_k(const float* __restrict__ y, float* __restrict__ stats) {
    int bc = blockIdx.x;                 // 0..127
    const float* yb = y + (size_t)bc * NSP;
    float s = 0.f, ss = 0.f;
    for (int i = threadIdx.x; i < NSP; i += blockDim.x) {
        float v = yb[i];
        s += v; ss += v * v;
    }
    __shared__ float rs[256], rss[256];
    rs[threadIdx.x] = s; rss[threadIdx.x] = ss;
    __syncthreads();
    for (int off = 128; off > 0; off >>= 1) {
        if (threadIdx.x < off) {
            rs[threadIdx.x]  += rs[threadIdx.x + off];
            rss[threadIdx.x] += rss[threadIdx.x + off];
        }
        __syncthreads();
    }
    if (threadIdx.x == 0) {
        float mean = rs[0] / (float)NSP;
        float var  = rss[0] / (float)NSP - mean * mean;
        stats[bc * 2 + 0] = mean;
        stats[bc * 2 + 1] = rsqrtf(var + EPSN);
    }
}

// ---------------- normalize + affine + LeakyReLU (in place) ----------------
__global__ void norm_lrelu_k(float* __restrict__ y, const float* __restrict__ stats,
                             const float* __restrict__ gamma, const float* __restrict__ beta) {
    int idx = blockIdx.x * blockDim.x + threadIdx.x;
    if (idx >= BB * COUT * NSP) return;
    int bc = idx / NSP;
    int c  = bc % COUT;
    float mean = stats[bc * 2 + 0];
    float rstd = stats[bc * 2 + 1];
    float v = (y[idx] - mean) * rstd * gamma[c] + beta[c];
    y[idx] = v >= 0.f ? v : SLOPE * v;
}

// ---------------- QKV projections -> bf16 hi/lo operand layouts (reg-blocked) ----------------
__global__ __launch_bounds__(256) void qkv_k(const float* __restrict__ f,
                      const float* __restrict__ wq, const float* __restrict__ bq,
                      const float* __restrict__ wk, const float* __restrict__ bk,
                      const float* __restrict__ wv, const float* __restrict__ bv,
                      unsigned short* __restrict__ Qhi, unsigned short* __restrict__ Qlo,
                      unsigned short* __restrict__ Khi, unsigned short* __restrict__ Klo,
                      unsigned short* __restrict__ Vb) {
    int blk = blockIdx.x;
    int vb  = blk & 31;
    int og  = (blk >> 5) & 7;       // uniform o-group
    int b   = blk >> 8;
    int n   = vb * 256 + threadIdx.x;
    bool valid = n < NSP;
    int nn  = valid ? n : 0;
    const float* fb = f + (size_t)b * COUT * NSP + nn;

    float aq[OG], ak[OG], av[OG];
    #pragma unroll
    for (int j = 0; j < OG; ++j) {
        int o = og * OG + j;
        aq[j] = bq[o]; ak[j] = bk[o]; av[j] = bv[o];
    }
    for (int c = 0; c < COUT; ++c) {
        float fc = fb[(size_t)c * NSP];
        #pragma unroll
        for (int j = 0; j < OG; ++j) {
            int o = og * OG + j;                         // uniform
            aq[j] += wq[o * COUT + c] * fc;
            ak[j] += wk[o * COUT + c] * fc;
            av[j] += wv[o * COUT + c] * fc;
        }
    }
    if (!valid) return;

    unsigned short qh[OG], ql[OG], kh[OG], kl[OG];
    #pragma unroll
    for (int j = 0; j < OG; ++j) {
        qh[j] = f2bf_rne(aq[j]); ql[j] = f2bf_rne(aq[j] - bf2f(qh[j]));
        kh[j] = f2bf_rne(ak[j]); kl[j] = f2bf_rne(ak[j] - bf2f(kh[j]));
    }
    size_t tq = ((size_t)(b * NSP + n)) * COUT + og * OG;
    *reinterpret_cast<uint4*>(Qhi + tq) = *reinterpret_cast<const uint4*>(qh);
    *reinterpret_cast<uint4*>(Qlo + tq) = *reinterpret_cast<const uint4*>(ql);
    *reinterpret_cast<uint4*>(Khi + tq) = *reinterpret_cast<const uint4*>(kh);
    *reinterpret_cast<uint4*>(Klo + tq) = *reinterpret_cast<const uint4*>(kl);
    #pragma unroll
    for (int j = 0; j < OG; ++j) {
        int o = og * OG + j;
        Vb[(size_t)(b * COUT + o) * NSP + n] = f2bf_rne(av[j]);
    }
}

// ---------------- flash attention pass 1: MFMA, split-K, online softmax ----------------
// split-major grid ordering: co-resident blocks share a narrow K/V window (L2 locality)
__global__ __launch_bounds__(128) void attn_pass1_mfma(
        const unsigned short* __restrict__ Qhi, const unsigned short* __restrict__ Qlo,
        const unsigned short* __restrict__ Khi, const unsigned short* __restrict__ Klo,
        const unsigned short* __restrict__ Vb,
        float* __restrict__ pm, float* __restrict__ pl, float* __restrict__ pacc) {
    int bid   = blockIdx.x;
    int split = bid / (BB * QPB);
    int rem   = bid % (BB * QPB);
    int b     = rem / QPB;
    int qpair = rem % QPB;
    int wave  = threadIdx.x >> 6;
    int lane  = threadIdx.x & 63;
    int col   = lane & 31;
    int half  = lane >> 5;
    int q0    = (qpair * 2 + wave) * 32;
    int n0base = split * KPS;

    short8 qfh[4], qfl[4];
    {
        const unsigned short* qp  = Qhi + ((size_t)(b * NSP + q0 + col)) * COUT + half * 8;
        const unsigned short* qp2 = Qlo + ((size_t)(b * NSP + q0 + col)) * COUT + half * 8;
        #pragma unroll
        for (int c = 0; c < 4; ++c) {
            qfh[c] = ld_frag(qp  + c * 16);
            qfl[c] = ld_frag(qp2 + c * 16);
        }
    }

    f32x16 oacc0 = {};
    f32x16 oacc1 = {};
    float m = -3e38f, lsum = 0.f;

    for (int t = 0; t < NKT; ++t) {
        int n0 = n0base + t * 32;
        const unsigned short* kp  = Khi + ((size_t)(b * NSP + n0 + col)) * COUT + half * 8;
        const unsigned short* kp2 = Klo + ((size_t)(b * NSP + n0 + col)) * COUT + half * 8;
        // dual accumulators: break the 12-deep dependent MFMA chain into 8 + 4
        f32x16 sA = {};
        f32x16 sB = {};
        #pragma unroll
        for (int c = 0; c < 4; ++c) {
            short8 kfh = ld_frag(kp  + c * 16);
            short8 kfl = ld_frag(kp2 + c * 16);
            sA = __builtin_amdgcn_mfma_f32_32x32x16_bf16(kfh, qfh[c], sA, 0, 0, 0);
            sA = __builtin_amdgcn_mfma_f32_32x32x16_bf16(kfh, qfl[c], sA, 0, 0, 0);
            sB = __builtin_amdgcn_mfma_f32_32x32x16_bf16(kfl, qfh[c], sB, 0, 0, 0);
        }
        float s[16];
        #pragma unroll
        for (int r = 0; r < 16; ++r) s[r] = sA[r] + sB[r];

        float tmax = s[0];
        #pragma unroll
        for (int r = 1; r < 16; ++r) tmax = fmaxf(tmax, s[r]);
        tmax = fmaxf(tmax, __shfl_xor(tmax, 32, 64));
        // T13 defer-rescale: only when max grows by > 8 (P bounded by e^8)
        if (__any(tmax > m + 8.f)) {
            float newm  = fmaxf(m, tmax);
            float scale = __expf(m - newm);
            lsum *= scale;
            #pragma unroll
            for (int r = 0; r < 16; ++r) { oacc0[r] *= scale; oacc1[r] *= scale; }
            m = newm;
        }
        float p[16]; float ls = 0.f;
        #pragma unroll
        for (int r = 0; r < 16; ++r) { p[r] = __expf(s[r] - m); ls += p[r]; }
        lsum += ls;
        unsigned W[8], X[8];
        #pragma unroll
        for (int j = 0; j < 8; ++j)
            asm("v_cvt_pk_bf16_f32 %0, %1, %2" : "=v"(W[j]) : "v"(p[2 * j]), "v"(p[2 * j + 1]));
        #pragma unroll
        for (int j = 0; j < 8; ++j) X[j] = (unsigned)__shfl_xor((int)W[j], 32, 64);
        uint4 u0, u1;
        if (half == 0) { u0 = make_uint4(W[0], W[1], X[0], X[1]); u1 = make_uint4(W[4], W[5], X[4], X[5]); }
        else           { u0 = make_uint4(X[2], X[3], W[2], W[3]); u1 = make_uint4(X[6], X[7], W[6], W[7]); }
        short8 pf0 = __builtin_bit_cast(short8, u0);
        short8 pf1 = __builtin_bit_cast(short8, u1);
        const unsigned short* vp = Vb + ((size_t)(b * COUT + col)) * NSP + n0 + half * 8;
        short8 v00 = ld_frag(vp);
        short8 v01 = ld_frag(vp + 16);
        short8 v10 = ld_frag(vp + (size_t)32 * NSP);
        short8 v11 = ld_frag(vp + (size_t)32 * NSP + 16);
        oacc0 = __builtin_amdgcn_mfma_f32_32x32x16_bf16(v00, pf0, oacc0, 0, 0, 0);
        oacc0 = __builtin_amdgcn_mfma_f32_32x32x16_bf16(v01, pf1, oacc0, 0, 0, 0);
        oacc1 = __builtin_amdgcn_mfma_f32_32x32x16_bf16(v10, pf0, oacc1, 0, 0, 0);
        oacc1 = __builtin_amdgcn_mfma_f32_32x32x16_bf16(v11, pf1, oacc1, 0, 0, 0);
    }

    float lfull = lsum + __shfl_xor(lsum, 32, 64);
    size_t base = (size_t)b * SPLITS + split;
    if (lane < 32) {
        pm[base * NSP + q0 + col] = m;
        pl[base * NSP + q0 + col] = lfull;
    }
    float* pa = pacc + base * (size_t)(COUT * NSP) + q0 + col;
    #pragma unroll
    for (int r = 0; r < 16; ++r) {
        int crow = (r & 3) + 8 * (r >> 2) + 4 * half;
        pa[(size_t)crow * NSP]        = oacc0[r];
        pa[(size_t)(crow + 32) * NSP] = oacc1[r];
    }
}

// ---------------- combine split-K partials ----------------
__global__ void attn_combine_k(const float* __restrict__ pm, const float* __restrict__ pl,
                               const float* __restrict__ pacc, float* __restrict__ out) {
    int idx = blockIdx.x * blockDim.x + threadIdx.x;   // over B*COUT*NSP
    if (idx >= BB * COUT * NSP) return;
    int n = idx % NSP;
    int c = (idx / NSP) % COUT;
    int b = idx / (NSP * COUT);
    float M = -1e30f;
    #pragma unroll
    for (int j = 0; j < SPLITS; ++j)
        M = fmaxf(M, pm[((size_t)b * SPLITS + j) * NSP + n]);
    float L = 0.f, O = 0.f;
    #pragma unroll
    for (int j = 0; j < SPLITS; ++j) {
        size_t base = (size_t)b * SPLITS + j;
        float wgt = __expf(pm[base * NSP + n] - M);
        L += pl[base * NSP + n] * wgt;
        O += pacc[(base * COUT + c) * NSP + n] * wgt;
    }
    out[idx] = O / L;
}

// ---------------- launch ----------------
extern "C" void kernel_launch(void* const* d_in, const int* in_sizes, int n_in,
                              void* d_out, int out_size, void* d_ws, size_t ws_size,
                              hipStream_t stream) {
    const float* x      = (const float*)d_in[0];
    const float* conv_w = (const float*)d_in[1];
    const float* conv_b = (const float*)d_in[2];
    const float* gamma  = (const float*)d_in[3];
    const float* beta   = (const float*)d_in[4];
    const float* wq     = (const float*)d_in[5];
    const float* bq     = (const float*)d_in[6];
    const float* wk     = (const float*)d_in[7];
    const float* bk     = (const float*)d_in[8];
    const float* wv     = (const float*)d_in[9];
    const float* bv     = (const float*)d_in[10];
    float* out = (float*)d_out;

    const int ELEMS = BB * COUT * NSP;      // 1,024,000
    char* w8 = (char*)d_ws;
    float* y     = (float*)w8;                          // 4,096,000 B
    float* stats = (float*)(w8 + 4096000);              // 1,024 B
    unsigned short* Qhi = (unsigned short*)(w8 + 4097024);
    unsigned short* Qlo = Qhi + (size_t)ELEMS;          // each 2,048,000 B
    unsigned short* Khi = Qlo + (size_t)ELEMS;
    unsigned short* Klo = Khi + (size_t)ELEMS;
    unsigned short* Vb  = Klo + (size_t)ELEMS;
    float* pm   = (float*)(Vb + (size_t)ELEMS);
    float* pl   = pm + (size_t)BB * SPLITS * NSP;       // 640,000 B each
    float* pacc = pl + (size_t)BB * SPLITS * NSP;       // 40,960,000 B
    // xpad aliases pacc: xpad is only live before conv3d_k; pacc only after qkv_k
    float* xpad = pacc;                                 // needs 2,725,888 B

    int blocks = (ELEMS + 255) / 256;       // 4000

    pad_k<<<(BB * CIN * PSP + 255) / 256, 256, 0, stream>>>(x, xpad);
    conv3d_k<<<BB * 8 * 32, 256, 0, stream>>>(xpad, conv_w, conv_b, y);
    instnorm_stats_k<<<BB * COUT, 256, 0, stream>>>(y, stats);
    norm_lrelu_k<<<blocks, 256, 0, stream>>>(y, stats, gamma, beta);
    qkv_k<<<BB * 8 * 32, 256, 0, stream>>>(y, wq, bq, wk, bk, wv, bv,
                                           Qhi, Qlo, Khi, Klo, Vb);
    attn_pass1_mfma<<<BB * QPB * SPLITS, 128, 0, stream>>>(Qhi, Qlo, Khi, Klo, Vb,
                                                           pm, pl, pacc);
    attn_combine_k<<<blocks, 256, 0, stream>>>(pm, pl, pacc, out);
}

// Round 5
// 249.148 us; speedup vs baseline: 1.1803x; 1.1803x over previous
//
#include <hip/hip_runtime.h>
#include <math.h>

#define CIN   32
#define COUT  64
#define DD    20
#define PD    22        // padded dim
#define PSP   (PD*PD*PD)   // 10648
#define NSP   8000      // 20*20*20
#define BB    2
#define EPSN  1e-5f
#define SLOPE 0.01f

#define NT     250              // 32-row k/q tiles per batch
#define SPLITS 10
#define NKT    (NT / SPLITS)    // 25 k-tiles per split
#define KPS    (NSP / SPLITS)
#define QUADS  63               // ceil(250/4) q-tiles, 4 per block

#define COG 8                   // conv: output channels per thread
#define OG  8                   // qkv: output channels per thread

typedef float  f32x16 __attribute__((ext_vector_type(16)));
typedef short  short8 __attribute__((ext_vector_type(8)));

__device__ __forceinline__ unsigned short f2bf_rne(float x) {
    unsigned u = __float_as_uint(x);
    unsigned r = (u + 0x7FFFu + ((u >> 16) & 1u)) >> 16;
    return (unsigned short)r;
}
__device__ __forceinline__ float bf2f(unsigned short h) {
    return __uint_as_float(((unsigned)h) << 16);
}
__device__ __forceinline__ short8 ld_frag(const unsigned short* p) {
    uint4 t = *reinterpret_cast<const uint4*>(p);
    return __builtin_bit_cast(short8, t);
}

// ---------------- zero-pad x into [B][CIN][22][22][22] ----------------
__global__ void pad_k(const float* __restrict__ x, float* __restrict__ xp) {
    int idx = blockIdx.x * blockDim.x + threadIdx.x;
    if (idx >= BB * CIN * PSP) return;
    int pw = idx % PD;
    int ph = (idx / PD) % PD;
    int pd = (idx / (PD * PD)) % PD;
    int bc = idx / PSP;
    float v = 0.f;
    if (pw >= 1 && pw <= DD && ph >= 1 && ph <= DD && pd >= 1 && pd <= DD)
        v = x[(size_t)bc * NSP + ((size_t)(pd - 1) * DD + (ph - 1)) * DD + (pw - 1)];
    xp[idx] = v;
}

// ---------------- Conv3d k=3 s=1 SAME + bias (padded input, reg-blocked) ----------------
__global__ __launch_bounds__(256) void conv3d_k(const float* __restrict__ xp,
                                                const float* __restrict__ w,
                                                const float* __restrict__ bias,
                                                float* __restrict__ y) {
    int blk = blockIdx.x;
    int vb  = blk & 31;
    int cg  = (blk >> 5) & 7;       // uniform co-group
    int b   = blk >> 8;
    int vox = vb * 256 + threadIdx.x;
    bool valid = vox < NSP;
    int v  = valid ? vox : 0;
    int w_ = v % DD;
    int h_ = (v / DD) % DD;
    int d_ = v / (DD * DD);
    int pvox = ((d_ + 1) * PD + (h_ + 1)) * PD + (w_ + 1);
    const float* xb = xp + (size_t)b * CIN * PSP + pvox;

    float acc[COG];
    #pragma unroll
    for (int j = 0; j < COG; ++j) acc[j] = 0.f;

    for (int ci = 0; ci < CIN; ++ci) {
        const float* xc = xb + (size_t)ci * PSP;
        float xv[27];
        #pragma unroll
        for (int kd = 0; kd < 3; ++kd)
            #pragma unroll
            for (int kh = 0; kh < 3; ++kh)
                #pragma unroll
                for (int kw = 0; kw < 3; ++kw)
                    xv[(kd * 3 + kh) * 3 + kw] =
                        xc[(kd - 1) * (PD * PD) + (kh - 1) * PD + (kw - 1)];
        #pragma unroll
        for (int j = 0; j < COG; ++j) {
            int co = cg * COG + j;                       // uniform
            const float* wr = w + ((size_t)co * CIN + ci) * 27;
            float a = acc[j];
            #pragma unroll
            for (int t = 0; t < 27; ++t) a += xv[t] * wr[t];
            acc[j] = a;
        }
    }
    if (valid) {
        #pragma unroll
        for (int j = 0; j < COG; ++j) {
            int co = cg * COG + j;
            y[((size_t)b * COUT + co) * NSP + vox] = acc[j] + bias[co];
        }
    }
}

// ---------------- InstanceNorm stats: one block per (b,c) ----------------
__global__ void instnorm_stats_k(const float* __restrict__ y, float* __restrict__ stats) {
    int bc = blockIdx.x;                 // 0..127
    const float* yb = y + (size_t)bc * NSP;
    float s = 0.f, ss = 0.f;
    for (int i = threadIdx.x; i < NSP; i += blockDim.x) {
        float v = yb[i];
        s += v; ss += v * v;
    }
    __shared__ float rs[256], rss[256];
    rs[threadIdx.x] = s; rss[threadIdx.x] = ss;
    __syncthreads();
    for (int off = 128; off > 0; off >>= 1) {
        if (threadIdx.x < off) {
            rs[threadIdx.x]  += rs[threadIdx.x + off];
            rss[threadIdx.x] += rss[threadIdx.x + off];
        }
        __syncthreads();
    }
    if (threadIdx.x == 0) {
        float mean = rs[0] / (float)NSP;
        float var  = rss[0] / (float)NSP - mean * mean;
        stats[bc * 2 + 0] = mean;
        stats[bc * 2 + 1] = rsqrtf(var + EPSN);
    }
}

// ---------------- normalize + affine + LeakyReLU (in place) ----------------
__global__ void norm_lrelu_k(float* __restrict__ y, const float* __restrict__ stats,
                             const float* __restrict__ gamma, const float* __restrict__ beta) {
    int idx = blockIdx.x * blockDim.x + threadIdx.x;
    if (idx >= BB * COUT * NSP) return;
    int bc = idx / NSP;
    int c  = bc % COUT;
    float mean = stats[bc * 2 + 0];
    float rstd = stats[bc * 2 + 1];
    float v = (y[idx] - mean) * rstd * gamma[c] + beta[c];
    y[idx] = v >= 0.f ? v : SLOPE * v;
}

// ---------------- QKV projections -> MFMA-fragment-order bf16 layouts ----------------
// Q/K (hi,lo): [b][tile][c(4)][half(2)][row(32)][e(8)]   (1KB contiguous per wave-load)
// V:           [b][tile][Y(2)][X(2)][half(2)][row(32)][e(8)]
__global__ __launch_bounds__(256) void qkv_k(const float* __restrict__ f,
                      const float* __restrict__ wq, const float* __restrict__ bq,
                      const float* __restrict__ wk, const float* __restrict__ bk,
                      const float* __restrict__ wv, const float* __restrict__ bv,
                      unsigned short* __restrict__ Qfh, unsigned short* __restrict__ Qfl,
                      unsigned short* __restrict__ Kfh, unsigned short* __restrict__ Kfl,
                      unsigned short* __restrict__ Vf) {
    int blk = blockIdx.x;
    int vb  = blk & 31;
    int og  = (blk >> 5) & 7;       // uniform o-group
    int b   = blk >> 8;
    int n   = vb * 256 + threadIdx.x;
    bool valid = n < NSP;
    int nn  = valid ? n : 0;
    const float* fb = f + (size_t)b * COUT * NSP + nn;

    float aq[OG], ak[OG], av[OG];
    #pragma unroll
    for (int j = 0; j < OG; ++j) {
        int o = og * OG + j;
        aq[j] = bq[o]; ak[j] = bk[o]; av[j] = bv[o];
    }
    for (int c = 0; c < COUT; ++c) {
        float fc = fb[(size_t)c * NSP];
        #pragma unroll
        for (int j = 0; j < OG; ++j) {
            int o = og * OG + j;                         // uniform
            aq[j] += wq[o * COUT + c] * fc;
            ak[j] += wk[o * COUT + c] * fc;
            av[j] += wv[o * COUT + c] * fc;
        }
    }
    if (!valid) return;

    int t  = n >> 5;                // tile
    int kk = n & 31;                // row within tile
    unsigned short qh[OG], ql[OG], kh[OG], kl[OG];
    #pragma unroll
    for (int j = 0; j < OG; ++j) {
        qh[j] = f2bf_rne(aq[j]); ql[j] = f2bf_rne(aq[j] - bf2f(qh[j]));
        kh[j] = f2bf_rne(ak[j]); kl[j] = f2bf_rne(ak[j] - bf2f(kh[j]));
    }
    // Q/K store: c = og>>1, half = og&1
    size_t qko = ((size_t)((b * NT + t) * 4 + (og >> 1)) * 2 + (og & 1)) * 256 + kk * 8;
    *reinterpret_cast<uint4*>(Qfh + qko) = *reinterpret_cast<const uint4*>(qh);
    *reinterpret_cast<uint4*>(Qfl + qko) = *reinterpret_cast<const uint4*>(ql);
    *reinterpret_cast<uint4*>(Kfh + qko) = *reinterpret_cast<const uint4*>(kh);
    *reinterpret_cast<uint4*>(Kfl + qko) = *reinterpret_cast<const uint4*>(kl);
    // V store: Y=kk>>4, half=(kk>>3)&1, e=kk&7 ; X=og>>2, row=(og&3)*8+j
    {
        int Y = kk >> 4, hf = (kk >> 3) & 1, e = kk & 7;
        size_t vbase = ((size_t)((b * NT + t) * 2 + Y) * 2 + (og >> 2)) * 512
                     + hf * 256 + e;
        #pragma unroll
        for (int j = 0; j < OG; ++j)
            Vf[vbase + ((og & 3) * 8 + j) * 8] = f2bf_rne(av[j]);
    }
}

// ---------------- flash attention pass 1: MFMA, split-K, online softmax ----------------
// block = 4 waves = 4 q-tiles sharing K/V tiles (L1 reuse, per-tile barrier)
__global__ __launch_bounds__(256, 3) void attn_pass1_mfma(
        const unsigned short* __restrict__ Qfh, const unsigned short* __restrict__ Qfl,
        const unsigned short* __restrict__ Kfh, const unsigned short* __restrict__ Kfl,
        const unsigned short* __restrict__ Vf,
        float* __restrict__ pm, float* __restrict__ pl, float* __restrict__ pacc) {
    int bid   = blockIdx.x;
    int split = bid / (BB * QUADS);         // split-major: co-resident share K/V window
    int rem   = bid % (BB * QUADS);
    int b     = rem / QUADS;
    int quad  = rem % QUADS;
    int wave  = threadIdx.x >> 6;
    int lane  = threadIdx.x & 63;
    int col   = lane & 31;
    int half  = lane >> 5;
    int qt    = quad * 4 + wave;
    bool qvalid = qt < NT;
    int qtc   = qvalid ? qt : NT - 1;

    // Q fragments: contiguous 1KB per c-chunk
    short8 qfh[4], qfl[4];
    {
        const unsigned short* qp  = Qfh + (size_t)(b * NT + qtc) * 2048 + lane * 8;
        const unsigned short* qp2 = Qfl + (size_t)(b * NT + qtc) * 2048 + lane * 8;
        #pragma unroll
        for (int c = 0; c < 4; ++c) {
            qfh[c] = ld_frag(qp  + c * 512);
            qfl[c] = ld_frag(qp2 + c * 512);
        }
    }

    f32x16 oacc0 = {};
    f32x16 oacc1 = {};
    float m = -3e38f, lsum = 0.f;

    for (int t = 0; t < NKT; ++t) {
        __syncthreads();                    // keep waves aligned for L1 reuse
        int tg = split * NKT + t;
        const unsigned short* kp  = Kfh + (size_t)(b * NT + tg) * 2048 + lane * 8;
        const unsigned short* kp2 = Kfl + (size_t)(b * NT + tg) * 2048 + lane * 8;
        f32x16 s = {};
        #pragma unroll
        for (int c = 0; c < 4; ++c) {
            short8 kfh = ld_frag(kp  + c * 512);
            short8 kfl = ld_frag(kp2 + c * 512);
            s = __builtin_amdgcn_mfma_f32_32x32x16_bf16(kfh, qfh[c], s, 0, 0, 0);
            s = __builtin_amdgcn_mfma_f32_32x32x16_bf16(kfh, qfl[c], s, 0, 0, 0);
            s = __builtin_amdgcn_mfma_f32_32x32x16_bf16(kfl, qfh[c], s, 0, 0, 0);
        }
        float tmax = s[0];
        #pragma unroll
        for (int r = 1; r < 16; ++r) tmax = fmaxf(tmax, s[r]);
        tmax = fmaxf(tmax, __shfl_xor(tmax, 32, 64));
        // T13 defer-rescale
        if (__any(tmax > m + 8.f)) {
            float newm  = fmaxf(m, tmax);
            float scale = __expf(m - newm);
            lsum *= scale;
            #pragma unroll
            for (int r = 0; r < 16; ++r) { oacc0[r] *= scale; oacc1[r] *= scale; }
            m = newm;
        }
        float p[16]; float ls = 0.f;
        #pragma unroll
        for (int r = 0; r < 16; ++r) { p[r] = __expf(s[r] - m); ls += p[r]; }
        lsum += ls;
        unsigned W[8], X[8];
        #pragma unroll
        for (int j = 0; j < 8; ++j)
            asm("v_cvt_pk_bf16_f32 %0, %1, %2" : "=v"(W[j]) : "v"(p[2 * j]), "v"(p[2 * j + 1]));
        #pragma unroll
        for (int j = 0; j < 8; ++j) X[j] = (unsigned)__shfl_xor((int)W[j], 32, 64);
        uint4 u0, u1;
        if (half == 0) { u0 = make_uint4(W[0], W[1], X[0], X[1]); u1 = make_uint4(W[4], W[5], X[4], X[5]); }
        else           { u0 = make_uint4(X[2], X[3], W[2], W[3]); u1 = make_uint4(X[6], X[7], W[6], W[7]); }
        short8 pf0 = __builtin_bit_cast(short8, u0);   // keys 0..15 of tile
        short8 pf1 = __builtin_bit_cast(short8, u1);   // keys 16..31
        const unsigned short* vp = Vf + (size_t)(b * NT + tg) * 2048 + lane * 8;
        short8 v00 = ld_frag(vp);                      // Y=0,X=0
        short8 v10 = ld_frag(vp + 512);                // Y=0,X=1
        short8 v01 = ld_frag(vp + 1024);               // Y=1,X=0
        short8 v11 = ld_frag(vp + 1536);               // Y=1,X=1
        oacc0 = __builtin_amdgcn_mfma_f32_32x32x16_bf16(v00, pf0, oacc0, 0, 0, 0);
        oacc0 = __builtin_amdgcn_mfma_f32_32x32x16_bf16(v01, pf1, oacc0, 0, 0, 0);
        oacc1 = __builtin_amdgcn_mfma_f32_32x32x16_bf16(v10, pf0, oacc1, 0, 0, 0);
        oacc1 = __builtin_amdgcn_mfma_f32_32x32x16_bf16(v11, pf1, oacc1, 0, 0, 0);
    }

    if (!qvalid) return;
    int q0 = qt * 32;
    float lfull = lsum + __shfl_xor(lsum, 32, 64);
    size_t base = (size_t)b * SPLITS + split;
    if (lane < 32) {
        pm[base * NSP + q0 + col] = m;
        pl[base * NSP + q0 + col] = lfull;
    }
    float* pa = pacc + base * (size_t)(COUT * NSP) + q0 + col;
    #pragma unroll
    for (int r = 0; r < 16; ++r) {
        int crow = (r & 3) + 8 * (r >> 2) + 4 * half;
        pa[(size_t)crow * NSP]        = oacc0[r];
        pa[(size_t)(crow + 32) * NSP] = oacc1[r];
    }
}

// ---------------- combine split-K partials ----------------
__global__ void attn_combine_k(const float* __restrict__ pm, const float* __restrict__ pl,
                               const float* __restrict__ pacc, float* __restrict__ out) {
    int idx = blockIdx.x * blockDim.x + threadIdx.x;   // over B*COUT*NSP
    if (idx >= BB * COUT * NSP) return;
    int n = idx % NSP;
    int c = (idx / NSP) % COUT;
    int b = idx / (NSP * COUT);
    float M = -1e30f;
    #pragma unroll
    for (int j = 0; j < SPLITS; ++j)
        M = fmaxf(M, pm[((size_t)b * SPLITS + j) * NSP + n]);
    float L = 0.f, O = 0.f;
    #pragma unroll
    for (int j = 0; j < SPLITS; ++j) {
        size_t base = (size_t)b * SPLITS + j;
        float wgt = __expf(pm[base * NSP + n] - M);
        L += pl[base * NSP + n] * wgt;
        O += pacc[(base * COUT + c) * NSP + n] * wgt;
    }
    out[idx] = O / L;
}

// ---------------- launch ----------------
extern "C" void kernel_launch(void* const* d_in, const int* in_sizes, int n_in,
                              void* d_out, int out_size, void* d_ws, size_t ws_size,
                              hipStream_t stream) {
    const float* x      = (const float*)d_in[0];
    const float* conv_w = (const float*)d_in[1];
    const float* conv_b = (const float*)d_in[2];
    const float* gamma  = (const float*)d_in[3];
    const float* beta   = (const float*)d_in[4];
    const float* wq     = (const float*)d_in[5];
    const float* bq     = (const float*)d_in[6];
    const float* wk     = (const float*)d_in[7];
    const float* bk     = (const float*)d_in[8];
    const float* wv     = (const float*)d_in[9];
    const float* bv     = (const float*)d_in[10];
    float* out = (float*)d_out;

    const int ELEMS = BB * COUT * NSP;      // 1,024,000
    char* w8 = (char*)d_ws;
    float* y     = (float*)w8;                          // 4,096,000 B
    float* stats = (float*)(w8 + 4096000);              // 1,024 B
    unsigned short* Qfh = (unsigned short*)(w8 + 4097024);
    unsigned short* Qfl = Qfh + (size_t)ELEMS;          // each 2,048,000 B
    unsigned short* Kfh = Qfl + (size_t)ELEMS;
    unsigned short* Kfl = Kfh + (size_t)ELEMS;
    unsigned short* Vf  = Kfl + (size_t)ELEMS;
    float* pm   = (float*)(Vf + (size_t)ELEMS);
    float* pl   = pm + (size_t)BB * SPLITS * NSP;       // 640,000 B each
    float* pacc = pl + (size_t)BB * SPLITS * NSP;       // 40,960,000 B
    // xpad aliases pacc: xpad live only before conv3d_k; pacc only after qkv_k
    float* xpad = pacc;                                 // needs 2,725,888 B

    int blocks = (ELEMS + 255) / 256;       // 4000

    pad_k<<<(BB * CIN * PSP + 255) / 256, 256, 0, stream>>>(x, xpad);
    conv3d_k<<<BB * 8 * 32, 256, 0, stream>>>(xpad, conv_w, conv_b, y);
    instnorm_stats_k<<<BB * COUT, 256, 0, stream>>>(y, stats);
    norm_lrelu_k<<<blocks, 256, 0, stream>>>(y, stats, gamma, beta);
    qkv_k<<<BB * 8 * 32, 256, 0, stream>>>(y, wq, bq, wk, bk, wv, bv,
                                           Qfh, Qfl, Kfh, Kfl, Vf);
    attn_pass1_mfma<<<SPLITS * BB * QUADS, 256, 0, stream>>>(Qfh, Qfl, Kfh, Kfl, Vf,
                                                             pm, pl, pacc);
    attn_combine_k<<<blocks, 256, 0, stream>>>(pm, pl, pacc, out);
}

// Round 6
// 199.429 us; speedup vs baseline: 1.4746x; 1.2493x over previous
//
#include <hip/hip_runtime.h>
#include <math.h>

#define CIN   32
#define COUT  64
#define DD    20
#define PD    22        // padded dim
#define PSP   (PD*PD*PD)   // 10648
#define NSP   8000      // 20*20*20
#define BB    2
#define EPSN  1e-5f
#define SLOPE 0.01f

#define NT     250              // 32-row k/q tiles per batch
#define SPLITS 10
#define NKT    (NT / SPLITS)    // 25 k-tiles per split
#define QUADS  63               // ceil(250/4) q-tiles, 4 per block

#define COG 8                   // conv: output channels per thread
#define OG  8                   // qkv: output channels per thread

typedef float  f32x16 __attribute__((ext_vector_type(16)));
typedef short  short8 __attribute__((ext_vector_type(8)));

__device__ __forceinline__ unsigned short f2bf_rne(float x) {
    unsigned u = __float_as_uint(x);
    unsigned r = (u + 0x7FFFu + ((u >> 16) & 1u)) >> 16;
    return (unsigned short)r;
}
__device__ __forceinline__ float bf2f(unsigned short h) {
    return __uint_as_float(((unsigned)h) << 16);
}
__device__ __forceinline__ short8 ld_frag(const unsigned short* p) {
    uint4 t = *reinterpret_cast<const uint4*>(p);
    return __builtin_bit_cast(short8, t);
}
// async global->LDS, 16B per lane; LDS dest is wave-uniform base + lane*16
__device__ __forceinline__ void gload_lds16(const void* gsrc, void* ldst) {
    typedef __attribute__((address_space(1))) const unsigned int GU;
    typedef __attribute__((address_space(3))) unsigned int LU;
    __builtin_amdgcn_global_load_lds((GU*)gsrc, (LU*)ldst, 16, 0, 0);
}

// ---------------- zero-pad x into [B][CIN][22][22][22] ----------------
__global__ void pad_k(const float* __restrict__ x, float* __restrict__ xp) {
    int idx = blockIdx.x * blockDim.x + threadIdx.x;
    if (idx >= BB * CIN * PSP) return;
    int pw = idx % PD;
    int ph = (idx / PD) % PD;
    int pd = (idx / (PD * PD)) % PD;
    int bc = idx / PSP;
    float v = 0.f;
    if (pw >= 1 && pw <= DD && ph >= 1 && ph <= DD && pd >= 1 && pd <= DD)
        v = x[(size_t)bc * NSP + ((size_t)(pd - 1) * DD + (ph - 1)) * DD + (pw - 1)];
    xp[idx] = v;
}

// ---------------- Conv3d k=3 s=1 SAME + bias (padded input, reg-blocked) ----------------
__global__ __launch_bounds__(256) void conv3d_k(const float* __restrict__ xp,
                                                const float* __restrict__ w,
                                                const float* __restrict__ bias,
                                                float* __restrict__ y) {
    int blk = blockIdx.x;
    int vb  = blk & 31;
    int cg  = (blk >> 5) & 7;       // uniform co-group
    int b   = blk >> 8;
    int vox = vb * 256 + threadIdx.x;
    bool valid = vox < NSP;
    int v  = valid ? vox : 0;
    int w_ = v % DD;
    int h_ = (v / DD) % DD;
    int d_ = v / (DD * DD);
    int pvox = ((d_ + 1) * PD + (h_ + 1)) * PD + (w_ + 1);
    const float* xb = xp + (size_t)b * CIN * PSP + pvox;

    float acc[COG];
    #pragma unroll
    for (int j = 0; j < COG; ++j) acc[j] = 0.f;

    for (int ci = 0; ci < CIN; ++ci) {
        const float* xc = xb + (size_t)ci * PSP;
        float xv[27];
        #pragma unroll
        for (int kd = 0; kd < 3; ++kd)
            #pragma unroll
            for (int kh = 0; kh < 3; ++kh)
                #pragma unroll
                for (int kw = 0; kw < 3; ++kw)
                    xv[(kd * 3 + kh) * 3 + kw] =
                        xc[(kd - 1) * (PD * PD) + (kh - 1) * PD + (kw - 1)];
        #pragma unroll
        for (int j = 0; j < COG; ++j) {
            int co = cg * COG + j;                       // uniform
            const float* wr = w + ((size_t)co * CIN + ci) * 27;
            float a = acc[j];
            #pragma unroll
            for (int t = 0; t < 27; ++t) a += xv[t] * wr[t];
            acc[j] = a;
        }
    }
    if (valid) {
        #pragma unroll
        for (int j = 0; j < COG; ++j) {
            int co = cg * COG + j;
            y[((size_t)b * COUT + co) * NSP + vox] = acc[j] + bias[co];
        }
    }
}

// ---------------- InstanceNorm stats: one block per (b,c) ----------------
__global__ void instnorm_stats_k(const float* __restrict__ y, float* __restrict__ stats) {
    int bc = blockIdx.x;                 // 0..127
    const float* yb = y + (size_t)bc * NSP;
    float s = 0.f, ss = 0.f;
    for (int i = threadIdx.x; i < NSP; i += blockDim.x) {
        float v = yb[i];
        s += v; ss += v * v;
    }
    __shared__ float rs[256], rss[256];
    rs[threadIdx.x] = s; rss[threadIdx.x] = ss;
    __syncthreads();
    for (int off = 128; off > 0; off >>= 1) {
        if (threadIdx.x < off) {
            rs[threadIdx.x]  += rs[threadIdx.x + off];
            rss[threadIdx.x] += rss[threadIdx.x + off];
        }
        __syncthreads();
    }
    if (threadIdx.x == 0) {
        float mean = rs[0] / (float)NSP;
        float var  = rss[0] / (float)NSP - mean * mean;
        stats[bc * 2 + 0] = mean;
        stats[bc * 2 + 1] = rsqrtf(var + EPSN);
    }
}

// ---------------- normalize + affine + LeakyReLU (in place) ----------------
__global__ void norm_lrelu_k(float* __restrict__ y, const float* __restrict__ stats,
                             const float* __restrict__ gamma, const float* __restrict__ beta) {
    int idx = blockIdx.x * blockDim.x + threadIdx.x;
    if (idx >= BB * COUT * NSP) return;
    int bc = idx / NSP;
    int c  = bc % COUT;
    float mean = stats[bc * 2 + 0];
    float rstd = stats[bc * 2 + 1];
    float v = (y[idx] - mean) * rstd * gamma[c] + beta[c];
    y[idx] = v >= 0.f ? v : SLOPE * v;
}

// ---------------- QKV projections -> MFMA-fragment-order bf16 layouts ----------------
// Q/K (hi,lo): [b][tile][c(4)][half(2)][row(32)][e(8)]   (4KB contiguous per tile)
// V:           [b][tile][Y(2)][X(2)][half(2)][row(32)][e(8)]
__global__ __launch_bounds__(256) void qkv_k(const float* __restrict__ f,
                      const float* __restrict__ wq, const float* __restrict__ bq,
                      const float* __restrict__ wk, const float* __restrict__ bk,
                      const float* __restrict__ wv, const float* __restrict__ bv,
                      unsigned short* __restrict__ Qfh, unsigned short* __restrict__ Qfl,
                      unsigned short* __restrict__ Kfh, unsigned short* __restrict__ Kfl,
                      unsigned short* __restrict__ Vf) {
    int blk = blockIdx.x;
    int vb  = blk & 31;
    int og  = (blk >> 5) & 7;       // uniform o-group
    int b   = blk >> 8;
    int n   = vb * 256 + threadIdx.x;
    bool valid = n < NSP;
    int nn  = valid ? n : 0;
    const float* fb = f + (size_t)b * COUT * NSP + nn;

    float aq[OG], ak[OG], av[OG];
    #pragma unroll
    for (int j = 0; j < OG; ++j) {
        int o = og * OG + j;
        aq[j] = bq[o]; ak[j] = bk[o]; av[j] = bv[o];
    }
    for (int c = 0; c < COUT; ++c) {
        float fc = fb[(size_t)c * NSP];
        #pragma unroll
        for (int j = 0; j < OG; ++j) {
            int o = og * OG + j;                         // uniform
            aq[j] += wq[o * COUT + c] * fc;
            ak[j] += wk[o * COUT + c] * fc;
            av[j] += wv[o * COUT + c] * fc;
        }
    }
    if (!valid) return;

    int t  = n >> 5;                // tile
    int kk = n & 31;                // row within tile
    unsigned short qh[OG], ql[OG], kh[OG], kl[OG];
    #pragma unroll
    for (int j = 0; j < OG; ++j) {
        qh[j] = f2bf_rne(aq[j]); ql[j] = f2bf_rne(aq[j] - bf2f(qh[j]));
        kh[j] = f2bf_rne(ak[j]); kl[j] = f2bf_rne(ak[j] - bf2f(kh[j]));
    }
    // Q/K store: c = og>>1, half = og&1
    size_t qko = ((size_t)((b * NT + t) * 4 + (og >> 1)) * 2 + (og & 1)) * 256 + kk * 8;
    *reinterpret_cast<uint4*>(Qfh + qko) = *reinterpret_cast<const uint4*>(qh);
    *reinterpret_cast<uint4*>(Qfl + qko) = *reinterpret_cast<const uint4*>(ql);
    *reinterpret_cast<uint4*>(Kfh + qko) = *reinterpret_cast<const uint4*>(kh);
    *reinterpret_cast<uint4*>(Kfl + qko) = *reinterpret_cast<const uint4*>(kl);
    // V store: Y=kk>>4, half=(kk>>3)&1, e=kk&7 ; X=og>>2, row=(og&3)*8+j
    {
        int Y = kk >> 4, hf = (kk >> 3) & 1, e = kk & 7;
        size_t vbase = ((size_t)((b * NT + t) * 2 + Y) * 2 + (og >> 2)) * 512
                     + hf * 256 + e;
        #pragma unroll
        for (int j = 0; j < OG; ++j)
            Vf[vbase + ((og & 3) * 8 + j) * 8] = f2bf_rne(av[j]);
    }
}

// ---------------- flash attention pass 1: MFMA + LDS double-buffer prefetch ----------------
// block = 4 waves = 4 q-tiles; K/V tile (12KB) staged cooperatively via global_load_lds;
// stage(t+1) issued right after the single per-tile barrier -> latency hidden by compute.
__global__ __launch_bounds__(256, 3) void attn_pass1_mfma(
        const unsigned short* __restrict__ Qfh, const unsigned short* __restrict__ Qfl,
        const unsigned short* __restrict__ Kfh, const unsigned short* __restrict__ Kfl,
        const unsigned short* __restrict__ Vf,
        float* __restrict__ pm, float* __restrict__ pl, float* __restrict__ pacc) {
    int bid   = blockIdx.x;
    int split = bid / (BB * QUADS);         // split-major: co-resident share K/V window
    int rem   = bid % (BB * QUADS);
    int b     = rem / QUADS;
    int quad  = rem % QUADS;
    int wave  = threadIdx.x >> 6;
    int lane  = threadIdx.x & 63;
    int col   = lane & 31;
    int half  = lane >> 5;
    int qt    = quad * 4 + wave;
    bool qvalid = qt < NT;
    int qtc   = qvalid ? qt : NT - 1;
    int bNT   = b * NT;

    __shared__ __align__(16) char ldsbuf[2][12288];   // [Kh 4K | Kl 4K | V 4K]

    // Q fragments: contiguous 1KB per c-chunk
    short8 qfh[4], qfl[4];
    {
        const unsigned short* qp  = Qfh + (size_t)(bNT + qtc) * 2048 + lane * 8;
        const unsigned short* qp2 = Qfl + (size_t)(bNT + qtc) * 2048 + lane * 8;
        #pragma unroll
        for (int c = 0; c < 4; ++c) {
            qfh[c] = ld_frag(qp  + c * 512);
            qfl[c] = ld_frag(qp2 + c * 512);
        }
    }

    int wo = wave * 1024;           // this wave's 1KB slice of each 4KB chunk
    int go = wo + lane * 16;        // byte offset into the tile's 4KB chunk

    auto STAGE = [&](int bufi, int tg) {
        size_t tb = (size_t)(bNT + tg) * 2048;     // elements (=4096 B)
        char* l = &ldsbuf[bufi][0];
        gload_lds16((const char*)(Kfh + tb) + go, l + wo);
        gload_lds16((const char*)(Kfl + tb) + go, l + 4096 + wo);
        gload_lds16((const char*)(Vf  + tb) + go, l + 8192 + wo);
    };

    f32x16 oacc0 = {};
    f32x16 oacc1 = {};
    float m = -3e38f, lsum = 0.f;

    int t0g = split * NKT;
    STAGE(0, t0g);                   // prologue stage of tile 0

    for (int t = 0; t < NKT; ++t) {
        asm volatile("s_waitcnt vmcnt(0)" ::: "memory");   // own stage(t) landed
        __syncthreads();            // all waves staged(t) + done reading buf[t-1]
        if (t + 1 < NKT) STAGE((t + 1) & 1, t0g + t + 1);

        const unsigned short* lk  = (const unsigned short*)&ldsbuf[t & 1][0];
        const unsigned short* lkl = (const unsigned short*)&ldsbuf[t & 1][4096];
        const unsigned short* lv  = (const unsigned short*)&ldsbuf[t & 1][8192];

        // QK^T: S^T = K.Q^T (3-term hi/lo product)
        f32x16 s = {};
        #pragma unroll
        for (int c = 0; c < 4; ++c) {
            short8 kfh = ld_frag(lk  + c * 512 + lane * 8);
            short8 kfl = ld_frag(lkl + c * 512 + lane * 8);
            s = __builtin_amdgcn_mfma_f32_32x32x16_bf16(kfh, qfh[c], s, 0, 0, 0);
            s = __builtin_amdgcn_mfma_f32_32x32x16_bf16(kfh, qfl[c], s, 0, 0, 0);
            s = __builtin_amdgcn_mfma_f32_32x32x16_bf16(kfl, qfh[c], s, 0, 0, 0);
        }
        // tree max over 16 + cross-half
        float t8[8];
        #pragma unroll
        for (int r = 0; r < 8; ++r) t8[r] = fmaxf(s[r], s[r + 8]);
        float t4a = fmaxf(t8[0], t8[1]), t4b = fmaxf(t8[2], t8[3]);
        float t4c = fmaxf(t8[4], t8[5]), t4d = fmaxf(t8[6], t8[7]);
        float tmax = fmaxf(fmaxf(t4a, t4b), fmaxf(t4c, t4d));
        tmax = fmaxf(tmax, __shfl_xor(tmax, 32, 64));
        // T13 defer-rescale
        if (__any(tmax > m + 8.f)) {
            float newm  = fmaxf(m, tmax);
            float scale = __expf(m - newm);
            lsum *= scale;
            #pragma unroll
            for (int r = 0; r < 16; ++r) { oacc0[r] *= scale; oacc1[r] *= scale; }
            m = newm;
        }
        // P in two groups of 8 (regs) -> bf16 B-fragments via cvt_pk + half-exchange
        short8 pf0, pf1;
        float ls;
        {
            float p[8];
            #pragma unroll
            for (int r = 0; r < 8; ++r) p[r] = __expf(s[r] - m);
            ls = ((p[0] + p[1]) + (p[2] + p[3])) + ((p[4] + p[5]) + (p[6] + p[7]));
            unsigned W[4], X[4];
            #pragma unroll
            for (int j = 0; j < 4; ++j)
                asm("v_cvt_pk_bf16_f32 %0, %1, %2" : "=v"(W[j]) : "v"(p[2 * j]), "v"(p[2 * j + 1]));
            #pragma unroll
            for (int j = 0; j < 4; ++j) X[j] = (unsigned)__shfl_xor((int)W[j], 32, 64);
            uint4 u = half ? make_uint4(X[2], X[3], W[2], W[3])
                           : make_uint4(W[0], W[1], X[0], X[1]);
            pf0 = __builtin_bit_cast(short8, u);
        }
        {
            float p[8];
            #pragma unroll
            for (int r = 0; r < 8; ++r) p[r] = __expf(s[r + 8] - m);
            ls += ((p[0] + p[1]) + (p[2] + p[3])) + ((p[4] + p[5]) + (p[6] + p[7]));
            unsigned W[4], X[4];
            #pragma unroll
            for (int j = 0; j < 4; ++j)
                asm("v_cvt_pk_bf16_f32 %0, %1, %2" : "=v"(W[j]) : "v"(p[2 * j]), "v"(p[2 * j + 1]));
            #pragma unroll
            for (int j = 0; j < 4; ++j) X[j] = (unsigned)__shfl_xor((int)W[j], 32, 64);
            uint4 u = half ? make_uint4(X[2], X[3], W[2], W[3])
                           : make_uint4(W[0], W[1], X[0], X[1]);
            pf1 = __builtin_bit_cast(short8, u);
        }
        lsum += ls;
        // PV: O^T = V^T.P^T  (X -> oacc, Y -> pf)
        {
            short8 v00 = ld_frag(lv + 0 * 512 + lane * 8);   // Y0 X0
            short8 v10 = ld_frag(lv + 1 * 512 + lane * 8);   // Y0 X1
            oacc0 = __builtin_amdgcn_mfma_f32_32x32x16_bf16(v00, pf0, oacc0, 0, 0, 0);
            oacc1 = __builtin_amdgcn_mfma_f32_32x32x16_bf16(v10, pf0, oacc1, 0, 0, 0);
            short8 v01 = ld_frag(lv + 2 * 512 + lane * 8);   // Y1 X0
            short8 v11 = ld_frag(lv + 3 * 512 + lane * 8);   // Y1 X1
            oacc0 = __builtin_amdgcn_mfma_f32_32x32x16_bf16(v01, pf1, oacc0, 0, 0, 0);
            oacc1 = __builtin_amdgcn_mfma_f32_32x32x16_bf16(v11, pf1, oacc1, 0, 0, 0);
        }
    }

    if (!qvalid) return;
    int q0 = qt * 32;
    float lfull = lsum + __shfl_xor(lsum, 32, 64);
    size_t base = (size_t)b * SPLITS + split;
    if (lane < 32) {
        pm[base * NSP + q0 + col] = m;
        pl[base * NSP + q0 + col] = lfull;
    }
    float* pa = pacc + base * (size_t)(COUT * NSP) + q0 + col;
    #pragma unroll
    for (int r = 0; r < 16; ++r) {
        int crow = (r & 3) + 8 * (r >> 2) + 4 * half;
        pa[(size_t)crow * NSP]        = oacc0[r];
        pa[(size_t)(crow + 32) * NSP] = oacc1[r];
    }
}

// ---------------- combine split-K partials ----------------
__global__ void attn_combine_k(const float* __restrict__ pm, const float* __restrict__ pl,
                               const float* __restrict__ pacc, float* __restrict__ out) {
    int idx = blockIdx.x * blockDim.x + threadIdx.x;   // over B*COUT*NSP
    if (idx >= BB * COUT * NSP) return;
    int n = idx % NSP;
    int c = (idx / NSP) % COUT;
    int b = idx / (NSP * COUT);
    float M = -1e30f;
    #pragma unroll
    for (int j = 0; j < SPLITS; ++j)
        M = fmaxf(M, pm[((size_t)b * SPLITS + j) * NSP + n]);
    float L = 0.f, O = 0.f;
    #pragma unroll
    for (int j = 0; j < SPLITS; ++j) {
        size_t base = (size_t)b * SPLITS + j;
        float wgt = __expf(pm[base * NSP + n] - M);
        L += pl[base * NSP + n] * wgt;
        O += pacc[(base * COUT + c) * NSP + n] * wgt;
    }
    out[idx] = O / L;
}

// ---------------- launch ----------------
extern "C" void kernel_launch(void* const* d_in, const int* in_sizes, int n_in,
                              void* d_out, int out_size, void* d_ws, size_t ws_size,
                              hipStream_t stream) {
    const float* x      = (const float*)d_in[0];
    const float* conv_w = (const float*)d_in[1];
    const float* conv_b = (const float*)d_in[2];
    const float* gamma  = (const float*)d_in[3];
    const float* beta   = (const float*)d_in[4];
    const float* wq     = (const float*)d_in[5];
    const float* bq     = (const float*)d_in[6];
    const float* wk     = (const float*)d_in[7];
    const float* bk     = (const float*)d_in[8];
    const float* wv     = (const float*)d_in[9];
    const float* bv     = (const float*)d_in[10];
    float* out = (float*)d_out;

    const int ELEMS = BB * COUT * NSP;      // 1,024,000
    char* w8 = (char*)d_ws;
    float* y     = (float*)w8;                          // 4,096,000 B
    float* stats = (float*)(w8 + 4096000);              // 1,024 B
    unsigned short* Qfh = (unsigned short*)(w8 + 4097024);
    unsigned short* Qfl = Qfh + (size_t)ELEMS;          // each 2,048,000 B
    unsigned short* Kfh = Qfl + (size_t)ELEMS;
    unsigned short* Kfl = Kfh + (size_t)ELEMS;
    unsigned short* Vf  = Kfl + (size_t)ELEMS;
    float* pm   = (float*)(Vf + (size_t)ELEMS);
    float* pl   = pm + (size_t)BB * SPLITS * NSP;       // 640,000 B each
    float* pacc = pl + (size_t)BB * SPLITS * NSP;       // 40,960,000 B
    // xpad aliases pacc: xpad live only before conv3d_k; pacc only after qkv_k
    float* xpad = pacc;                                 // needs 2,725,888 B

    int blocks = (ELEMS + 255) / 256;       // 4000

    pad_k<<<(BB * CIN * PSP + 255) / 256, 256, 0, stream>>>(x, xpad);
    conv3d_k<<<BB * 8 * 32, 256, 0, stream>>>(xpad, conv_w, conv_b, y);
    instnorm_stats_k<<<BB * COUT, 256, 0, stream>>>(y, stats);
    norm_lrelu_k<<<blocks, 256, 0, stream>>>(y, stats, gamma, beta);
    qkv_k<<<BB * 8 * 32, 256, 0, stream>>>(y, wq, bq, wk, bk, wv, bv,
                                           Qfh, Qfl, Kfh, Kfl, Vf);
    attn_pass1_mfma<<<SPLITS * BB * QUADS, 256, 0, stream>>>(Qfh, Qfl, Kfh, Kfl, Vf,
                                                             pm, pl, pacc);
    attn_combine_k<<<blocks, 256, 0, stream>>>(pm, pl, pacc, out);
}

// Round 7
// 196.376 us; speedup vs baseline: 1.4975x; 1.0155x over previous
//
#include <hip/hip_runtime.h>
#include <math.h>

#define CIN   32
#define COUT  64
#define DD    20
#define PD    22        // padded dim
#define PSP   (PD*PD*PD)   // 10648
#define NSP   8000      // 20*20*20
#define BB    2
#define EPSN  1e-5f
#define SLOPE 0.01f

#define NT     250              // 32-row k/q tiles per batch
#define SPLITS 10
#define NKT    (NT / SPLITS)    // 25 k-tiles per split
#define QUADS  63               // ceil(250/4) q-tiles, 4 per block

#define COG 8                   // conv: output channels per thread
#define OG  8                   // qkv: output channels per thread

typedef float  f32x16 __attribute__((ext_vector_type(16)));
typedef short  short8 __attribute__((ext_vector_type(8)));

__device__ __forceinline__ unsigned short f2bf_rne(float x) {
    unsigned u = __float_as_uint(x);
    unsigned r = (u + 0x7FFFu + ((u >> 16) & 1u)) >> 16;
    return (unsigned short)r;
}
__device__ __forceinline__ float bf2f(unsigned short h) {
    return __uint_as_float(((unsigned)h) << 16);
}
__device__ __forceinline__ short8 ld_frag(const unsigned short* p) {
    uint4 t = *reinterpret_cast<const uint4*>(p);
    return __builtin_bit_cast(short8, t);
}
// async global->LDS, 16B per lane; LDS dest is wave-uniform base + lane*16
__device__ __forceinline__ void gload_lds16(const void* gsrc, void* ldst) {
    typedef __attribute__((address_space(1))) const unsigned int GU;
    typedef __attribute__((address_space(3))) unsigned int LU;
    __builtin_amdgcn_global_load_lds((GU*)gsrc, (LU*)ldst, 16, 0, 0);
}

// ---------------- zero-pad x into [B][CIN][22][22][22] ----------------
__global__ void pad_k(const float* __restrict__ x, float* __restrict__ xp) {
    int idx = blockIdx.x * blockDim.x + threadIdx.x;
    if (idx >= BB * CIN * PSP) return;
    int pw = idx % PD;
    int ph = (idx / PD) % PD;
    int pd = (idx / (PD * PD)) % PD;
    int bc = idx / PSP;
    float v = 0.f;
    if (pw >= 1 && pw <= DD && ph >= 1 && ph <= DD && pd >= 1 && pd <= DD)
        v = x[(size_t)bc * NSP + ((size_t)(pd - 1) * DD + (ph - 1)) * DD + (pw - 1)];
    xp[idx] = v;
}

// ---------------- Conv3d k=3 s=1 SAME + bias (padded input, reg-blocked) ----------------
__global__ __launch_bounds__(256) void conv3d_k(const float* __restrict__ xp,
                                                const float* __restrict__ w,
                                                const float* __restrict__ bias,
                                                float* __restrict__ y) {
    int blk = blockIdx.x;
    int vb  = blk & 31;
    int cg  = (blk >> 5) & 7;       // uniform co-group
    int b   = blk >> 8;
    int vox = vb * 256 + threadIdx.x;
    bool valid = vox < NSP;
    int v  = valid ? vox : 0;
    int w_ = v % DD;
    int h_ = (v / DD) % DD;
    int d_ = v / (DD * DD);
    int pvox = ((d_ + 1) * PD + (h_ + 1)) * PD + (w_ + 1);
    const float* xb = xp + (size_t)b * CIN * PSP + pvox;

    float acc[COG];
    #pragma unroll
    for (int j = 0; j < COG; ++j) acc[j] = 0.f;

    for (int ci = 0; ci < CIN; ++ci) {
        const float* xc = xb + (size_t)ci * PSP;
        float xv[27];
        #pragma unroll
        for (int kd = 0; kd < 3; ++kd)
            #pragma unroll
            for (int kh = 0; kh < 3; ++kh)
                #pragma unroll
                for (int kw = 0; kw < 3; ++kw)
                    xv[(kd * 3 + kh) * 3 + kw] =
                        xc[(kd - 1) * (PD * PD) + (kh - 1) * PD + (kw - 1)];
        #pragma unroll
        for (int j = 0; j < COG; ++j) {
            int co = cg * COG + j;                       // uniform
            const float* wr = w + ((size_t)co * CIN + ci) * 27;
            float a = acc[j];
            #pragma unroll
            for (int t = 0; t < 27; ++t) a += xv[t] * wr[t];
            acc[j] = a;
        }
    }
    if (valid) {
        #pragma unroll
        for (int j = 0; j < COG; ++j) {
            int co = cg * COG + j;
            y[((size_t)b * COUT + co) * NSP + vox] = acc[j] + bias[co];
        }
    }
}

// ---------------- InstanceNorm stats: one block per (b,c) ----------------
__global__ void instnorm_stats_k(const float* __restrict__ y, float* __restrict__ stats) {
    int bc = blockIdx.x;                 // 0..127
    const float* yb = y + (size_t)bc * NSP;
    float s = 0.f, ss = 0.f;
    for (int i = threadIdx.x; i < NSP; i += blockDim.x) {
        float v = yb[i];
        s += v; ss += v * v;
    }
    __shared__ float rs[256], rss[256];
    rs[threadIdx.x] = s; rss[threadIdx.x] = ss;
    __syncthreads();
    for (int off = 128; off > 0; off >>= 1) {
        if (threadIdx.x < off) {
            rs[threadIdx.x]  += rs[threadIdx.x + off];
            rss[threadIdx.x] += rss[threadIdx.x + off];
        }
        __syncthreads();
    }
    if (threadIdx.x == 0) {
        float mean = rs[0] / (float)NSP;
        float var  = rss[0] / (float)NSP - mean * mean;
        stats[bc * 2 + 0] = mean;
        stats[bc * 2 + 1] = rsqrtf(var + EPSN);
    }
}

// ---------------- QKV projections (norm+LeakyReLU fused) -> MFMA-fragment layouts ----------------
// Q/K (hi,lo): [b][tile][c(4)][half(2)][row(32)][e(8)]   (4KB contiguous per tile)
// V:           [b][tile][Y(2)][X(2)][half(2)][row(32)][e(8)]
__global__ __launch_bounds__(256) void qkv_k(const float* __restrict__ yraw,
                      const float* __restrict__ stats,
                      const float* __restrict__ gamma, const float* __restrict__ beta,
                      const float* __restrict__ wq, const float* __restrict__ bq,
                      const float* __restrict__ wk, const float* __restrict__ bk,
                      const float* __restrict__ wv, const float* __restrict__ bv,
                      unsigned short* __restrict__ Qfh, unsigned short* __restrict__ Qfl,
                      unsigned short* __restrict__ Kfh, unsigned short* __restrict__ Kfl,
                      unsigned short* __restrict__ Vf) {
    int blk = blockIdx.x;
    int vb  = blk & 31;
    int og  = (blk >> 5) & 7;       // uniform o-group
    int b   = blk >> 8;
    int n   = vb * 256 + threadIdx.x;
    bool valid = n < NSP;
    int nn  = valid ? n : 0;
    const float* fb = yraw + (size_t)b * COUT * NSP + nn;

    float aq[OG], ak[OG], av[OG];
    #pragma unroll
    for (int j = 0; j < OG; ++j) {
        int o = og * OG + j;
        aq[j] = bq[o]; ak[j] = bk[o]; av[j] = bv[o];
    }
    for (int c = 0; c < COUT; ++c) {
        float mean = stats[(b * COUT + c) * 2 + 0];
        float rstd = stats[(b * COUT + c) * 2 + 1];
        float fc = (fb[(size_t)c * NSP] - mean) * rstd * gamma[c] + beta[c];
        fc = fc >= 0.f ? fc : SLOPE * fc;            // LeakyReLU fused
        #pragma unroll
        for (int j = 0; j < OG; ++j) {
            int o = og * OG + j;                         // uniform
            aq[j] += wq[o * COUT + c] * fc;
            ak[j] += wk[o * COUT + c] * fc;
            av[j] += wv[o * COUT + c] * fc;
        }
    }
    if (!valid) return;

    int t  = n >> 5;                // tile
    int kk = n & 31;                // row within tile
    unsigned short qh[OG], ql[OG], kh[OG], kl[OG];
    #pragma unroll
    for (int j = 0; j < OG; ++j) {
        qh[j] = f2bf_rne(aq[j]); ql[j] = f2bf_rne(aq[j] - bf2f(qh[j]));
        kh[j] = f2bf_rne(ak[j]); kl[j] = f2bf_rne(ak[j] - bf2f(kh[j]));
    }
    // Q/K store: c = og>>1, half = og&1
    size_t qko = ((size_t)((b * NT + t) * 4 + (og >> 1)) * 2 + (og & 1)) * 256 + kk * 8;
    *reinterpret_cast<uint4*>(Qfh + qko) = *reinterpret_cast<const uint4*>(qh);
    *reinterpret_cast<uint4*>(Qfl + qko) = *reinterpret_cast<const uint4*>(ql);
    *reinterpret_cast<uint4*>(Kfh + qko) = *reinterpret_cast<const uint4*>(kh);
    *reinterpret_cast<uint4*>(Kfl + qko) = *reinterpret_cast<const uint4*>(kl);
    // V store: Y=kk>>4, half=(kk>>3)&1, e=kk&7 ; X=og>>2, row=(og&3)*8+j
    {
        int Y = kk >> 4, hf = (kk >> 3) & 1, e = kk & 7;
        size_t vbase = ((size_t)((b * NT + t) * 2 + Y) * 2 + (og >> 2)) * 512
                     + hf * 256 + e;
        #pragma unroll
        for (int j = 0; j < OG; ++j)
            Vf[vbase + ((og & 3) * 8 + j) * 8] = f2bf_rne(av[j]);
    }
}

// ---------------- flash attention pass 1: MFMA + distance-2 LDS pipeline ----------------
// 3 LDS buffers; counted vmcnt(3) (never drain in-loop), raw s_barrier (no implicit drain).
__global__ __launch_bounds__(256, 3) void attn_pass1_mfma(
        const unsigned short* __restrict__ Qfh, const unsigned short* __restrict__ Qfl,
        const unsigned short* __restrict__ Kfh, const unsigned short* __restrict__ Kfl,
        const unsigned short* __restrict__ Vf,
        float* __restrict__ pm, float* __restrict__ pl, float* __restrict__ pacc) {
    int bid   = blockIdx.x;
    int split = bid / (BB * QUADS);         // split-major: co-resident share K/V window
    int rem   = bid % (BB * QUADS);
    int b     = rem / QUADS;
    int quad  = rem % QUADS;
    int wave  = threadIdx.x >> 6;
    int lane  = threadIdx.x & 63;
    int col   = lane & 31;
    int half  = lane >> 5;
    int qt    = quad * 4 + wave;
    bool qvalid = qt < NT;
    int qtc   = qvalid ? qt : NT - 1;
    int bNT   = b * NT;

    __shared__ __align__(16) char ldsbuf[3][12288];   // [Kh 4K | Kl 4K | V 4K] x3

    // Q fragments: contiguous 1KB per c-chunk
    short8 qfh[4], qfl[4];
    {
        const unsigned short* qp  = Qfh + (size_t)(bNT + qtc) * 2048 + lane * 8;
        const unsigned short* qp2 = Qfl + (size_t)(bNT + qtc) * 2048 + lane * 8;
        #pragma unroll
        for (int c = 0; c < 4; ++c) {
            qfh[c] = ld_frag(qp  + c * 512);
            qfl[c] = ld_frag(qp2 + c * 512);
        }
    }

    int wo = wave * 1024;           // this wave's 1KB slice of each 4KB chunk
    int go = wo + lane * 16;        // byte offset into the tile's 4KB chunk

    auto STAGE = [&](int bufi, int tg) {
        size_t tb = (size_t)(bNT + tg) * 2048;     // elements (=4096 B)
        char* l = &ldsbuf[bufi][0];
        gload_lds16((const char*)(Kfh + tb) + go, l + wo);
        gload_lds16((const char*)(Kfl + tb) + go, l + 4096 + wo);
        gload_lds16((const char*)(Vf  + tb) + go, l + 8192 + wo);
    };

    f32x16 oacc0 = {};
    f32x16 oacc1 = {};
    float m = -3e38f, lsum = 0.f;

    int t0g = split * NKT;
    STAGE(0, t0g);                   // prologue: stage tiles 0 and 1
    STAGE(1, t0g + 1);

    for (int t = 0; t < NKT; ++t) {
        // wait for stage(t): 3 newer loads (stage(t+1)) may stay in flight
        if (t == NKT - 1) { asm volatile("s_waitcnt vmcnt(0)" ::: "memory"); }
        else              { asm volatile("s_waitcnt vmcnt(3)" ::: "memory"); }
        __builtin_amdgcn_sched_barrier(0);
        __builtin_amdgcn_s_barrier();          // raw: no implicit vmcnt drain
        __builtin_amdgcn_sched_barrier(0);
        if (t + 2 < NKT) STAGE((t + 2) % 3, t0g + t + 2);

        const unsigned short* lk  = (const unsigned short*)&ldsbuf[t % 3][0];
        const unsigned short* lkl = (const unsigned short*)&ldsbuf[t % 3][4096];
        const unsigned short* lv  = (const unsigned short*)&ldsbuf[t % 3][8192];

        // QK^T: S^T = K.Q^T (3-term hi/lo product)
        f32x16 s = {};
        __builtin_amdgcn_s_setprio(1);
        #pragma unroll
        for (int c = 0; c < 4; ++c) {
            short8 kfh = ld_frag(lk  + c * 512 + lane * 8);
            short8 kfl = ld_frag(lkl + c * 512 + lane * 8);
            s = __builtin_amdgcn_mfma_f32_32x32x16_bf16(kfh, qfh[c], s, 0, 0, 0);
            s = __builtin_amdgcn_mfma_f32_32x32x16_bf16(kfh, qfl[c], s, 0, 0, 0);
            s = __builtin_amdgcn_mfma_f32_32x32x16_bf16(kfl, qfh[c], s, 0, 0, 0);
        }
        __builtin_amdgcn_s_setprio(0);
        // tree max over 16 + cross-half
        float t8[8];
        #pragma unroll
        for (int r = 0; r < 8; ++r) t8[r] = fmaxf(s[r], s[r + 8]);
        float t4a = fmaxf(t8[0], t8[1]), t4b = fmaxf(t8[2], t8[3]);
        float t4c = fmaxf(t8[4], t8[5]), t4d = fmaxf(t8[6], t8[7]);
        float tmax = fmaxf(fmaxf(t4a, t4b), fmaxf(t4c, t4d));
        tmax = fmaxf(tmax, __shfl_xor(tmax, 32, 64));
        // T13 defer-rescale
        if (__any(tmax > m + 8.f)) {
            float newm  = fmaxf(m, tmax);
            float scale = __expf(m - newm);
            lsum *= scale;
            #pragma unroll
            for (int r = 0; r < 16; ++r) { oacc0[r] *= scale; oacc1[r] *= scale; }
            m = newm;
        }
        // P in two groups of 8 (regs) -> bf16 B-fragments via cvt_pk + half-exchange
        short8 pf0, pf1;
        float ls;
        {
            float p[8];
            #pragma unroll
            for (int r = 0; r < 8; ++r) p[r] = __expf(s[r] - m);
            ls = ((p[0] + p[1]) + (p[2] + p[3])) + ((p[4] + p[5]) + (p[6] + p[7]));
            unsigned W[4], X[4];
            #pragma unroll
            for (int j = 0; j < 4; ++j)
                asm("v_cvt_pk_bf16_f32 %0, %1, %2" : "=v"(W[j]) : "v"(p[2 * j]), "v"(p[2 * j + 1]));
            #pragma unroll
            for (int j = 0; j < 4; ++j) X[j] = (unsigned)__shfl_xor((int)W[j], 32, 64);
            uint4 u = half ? make_uint4(X[2], X[3], W[2], W[3])
                           : make_uint4(W[0], W[1], X[0], X[1]);
            pf0 = __builtin_bit_cast(short8, u);
        }
        {
            float p[8];
            #pragma unroll
            for (int r = 0; r < 8; ++r) p[r] = __expf(s[r + 8] - m);
            ls += ((p[0] + p[1]) + (p[2] + p[3])) + ((p[4] + p[5]) + (p[6] + p[7]));
            unsigned W[4], X[4];
            #pragma unroll
            for (int j = 0; j < 4; ++j)
                asm("v_cvt_pk_bf16_f32 %0, %1, %2" : "=v"(W[j]) : "v"(p[2 * j]), "v"(p[2 * j + 1]));
            #pragma unroll
            for (int j = 0; j < 4; ++j) X[j] = (unsigned)__shfl_xor((int)W[j], 32, 64);
            uint4 u = half ? make_uint4(X[2], X[3], W[2], W[3])
                           : make_uint4(W[0], W[1], X[0], X[1]);
            pf1 = __builtin_bit_cast(short8, u);
        }
        lsum += ls;
        // PV: O^T = V^T.P^T  (X -> oacc, Y -> pf)
        {
            short8 v00 = ld_frag(lv + 0 * 512 + lane * 8);   // Y0 X0
            short8 v10 = ld_frag(lv + 1 * 512 + lane * 8);   // Y0 X1
            __builtin_amdgcn_s_setprio(1);
            oacc0 = __builtin_amdgcn_mfma_f32_32x32x16_bf16(v00, pf0, oacc0, 0, 0, 0);
            oacc1 = __builtin_amdgcn_mfma_f32_32x32x16_bf16(v10, pf0, oacc1, 0, 0, 0);
            __builtin_amdgcn_s_setprio(0);
            short8 v01 = ld_frag(lv + 2 * 512 + lane * 8);   // Y1 X0
            short8 v11 = ld_frag(lv + 3 * 512 + lane * 8);   // Y1 X1
            __builtin_amdgcn_s_setprio(1);
            oacc0 = __builtin_amdgcn_mfma_f32_32x32x16_bf16(v01, pf1, oacc0, 0, 0, 0);
            oacc1 = __builtin_amdgcn_mfma_f32_32x32x16_bf16(v11, pf1, oacc1, 0, 0, 0);
            __builtin_amdgcn_s_setprio(0);
        }
    }

    if (!qvalid) return;
    int q0 = qt * 32;
    float lfull = lsum + __shfl_xor(lsum, 32, 64);
    size_t base = (size_t)b * SPLITS + split;
    if (lane < 32) {
        pm[base * NSP + q0 + col] = m;
        pl[base * NSP + q0 + col] = lfull;
    }
    float* pa = pacc + base * (size_t)(COUT * NSP) + q0 + col;
    #pragma unroll
    for (int r = 0; r < 16; ++r) {
        int crow = (r & 3) + 8 * (r >> 2) + 4 * half;
        pa[(size_t)crow * NSP]        = oacc0[r];
        pa[(size_t)(crow + 32) * NSP] = oacc1[r];
    }
}

// ---------------- combine split-K partials ----------------
__global__ void attn_combine_k(const float* __restrict__ pm, const float* __restrict__ pl,
                               const float* __restrict__ pacc, float* __restrict__ out) {
    int idx = blockIdx.x * blockDim.x + threadIdx.x;   // over B*COUT*NSP
    if (idx >= BB * COUT * NSP) return;
    int n = idx % NSP;
    int c = (idx / NSP) % COUT;
    int b = idx / (NSP * COUT);
    float M = -1e30f;
    #pragma unroll
    for (int j = 0; j < SPLITS; ++j)
        M = fmaxf(M, pm[((size_t)b * SPLITS + j) * NSP + n]);
    float L = 0.f, O = 0.f;
    #pragma unroll
    for (int j = 0; j < SPLITS; ++j) {
        size_t base = (size_t)b * SPLITS + j;
        float wgt = __expf(pm[base * NSP + n] - M);
        L += pl[base * NSP + n] * wgt;
        O += pacc[(base * COUT + c) * NSP + n] * wgt;
    }
    out[idx] = O / L;
}

// ---------------- launch ----------------
extern "C" void kernel_launch(void* const* d_in, const int* in_sizes, int n_in,
                              void* d_out, int out_size, void* d_ws, size_t ws_size,
                              hipStream_t stream) {
    const float* x      = (const float*)d_in[0];
    const float* conv_w = (const float*)d_in[1];
    const float* conv_b = (const float*)d_in[2];
    const float* gamma  = (const float*)d_in[3];
    const float* beta   = (const float*)d_in[4];
    const float* wq     = (const float*)d_in[5];
    const float* bq     = (const float*)d_in[6];
    const float* wk     = (const float*)d_in[7];
    const float* bk     = (const float*)d_in[8];
    const float* wv     = (const float*)d_in[9];
    const float* bv     = (const float*)d_in[10];
    float* out = (float*)d_out;

    const int ELEMS = BB * COUT * NSP;      // 1,024,000
    char* w8 = (char*)d_ws;
    float* y     = (float*)w8;                          // 4,096,000 B
    float* stats = (float*)(w8 + 4096000);              // 1,024 B
    unsigned short* Qfh = (unsigned short*)(w8 + 4097024);
    unsigned short* Qfl = Qfh + (size_t)ELEMS;          // each 2,048,000 B
    unsigned short* Kfh = Qfl + (size_t)ELEMS;
    unsigned short* Kfl = Kfh + (size_t)ELEMS;
    unsigned short* Vf  = Kfl + (size_t)ELEMS;
    float* pm   = (float*)(Vf + (size_t)ELEMS);
    float* pl   = pm + (size_t)BB * SPLITS * NSP;       // 640,000 B each
    float* pacc = pl + (size_t)BB * SPLITS * NSP;       // 40,960,000 B
    // xpad aliases pacc: xpad live only before conv3d_k; pacc only after qkv_k
    float* xpad = pacc;                                 // needs 2,725,888 B

    pad_k<<<(BB * CIN * PSP + 255) / 256, 256, 0, stream>>>(x, xpad);
    conv3d_k<<<BB * 8 * 32, 256, 0, stream>>>(xpad, conv_w, conv_b, y);
    instnorm_stats_k<<<BB * COUT, 256, 0, stream>>>(y, stats);
    qkv_k<<<BB * 8 * 32, 256, 0, stream>>>(y, stats, gamma, beta,
                                           wq, bq, wk, bk, wv, bv,
                                           Qfh, Qfl, Kfh, Kfl, Vf);
    attn_pass1_mfma<<<SPLITS * BB * QUADS, 256, 0, stream>>>(Qfh, Qfl, Kfh, Kfl, Vf,
                                                             pm, pl, pacc);
    attn_combine_k<<<(ELEMS + 255) / 256, 256, 0, stream>>>(pm, pl, pacc, out);
}

// Round 9
// 196.261 us; speedup vs baseline: 1.4984x; 1.0006x over previous
//
#include <hip/hip_runtime.h>
#include <math.h>

#define CIN   32
#define COUT  64
#define DD    20
#define PD    22        // padded dim
#define PSP   (PD*PD*PD)   // 10648
#define NSP   8000      // 20*20*20
#define BB    2
#define EPSN  1e-5f
#define SLOPE 0.01f

#define NT     250              // 32-row k/q tiles per batch
#define SPLITS 10
#define NKT    (NT / SPLITS)    // 25 k-tiles per split
#define QUADS  63               // ceil(250/4) q-tiles, 4 per block

#define COG 8                   // conv: output channels per thread
#define OG  8                   // qkv: output channels per thread

typedef float  f32x16 __attribute__((ext_vector_type(16)));
typedef short  short8 __attribute__((ext_vector_type(8)));

__device__ __forceinline__ unsigned short f2bf_rne(float x) {
    unsigned u = __float_as_uint(x);
    unsigned r = (u + 0x7FFFu + ((u >> 16) & 1u)) >> 16;
    return (unsigned short)r;
}
__device__ __forceinline__ float bf2f(unsigned short h) {
    return __uint_as_float(((unsigned)h) << 16);
}
__device__ __forceinline__ short8 ld_frag(const unsigned short* p) {
    uint4 t = *reinterpret_cast<const uint4*>(p);
    return __builtin_bit_cast(short8, t);
}
// async global->LDS, 16B per lane; LDS dest is wave-uniform base + lane*16
__device__ __forceinline__ void gload_lds16(const void* gsrc, void* ldst) {
    typedef __attribute__((address_space(1))) const unsigned int GU;
    typedef __attribute__((address_space(3))) unsigned int LU;
    __builtin_amdgcn_global_load_lds((GU*)gsrc, (LU*)ldst, 16, 0, 0);
}

// ---------------- zero-pad x into [B][CIN][22][22][22] ----------------
__global__ void pad_k(const float* __restrict__ x, float* __restrict__ xp) {
    int idx = blockIdx.x * blockDim.x + threadIdx.x;
    if (idx >= BB * CIN * PSP) return;
    int pw = idx % PD;
    int ph = (idx / PD) % PD;
    int pd = (idx / (PD * PD)) % PD;
    int bc = idx / PSP;
    float v = 0.f;
    if (pw >= 1 && pw <= DD && ph >= 1 && ph <= DD && pd >= 1 && pd <= DD)
        v = x[(size_t)bc * NSP + ((size_t)(pd - 1) * DD + (ph - 1)) * DD + (pw - 1)];
    xp[idx] = v;
}

// ---------------- Conv3d k=3 s=1 SAME + bias (padded input, reg-blocked) ----------------
__global__ __launch_bounds__(256) void conv3d_k(const float* __restrict__ xp,
                                                const float* __restrict__ w,
                                                const float* __restrict__ bias,
                                                float* __restrict__ y) {
    int blk = blockIdx.x;
    int vb  = blk & 31;
    int cg  = (blk >> 5) & 7;       // uniform co-group
    int b   = blk >> 8;
    int vox = vb * 256 + threadIdx.x;
    bool valid = vox < NSP;
    int v  = valid ? vox : 0;
    int w_ = v % DD;
    int h_ = (v / DD) % DD;
    int d_ = v / (DD * DD);
    int pvox = ((d_ + 1) * PD + (h_ + 1)) * PD + (w_ + 1);
    const float* xb = xp + (size_t)b * CIN * PSP + pvox;

    float acc[COG];
    #pragma unroll
    for (int j = 0; j < COG; ++j) acc[j] = 0.f;

    for (int ci = 0; ci < CIN; ++ci) {
        const float* xc = xb + (size_t)ci * PSP;
        float xv[27];
        #pragma unroll
        for (int kd = 0; kd < 3; ++kd)
            #pragma unroll
            for (int kh = 0; kh < 3; ++kh)
                #pragma unroll
                for (int kw = 0; kw < 3; ++kw)
                    xv[(kd * 3 + kh) * 3 + kw] =
                        xc[(kd - 1) * (PD * PD) + (kh - 1) * PD + (kw - 1)];
        #pragma unroll
        for (int j = 0; j < COG; ++j) {
            int co = cg * COG + j;                       // uniform
            const float* wr = w + ((size_t)co * CIN + ci) * 27;
            float a = acc[j];
            #pragma unroll
            for (int t = 0; t < 27; ++t) a += xv[t] * wr[t];
            acc[j] = a;
        }
    }
    if (valid) {
        #pragma unroll
        for (int j = 0; j < COG; ++j) {
            int co = cg * COG + j;
            y[((size_t)b * COUT + co) * NSP + vox] = acc[j] + bias[co];
        }
    }
}

// ---------------- InstanceNorm stats: one block per (b,c) ----------------
__global__ void instnorm_stats_k(const float* __restrict__ y, float* __restrict__ stats) {
    int bc = blockIdx.x;                 // 0..127
    const float* yb = y + (size_t)bc * NSP;
    float s = 0.f, ss = 0.f;
    for (int i = threadIdx.x; i < NSP; i += blockDim.x) {
        float v = yb[i];
        s += v; ss += v * v;
    }
    __shared__ float rs[256], rss[256];
    rs[threadIdx.x] = s; rss[threadIdx.x] = ss;
    __syncthreads();
    for (int off = 128; off > 0; off >>= 1) {
        if (threadIdx.x < off) {
            rs[threadIdx.x]  += rs[threadIdx.x + off];
            rss[threadIdx.x] += rss[threadIdx.x + off];
        }
        __syncthreads();
    }
    if (threadIdx.x == 0) {
        float mean = rs[0] / (float)NSP;
        float var  = rss[0] / (float)NSP - mean * mean;
        stats[bc * 2 + 0] = mean;
        stats[bc * 2 + 1] = rsqrtf(var + EPSN);
    }
}

// ---------------- QKV projections (norm+LeakyReLU fused) -> MFMA-fragment layouts ----------------
// Q/K (hi,lo): [b][tile][c(4)][half(2)][row(32)][e(8)]   (4KB contiguous per tile)
// V:           [b][tile][Y(2)][X(2)][half(2)][row(32)][e(8)]
__global__ __launch_bounds__(256) void qkv_k(const float* __restrict__ yraw,
                      const float* __restrict__ stats,
                      const float* __restrict__ gamma, const float* __restrict__ beta,
                      const float* __restrict__ wq, const float* __restrict__ bq,
                      const float* __restrict__ wk, const float* __restrict__ bk,
                      const float* __restrict__ wv, const float* __restrict__ bv,
                      unsigned short* __restrict__ Qfh, unsigned short* __restrict__ Qfl,
                      unsigned short* __restrict__ Kfh, unsigned short* __restrict__ Kfl,
                      unsigned short* __restrict__ Vf) {
    int blk = blockIdx.x;
    int vb  = blk & 31;
    int og  = (blk >> 5) & 7;       // uniform o-group
    int b   = blk >> 8;
    int n   = vb * 256 + threadIdx.x;
    bool valid = n < NSP;
    int nn  = valid ? n : 0;
    const float* fb = yraw + (size_t)b * COUT * NSP + nn;

    float aq[OG], ak[OG], av[OG];
    #pragma unroll
    for (int j = 0; j < OG; ++j) {
        int o = og * OG + j;
        aq[j] = bq[o]; ak[j] = bk[o]; av[j] = bv[o];
    }
    for (int c = 0; c < COUT; ++c) {
        float mean = stats[(b * COUT + c) * 2 + 0];
        float rstd = stats[(b * COUT + c) * 2 + 1];
        float fc = (fb[(size_t)c * NSP] - mean) * rstd * gamma[c] + beta[c];
        fc = fc >= 0.f ? fc : SLOPE * fc;            // LeakyReLU fused
        #pragma unroll
        for (int j = 0; j < OG; ++j) {
            int o = og * OG + j;                         // uniform
            aq[j] += wq[o * COUT + c] * fc;
            ak[j] += wk[o * COUT + c] * fc;
            av[j] += wv[o * COUT + c] * fc;
        }
    }
    if (!valid) return;

    int t  = n >> 5;                // tile
    int kk = n & 31;                // row within tile
    unsigned short qh[OG], ql[OG], kh[OG], kl[OG];
    #pragma unroll
    for (int j = 0; j < OG; ++j) {
        qh[j] = f2bf_rne(aq[j]); ql[j] = f2bf_rne(aq[j] - bf2f(qh[j]));
        kh[j] = f2bf_rne(ak[j]); kl[j] = f2bf_rne(ak[j] - bf2f(kh[j]));
    }
    // Q/K store: c = og>>1, half = og&1
    size_t qko = ((size_t)((b * NT + t) * 4 + (og >> 1)) * 2 + (og & 1)) * 256 + kk * 8;
    *reinterpret_cast<uint4*>(Qfh + qko) = *reinterpret_cast<const uint4*>(qh);
    *reinterpret_cast<uint4*>(Qfl + qko) = *reinterpret_cast<const uint4*>(ql);
    *reinterpret_cast<uint4*>(Kfh + qko) = *reinterpret_cast<const uint4*>(kh);
    *reinterpret_cast<uint4*>(Kfl + qko) = *reinterpret_cast<const uint4*>(kl);
    // V store: Y=kk>>4, half=(kk>>3)&1, e=kk&7 ; X=og>>2, row=(og&3)*8+j
    {
        int Y = kk >> 4, hf = (kk >> 3) & 1, e = kk & 7;
        size_t vbase = ((size_t)((b * NT + t) * 2 + Y) * 2 + (og >> 2)) * 512
                     + hf * 256 + e;
        #pragma unroll
        for (int j = 0; j < OG; ++j)
            Vf[vbase + ((og & 3) * 8 + j) * 8] = f2bf_rne(av[j]);
    }
}

// ---------------- flash attention pass 1: MFMA + distance-2 LDS pipeline ----------------
// 3 LDS buffers; counted vmcnt(3) (never drain in-loop), raw s_barrier (no implicit drain).
// launch_bounds (256,4): target 4 waves/SIMD (total regs must fit 128/wave).
__global__ __launch_bounds__(256, 4) void attn_pass1_mfma(
        const unsigned short* __restrict__ Qfh, const unsigned short* __restrict__ Qfl,
        const unsigned short* __restrict__ Kfh, const unsigned short* __restrict__ Kfl,
        const unsigned short* __restrict__ Vf,
        float* __restrict__ pm, float* __restrict__ pl, float* __restrict__ pacc) {
    int bid   = blockIdx.x;
    int split = bid / (BB * QUADS);         // split-major: co-resident share K/V window
    int rem   = bid % (BB * QUADS);
    int b     = rem / QUADS;
    int quad  = rem % QUADS;
    int wave  = threadIdx.x >> 6;
    int lane  = threadIdx.x & 63;
    int col   = lane & 31;
    int half  = lane >> 5;
    int qt    = quad * 4 + wave;
    bool qvalid = qt < NT;
    int qtc   = qvalid ? qt : NT - 1;
    int bNT   = b * NT;

    __shared__ __align__(16) char ldsbuf[3][12288];   // [Kh 4K | Kl 4K | V 4K] x3

    // Q fragments: contiguous 1KB per c-chunk
    short8 qfh[4], qfl[4];
    {
        const unsigned short* qp  = Qfh + (size_t)(bNT + qtc) * 2048 + lane * 8;
        const unsigned short* qp2 = Qfl + (size_t)(bNT + qtc) * 2048 + lane * 8;
        #pragma unroll
        for (int c = 0; c < 4; ++c) {
            qfh[c] = ld_frag(qp  + c * 512);
            qfl[c] = ld_frag(qp2 + c * 512);
        }
    }

    int wo = wave * 1024;           // this wave's 1KB slice of each 4KB chunk
    int go = wo + lane * 16;        // byte offset into the tile's 4KB chunk

    auto STAGE = [&](int bufi, int tg) {
        size_t tb = (size_t)(bNT + tg) * 2048;     // elements (=4096 B)
        char* l = &ldsbuf[bufi][0];
        gload_lds16((const char*)(Kfh + tb) + go, l + wo);
        gload_lds16((const char*)(Kfl + tb) + go, l + 4096 + wo);
        gload_lds16((const char*)(Vf  + tb) + go, l + 8192 + wo);
    };

    f32x16 oacc0 = {};
    f32x16 oacc1 = {};
    float m = -3e38f, lsum = 0.f;

    int t0g = split * NKT;
    STAGE(0, t0g);                   // prologue: stage tiles 0 and 1
    STAGE(1, t0g + 1);

    for (int t = 0; t < NKT; ++t) {
        // wait for stage(t): 3 newer loads (stage(t+1)) may stay in flight
        if (t == NKT - 1) { asm volatile("s_waitcnt vmcnt(0)" ::: "memory"); }
        else              { asm volatile("s_waitcnt vmcnt(3)" ::: "memory"); }
        __builtin_amdgcn_sched_barrier(0);
        __builtin_amdgcn_s_barrier();          // raw: no implicit vmcnt drain
        __builtin_amdgcn_sched_barrier(0);
        if (t + 2 < NKT) STAGE((t + 2) % 3, t0g + t + 2);

        const unsigned short* lk  = (const unsigned short*)&ldsbuf[t % 3][0];
        const unsigned short* lkl = (const unsigned short*)&ldsbuf[t % 3][4096];
        const unsigned short* lv  = (const unsigned short*)&ldsbuf[t % 3][8192];

        // QK^T: S^T = K.Q^T (3-term hi/lo product)
        f32x16 s = {};
        __builtin_amdgcn_s_setprio(1);
        #pragma unroll
        for (int c = 0; c < 4; ++c) {
            short8 kfh = ld_frag(lk  + c * 512 + lane * 8);
            short8 kfl = ld_frag(lkl + c * 512 + lane * 8);
            s = __builtin_amdgcn_mfma_f32_32x32x16_bf16(kfh, qfh[c], s, 0, 0, 0);
            s = __builtin_amdgcn_mfma_f32_32x32x16_bf16(kfh, qfl[c], s, 0, 0, 0);
            s = __builtin_amdgcn_mfma_f32_32x32x16_bf16(kfl, qfh[c], s, 0, 0, 0);
        }
        __builtin_amdgcn_s_setprio(0);
        // tree max over 16 + cross-half
        float t8[8];
        #pragma unroll
        for (int r = 0; r < 8; ++r) t8[r] = fmaxf(s[r], s[r + 8]);
        float t4a = fmaxf(t8[0], t8[1]), t4b = fmaxf(t8[2], t8[3]);
        float t4c = fmaxf(t8[4], t8[5]), t4d = fmaxf(t8[6], t8[7]);
        float tmax = fmaxf(fmaxf(t4a, t4b), fmaxf(t4c, t4d));
        tmax = fmaxf(tmax, __shfl_xor(tmax, 32, 64));
        // T13 defer-rescale
        if (__any(tmax > m + 8.f)) {
            float newm  = fmaxf(m, tmax);
            float scale = __expf(m - newm);
            lsum *= scale;
            #pragma unroll
            for (int r = 0; r < 16; ++r) { oacc0[r] *= scale; oacc1[r] *= scale; }
            m = newm;
        }
        // P in two groups of 8 (regs) -> bf16 B-fragments via cvt_pk + half-exchange
        short8 pf0, pf1;
        float ls;
        {
            float p[8];
            #pragma unroll
            for (int r = 0; r < 8; ++r) p[r] = __expf(s[r] - m);
            ls = ((p[0] + p[1]) + (p[2] + p[3])) + ((p[4] + p[5]) + (p[6] + p[7]));
            unsigned W[4], X[4];
            #pragma unroll
            for (int j = 0; j < 4; ++j)
                asm("v_cvt_pk_bf16_f32 %0, %1, %2" : "=v"(W[j]) : "v"(p[2 * j]), "v"(p[2 * j + 1]));
            #pragma unroll
            for (int j = 0; j < 4; ++j) X[j] = (unsigned)__shfl_xor((int)W[j], 32, 64);
            uint4 u = half ? make_uint4(X[2], X[3], W[2], W[3])
                           : make_uint4(W[0], W[1], X[0], X[1]);
            pf0 = __builtin_bit_cast(short8, u);
        }
        {
            float p[8];
            #pragma unroll
            for (int r = 0; r < 8; ++r) p[r] = __expf(s[r + 8] - m);
            ls += ((p[0] + p[1]) + (p[2] + p[3])) + ((p[4] + p[5]) + (p[6] + p[7]));
            unsigned W[4], X[4];
            #pragma unroll
            for (int j = 0; j < 4; ++j)
                asm("v_cvt_pk_bf16_f32 %0, %1, %2" : "=v"(W[j]) : "v"(p[2 * j]), "v"(p[2 * j + 1]));
            #pragma unroll
            for (int j = 0; j < 4; ++j) X[j] = (unsigned)__shfl_xor((int)W[j], 32, 64);
            uint4 u = half ? make_uint4(X[2], X[3], W[2], W[3])
                           : make_uint4(W[0], W[1], X[0], X[1]);
            pf1 = __builtin_bit_cast(short8, u);
        }
        lsum += ls;
        // PV: O^T = V^T.P^T  (X -> oacc, Y -> pf)
        {
            short8 v00 = ld_frag(lv + 0 * 512 + lane * 8);   // Y0 X0
            short8 v10 = ld_frag(lv + 1 * 512 + lane * 8);   // Y0 X1
            __builtin_amdgcn_s_setprio(1);
            oacc0 = __builtin_amdgcn_mfma_f32_32x32x16_bf16(v00, pf0, oacc0, 0, 0, 0);
            oacc1 = __builtin_amdgcn_mfma_f32_32x32x16_bf16(v10, pf0, oacc1, 0, 0, 0);
            __builtin_amdgcn_s_setprio(0);
            short8 v01 = ld_frag(lv + 2 * 512 + lane * 8);   // Y1 X0
            short8 v11 = ld_frag(lv + 3 * 512 + lane * 8);   // Y1 X1
            __builtin_amdgcn_s_setprio(1);
            oacc0 = __builtin_amdgcn_mfma_f32_32x32x16_bf16(v01, pf1, oacc0, 0, 0, 0);
            oacc1 = __builtin_amdgcn_mfma_f32_32x32x16_bf16(v11, pf1, oacc1, 0, 0, 0);
            __builtin_amdgcn_s_setprio(0);
        }
    }

    if (!qvalid) return;
    int q0 = qt * 32;
    float lfull = lsum + __shfl_xor(lsum, 32, 64);
    size_t base = (size_t)b * SPLITS + split;
    if (lane < 32) {
        pm[base * NSP + q0 + col] = m;
        pl[base * NSP + q0 + col] = lfull;
    }
    float* pa = pacc + base * (size_t)(COUT * NSP) + q0 + col;
    #pragma unroll
    for (int r = 0; r < 16; ++r) {
        int crow = (r & 3) + 8 * (r >> 2) + 4 * half;
        pa[(size_t)crow * NSP]        = oacc0[r];
        pa[(size_t)(crow + 32) * NSP] = oacc1[r];
    }
}

// ---------------- combine split-K partials ----------------
__global__ void attn_combine_k(const float* __restrict__ pm, const float* __restrict__ pl,
                               const float* __restrict__ pacc, float* __restrict__ out) {
    int idx = blockIdx.x * blockDim.x + threadIdx.x;   // over B*COUT*NSP
    if (idx >= BB * COUT * NSP) return;
    int n = idx % NSP;
    int c = (idx / NSP) % COUT;
    int b = idx / (NSP * COUT);
    float M = -1e30f;
    #pragma unroll
    for (int j = 0; j < SPLITS; ++j)
        M = fmaxf(M, pm[((size_t)b * SPLITS + j) * NSP + n]);
    float L = 0.f, O = 0.f;
    #pragma unroll
    for (int j = 0; j < SPLITS; ++j) {
        size_t base = (size_t)b * SPLITS + j;
        float wgt = __expf(pm[base * NSP + n] - M);
        L += pl[base * NSP + n] * wgt;
        O += pacc[(base * COUT + c) * NSP + n] * wgt;
    }
    out[idx] = O / L;
}

// ---------------- launch ----------------
extern "C" void kernel_launch(void* const* d_in, const int* in_sizes, int n_in,
                              void* d_out, int out_size, void* d_ws, size_t ws_size,
                              hipStream_t stream) {
    const float* x      = (const float*)d_in[0];
    const float* conv_w = (const float*)d_in[1];
    const float* conv_b = (const float*)d_in[2];
    const float* gamma  = (const float*)d_in[3];
    const float* beta   = (const float*)d_in[4];
    const float* wq     = (const float*)d_in[5];
    const float* bq     = (const float*)d_in[6];
    const float* wk     = (const float*)d_in[7];
    const float* bk     = (const float*)d_in[8];
    const float* wv     = (const float*)d_in[9];
    const float* bv     = (const float*)d_in[10];
    float* out = (float*)d_out;

    const int ELEMS = BB * COUT * NSP;      // 1,024,000
    char* w8 = (char*)d_ws;
    float* y     = (float*)w8;                          // 4,096,000 B
    float* stats = (float*)(w8 + 4096000);              // 1,024 B
    unsigned short* Qfh = (unsigned short*)(w8 + 4097024);
    unsigned short* Qfl = Qfh + (size_t)ELEMS;          // each 2,048,000 B
    unsigned short* Kfh = Qfl + (size_t)ELEMS;
    unsigned short* Kfl = Kfh + (size_t)ELEMS;
    unsigned short* Vf  = Kfl + (size_t)ELEMS;
    float* pm   = (float*)(Vf + (size_t)ELEMS);
    float* pl   = pm + (size_t)BB * SPLITS * NSP;       // 640,000 B each
    float* pacc = pl + (size_t)BB * SPLITS * NSP;       // 40,960,000 B
    // xpad aliases pacc: xpad live only before conv3d_k; pacc only after qkv_k
    float* xpad = pacc;                                 // needs 2,725,888 B

    pad_k<<<(BB * CIN * PSP + 255) / 256, 256, 0, stream>>>(x, xpad);
    conv3d_k<<<BB * 8 * 32, 256, 0, stream>>>(xpad, conv_w, conv_b, y);
    instnorm_stats_k<<<BB * COUT, 256, 0, stream>>>(y, stats);
    qkv_k<<<BB * 8 * 32, 256, 0, stream>>>(y, stats, gamma, beta,
                                           wq, bq, wk, bk, wv, bv,
                                           Qfh, Qfl, Kfh, Kfl, Vf);
    attn_pass1_mfma<<<SPLITS * BB * QUADS, 256, 0, stream>>>(Qfh, Qfl, Kfh, Kfl, Vf,
                                                             pm, pl, pacc);
    attn_combine_k<<<(ELEMS + 255) / 256, 256, 0, stream>>>(pm, pl, pacc, out);
}

// Round 10
// 156.838 us; speedup vs baseline: 1.8750x; 1.2514x over previous
//
#include <hip/hip_runtime.h>
#include <math.h>

#define CIN   32
#define COUT  64
#define DD    20
#define PD    22        // padded dim
#define PSP   (PD*PD*PD)   // 10648
#define NSP   8000      // 20*20*20
#define BB    2
#define EPSN  1e-5f
#define SLOPE 0.01f

#define NT     250              // 32-row k/q tiles per batch
#define SPLITS 10
#define NKT    (NT / SPLITS)    // 25 k-tiles per split
#define QUADS  63               // ceil(250/4) q-tiles, 4 per block

#define COG 4                   // conv: output channels per thread (4 -> 1024 blocks)
#define OG  8                   // qkv: output channels per thread

typedef float  f32x16 __attribute__((ext_vector_type(16)));
typedef short  short8 __attribute__((ext_vector_type(8)));

__device__ __forceinline__ unsigned short f2bf_rne(float x) {
    unsigned u = __float_as_uint(x);
    unsigned r = (u + 0x7FFFu + ((u >> 16) & 1u)) >> 16;
    return (unsigned short)r;
}
__device__ __forceinline__ float bf2f(unsigned short h) {
    return __uint_as_float(((unsigned)h) << 16);
}
__device__ __forceinline__ short8 ld_frag(const unsigned short* p) {
    uint4 t = *reinterpret_cast<const uint4*>(p);
    return __builtin_bit_cast(short8, t);
}
// async global->LDS, 16B per lane; LDS dest is wave-uniform base + lane*16
__device__ __forceinline__ void gload_lds16(const void* gsrc, void* ldst) {
    typedef __attribute__((address_space(1))) const unsigned int GU;
    typedef __attribute__((address_space(3))) unsigned int LU;
    __builtin_amdgcn_global_load_lds((GU*)gsrc, (LU*)ldst, 16, 0, 0);
}

// ---------------- zero-pad x into [B][CIN][22][22][22] ----------------
__global__ void pad_k(const float* __restrict__ x, float* __restrict__ xp) {
    int idx = blockIdx.x * blockDim.x + threadIdx.x;
    if (idx >= BB * CIN * PSP) return;
    int pw = idx % PD;
    int ph = (idx / PD) % PD;
    int pd = (idx / (PD * PD)) % PD;
    int bc = idx / PSP;
    float v = 0.f;
    if (pw >= 1 && pw <= DD && ph >= 1 && ph <= DD && pd >= 1 && pd <= DD)
        v = x[(size_t)bc * NSP + ((size_t)(pd - 1) * DD + (ph - 1)) * DD + (pw - 1)];
    xp[idx] = v;
}

// ---------------- Conv3d k=3 s=1 SAME + bias (padded input, reg-blocked) ----------------
// grid: b * 16 co-groups * 32 voxel-blocks ; thread = 1 voxel, COG=4 output channels
__global__ __launch_bounds__(256) void conv3d_k(const float* __restrict__ xp,
                                                const float* __restrict__ w,
                                                const float* __restrict__ bias,
                                                float* __restrict__ y) {
    int blk = blockIdx.x;
    int vb  = blk & 31;
    int cg  = (blk >> 5) & 15;      // uniform co-group (of 4)
    int b   = blk >> 9;
    int vox = vb * 256 + threadIdx.x;
    bool valid = vox < NSP;
    int v  = valid ? vox : 0;
    int w_ = v % DD;
    int h_ = (v / DD) % DD;
    int d_ = v / (DD * DD);
    int pvox = ((d_ + 1) * PD + (h_ + 1)) * PD + (w_ + 1);
    const float* xb = xp + (size_t)b * CIN * PSP + pvox;

    float acc[COG];
    #pragma unroll
    for (int j = 0; j < COG; ++j) acc[j] = 0.f;

    for (int ci = 0; ci < CIN; ++ci) {
        const float* xc = xb + (size_t)ci * PSP;
        float xv[27];
        #pragma unroll
        for (int kd = 0; kd < 3; ++kd)
            #pragma unroll
            for (int kh = 0; kh < 3; ++kh)
                #pragma unroll
                for (int kw = 0; kw < 3; ++kw)
                    xv[(kd * 3 + kh) * 3 + kw] =
                        xc[(kd - 1) * (PD * PD) + (kh - 1) * PD + (kw - 1)];
        #pragma unroll
        for (int j = 0; j < COG; ++j) {
            int co = cg * COG + j;                       // uniform
            const float* wr = w + ((size_t)co * CIN + ci) * 27;
            float a = acc[j];
            #pragma unroll
            for (int t = 0; t < 27; ++t) a += xv[t] * wr[t];
            acc[j] = a;
        }
    }
    if (valid) {
        #pragma unroll
        for (int j = 0; j < COG; ++j) {
            int co = cg * COG + j;
            y[((size_t)b * COUT + co) * NSP + vox] = acc[j] + bias[co];
        }
    }
}

// ---------------- InstanceNorm partial sums: 4 chunks per (b,c) -> 512 blocks ----------------
__global__ void instnorm_part_k(const float* __restrict__ y, float2* __restrict__ part) {
    int bc    = blockIdx.x >> 2;         // 0..127
    int chunk = blockIdx.x & 3;          // 0..3  (2000 elems each)
    const float* yb = y + (size_t)bc * NSP + chunk * 2000;
    float s = 0.f, ss = 0.f;
    for (int i = threadIdx.x; i < 2000; i += 256) {
        float v = yb[i];
        s += v; ss += v * v;
    }
    __shared__ float rs[256], rss[256];
    rs[threadIdx.x] = s; rss[threadIdx.x] = ss;
    __syncthreads();
    for (int off = 128; off > 0; off >>= 1) {
        if (threadIdx.x < off) {
            rs[threadIdx.x]  += rs[threadIdx.x + off];
            rss[threadIdx.x] += rss[threadIdx.x + off];
        }
        __syncthreads();
    }
    if (threadIdx.x == 0) part[blockIdx.x] = make_float2(rs[0], rss[0]);
}

// ---------------- QKV projections (stats-finalize + norm + LeakyReLU fused) ----------------
// Q (hi,lo), K (hi): [b][tile][c(4)][half(2)][row(32)][e(8)]  (4KB contiguous per tile)
// V:                 [b][tile][Y(2)][X(2)][half(2)][row(32)][e(8)]
__global__ __launch_bounds__(256) void qkv_k(const float* __restrict__ yraw,
                      const float2* __restrict__ part,
                      const float* __restrict__ gamma, const float* __restrict__ beta,
                      const float* __restrict__ wq, const float* __restrict__ bq,
                      const float* __restrict__ wk, const float* __restrict__ bk,
                      const float* __restrict__ wv, const float* __restrict__ bv,
                      unsigned short* __restrict__ Qfh, unsigned short* __restrict__ Qfl,
                      unsigned short* __restrict__ Kfh,
                      unsigned short* __restrict__ Vf) {
    int blk = blockIdx.x;
    int vb  = blk & 31;
    int og  = (blk >> 5) & 7;       // uniform o-group
    int b   = blk >> 8;
    int n   = vb * 256 + threadIdx.x;
    bool valid = n < NSP;
    int nn  = valid ? n : 0;
    const float* fb = yraw + (size_t)b * COUT * NSP + nn;

    // finalize instance-norm stats (deterministic 4-way sum per channel)
    __shared__ float smean[COUT], srstd[COUT];
    if (threadIdx.x < COUT) {
        int c = threadIdx.x;
        float s = 0.f, ss = 0.f;
        #pragma unroll
        for (int ch = 0; ch < 4; ++ch) {
            float2 p = part[(b * COUT + c) * 4 + ch];
            s += p.x; ss += p.y;
        }
        float mean = s * (1.f / NSP);
        smean[c] = mean;
        srstd[c] = rsqrtf(ss * (1.f / NSP) - mean * mean + EPSN);
    }
    __syncthreads();

    float aq[OG], ak[OG], av[OG];
    #pragma unroll
    for (int j = 0; j < OG; ++j) {
        int o = og * OG + j;
        aq[j] = bq[o]; ak[j] = bk[o]; av[j] = bv[o];
    }
    for (int c = 0; c < COUT; ++c) {
        float fc = (fb[(size_t)c * NSP] - smean[c]) * srstd[c] * gamma[c] + beta[c];
        fc = fc >= 0.f ? fc : SLOPE * fc;            // LeakyReLU fused
        #pragma unroll
        for (int j = 0; j < OG; ++j) {
            int o = og * OG + j;                         // uniform
            aq[j] += wq[o * COUT + c] * fc;
            ak[j] += wk[o * COUT + c] * fc;
            av[j] += wv[o * COUT + c] * fc;
        }
    }
    if (!valid) return;

    int t  = n >> 5;                // tile
    int kk = n & 31;                // row within tile
    unsigned short qh[OG], ql[OG], kh[OG];
    #pragma unroll
    for (int j = 0; j < OG; ++j) {
        qh[j] = f2bf_rne(aq[j]); ql[j] = f2bf_rne(aq[j] - bf2f(qh[j]));
        kh[j] = f2bf_rne(ak[j]);
    }
    // Q/K store: c = og>>1, half = og&1
    size_t qko = ((size_t)((b * NT + t) * 4 + (og >> 1)) * 2 + (og & 1)) * 256 + kk * 8;
    *reinterpret_cast<uint4*>(Qfh + qko) = *reinterpret_cast<const uint4*>(qh);
    *reinterpret_cast<uint4*>(Qfl + qko) = *reinterpret_cast<const uint4*>(ql);
    *reinterpret_cast<uint4*>(Kfh + qko) = *reinterpret_cast<const uint4*>(kh);
    // V store: Y=kk>>4, half=(kk>>3)&1, e=kk&7 ; X=og>>2, row=(og&3)*8+j
    {
        int Y = kk >> 4, hf = (kk >> 3) & 1, e = kk & 7;
        size_t vbase = ((size_t)((b * NT + t) * 2 + Y) * 2 + (og >> 2)) * 512
                     + hf * 256 + e;
        #pragma unroll
        for (int j = 0; j < OG; ++j)
            Vf[vbase + ((og & 3) * 8 + j) * 8] = f2bf_rne(av[j]);
    }
}

// ---------------- flash attention pass 1: MFMA + distance-2 LDS pipeline ----------------
// K single-precision-term: S = Kh.(Qh+Ql) — 8 QK MFMAs in two independent chains.
// 3 LDS buffers of 8KB; counted vmcnt(2); raw s_barrier (no implicit drain).
__global__ __launch_bounds__(256, 4) void attn_pass1_mfma(
        const unsigned short* __restrict__ Qfh, const unsigned short* __restrict__ Qfl,
        const unsigned short* __restrict__ Kfh,
        const unsigned short* __restrict__ Vf,
        float* __restrict__ pm, float* __restrict__ pl, float* __restrict__ pacc) {
    int bid   = blockIdx.x;
    int split = bid / (BB * QUADS);         // split-major: co-resident share K/V window
    int rem   = bid % (BB * QUADS);
    int b     = rem / QUADS;
    int quad  = rem % QUADS;
    int wave  = threadIdx.x >> 6;
    int lane  = threadIdx.x & 63;
    int col   = lane & 31;
    int half  = lane >> 5;
    int qt    = quad * 4 + wave;
    bool qvalid = qt < NT;
    int qtc   = qvalid ? qt : NT - 1;
    int bNT   = b * NT;

    __shared__ __align__(16) char ldsbuf[3][8192];   // [Kh 4K | V 4K] x3

    // Q fragments: contiguous 1KB per c-chunk
    short8 qfh[4], qfl[4];
    {
        const unsigned short* qp  = Qfh + (size_t)(bNT + qtc) * 2048 + lane * 8;
        const unsigned short* qp2 = Qfl + (size_t)(bNT + qtc) * 2048 + lane * 8;
        #pragma unroll
        for (int c = 0; c < 4; ++c) {
            qfh[c] = ld_frag(qp  + c * 512);
            qfl[c] = ld_frag(qp2 + c * 512);
        }
    }

    int wo = wave * 1024;           // this wave's 1KB slice of each 4KB chunk
    int go = wo + lane * 16;        // byte offset into the tile's 4KB chunk

    auto STAGE = [&](int bufi, int tg) {
        size_t tb = (size_t)(bNT + tg) * 2048;     // elements (=4096 B)
        char* l = &ldsbuf[bufi][0];
        gload_lds16((const char*)(Kfh + tb) + go, l + wo);
        gload_lds16((const char*)(Vf  + tb) + go, l + 4096 + wo);
    };

    f32x16 oacc0 = {};
    f32x16 oacc1 = {};
    float m = -3e38f, lsum = 0.f;

    int t0g = split * NKT;
    STAGE(0, t0g);                   // prologue: stage tiles 0 and 1
    STAGE(1, t0g + 1);

    for (int t = 0; t < NKT; ++t) {
        // wait for stage(t): 2 newer loads (stage(t+1)) may stay in flight
        if (t == NKT - 1) { asm volatile("s_waitcnt vmcnt(0)" ::: "memory"); }
        else              { asm volatile("s_waitcnt vmcnt(2)" ::: "memory"); }
        __builtin_amdgcn_sched_barrier(0);
        __builtin_amdgcn_s_barrier();          // raw: no implicit vmcnt drain
        __builtin_amdgcn_sched_barrier(0);
        if (t + 2 < NKT) STAGE((t + 2) % 3, t0g + t + 2);

        const unsigned short* lk = (const unsigned short*)&ldsbuf[t % 3][0];
        const unsigned short* lv = (const unsigned short*)&ldsbuf[t % 3][4096];

        // QK^T: S^T = Kh.(Qh+Ql)^T — two independent 4-MFMA chains
        f32x16 sA = {};
        f32x16 sB = {};
        __builtin_amdgcn_s_setprio(1);
        #pragma unroll
        for (int c = 0; c < 4; ++c) {
            short8 kfh = ld_frag(lk + c * 512 + lane * 8);
            sA = __builtin_amdgcn_mfma_f32_32x32x16_bf16(kfh, qfh[c], sA, 0, 0, 0);
            sB = __builtin_amdgcn_mfma_f32_32x32x16_bf16(kfh, qfl[c], sB, 0, 0, 0);
        }
        __builtin_amdgcn_s_setprio(0);
        float s[16];
        #pragma unroll
        for (int r = 0; r < 16; ++r) s[r] = sA[r] + sB[r];

        // tree max over 16 + cross-half
        float t8[8];
        #pragma unroll
        for (int r = 0; r < 8; ++r) t8[r] = fmaxf(s[r], s[r + 8]);
        float t4a = fmaxf(t8[0], t8[1]), t4b = fmaxf(t8[2], t8[3]);
        float t4c = fmaxf(t8[4], t8[5]), t4d = fmaxf(t8[6], t8[7]);
        float tmax = fmaxf(fmaxf(t4a, t4b), fmaxf(t4c, t4d));
        tmax = fmaxf(tmax, __shfl_xor(tmax, 32, 64));
        // T13 defer-rescale
        if (__any(tmax > m + 8.f)) {
            float newm  = fmaxf(m, tmax);
            float scale = __expf(m - newm);
            lsum *= scale;
            #pragma unroll
            for (int r = 0; r < 16; ++r) { oacc0[r] *= scale; oacc1[r] *= scale; }
            m = newm;
        }
        // P in two groups of 8 (regs) -> bf16 B-fragments via cvt_pk + half-exchange
        short8 pf0, pf1;
        float ls;
        {
            float p[8];
            #pragma unroll
            for (int r = 0; r < 8; ++r) p[r] = __expf(s[r] - m);
            ls = ((p[0] + p[1]) + (p[2] + p[3])) + ((p[4] + p[5]) + (p[6] + p[7]));
            unsigned W[4], X[4];
            #pragma unroll
            for (int j = 0; j < 4; ++j)
                asm("v_cvt_pk_bf16_f32 %0, %1, %2" : "=v"(W[j]) : "v"(p[2 * j]), "v"(p[2 * j + 1]));
            #pragma unroll
            for (int j = 0; j < 4; ++j) X[j] = (unsigned)__shfl_xor((int)W[j], 32, 64);
            uint4 u = half ? make_uint4(X[2], X[3], W[2], W[3])
                           : make_uint4(W[0], W[1], X[0], X[1]);
            pf0 = __builtin_bit_cast(short8, u);
        }
        {
            float p[8];
            #pragma unroll
            for (int r = 0; r < 8; ++r) p[r] = __expf(s[r + 8] - m);
            ls += ((p[0] + p[1]) + (p[2] + p[3])) + ((p[4] + p[5]) + (p[6] + p[7]));
            unsigned W[4], X[4];
            #pragma unroll
            for (int j = 0; j < 4; ++j)
                asm("v_cvt_pk_bf16_f32 %0, %1, %2" : "=v"(W[j]) : "v"(p[2 * j]), "v"(p[2 * j + 1]));
            #pragma unroll
            for (int j = 0; j < 4; ++j) X[j] = (unsigned)__shfl_xor((int)W[j], 32, 64);
            uint4 u = half ? make_uint4(X[2], X[3], W[2], W[3])
                           : make_uint4(W[0], W[1], X[0], X[1]);
            pf1 = __builtin_bit_cast(short8, u);
        }
        lsum += ls;
        // PV: O^T = V^T.P^T  (X -> oacc, Y -> pf)
        {
            short8 v00 = ld_frag(lv + 0 * 512 + lane * 8);   // Y0 X0
            short8 v10 = ld_frag(lv + 1 * 512 + lane * 8);   // Y0 X1
            __builtin_amdgcn_s_setprio(1);
            oacc0 = __builtin_amdgcn_mfma_f32_32x32x16_bf16(v00, pf0, oacc0, 0, 0, 0);
            oacc1 = __builtin_amdgcn_mfma_f32_32x32x16_bf16(v10, pf0, oacc1, 0, 0, 0);
            __builtin_amdgcn_s_setprio(0);
            short8 v01 = ld_frag(lv + 2 * 512 + lane * 8);   // Y1 X0
            short8 v11 = ld_frag(lv + 3 * 512 + lane * 8);   // Y1 X1
            __builtin_amdgcn_s_setprio(1);
            oacc0 = __builtin_amdgcn_mfma_f32_32x32x16_bf16(v01, pf1, oacc0, 0, 0, 0);
            oacc1 = __builtin_amdgcn_mfma_f32_32x32x16_bf16(v11, pf1, oacc1, 0, 0, 0);
            __builtin_amdgcn_s_setprio(0);
        }
    }

    if (!qvalid) return;
    int q0 = qt * 32;
    float lfull = lsum + __shfl_xor(lsum, 32, 64);
    size_t base = (size_t)b * SPLITS + split;
    if (lane < 32) {
        pm[base * NSP + q0 + col] = m;
        pl[base * NSP + q0 + col] = lfull;
    }
    float* pa = pacc + base * (size_t)(COUT * NSP) + q0 + col;
    #pragma unroll
    for (int r = 0; r < 16; ++r) {
        int crow = (r & 3) + 8 * (r >> 2) + 4 * half;
        pa[(size_t)crow * NSP]        = oacc0[r];
        pa[(size_t)(crow + 32) * NSP] = oacc1[r];
    }
}

// ---------------- combine split-K partials ----------------
__global__ void attn_combine_k(const float* __restrict__ pm, const float* __restrict__ pl,
                               const float* __restrict__ pacc, float* __restrict__ out) {
    int idx = blockIdx.x * blockDim.x + threadIdx.x;   // over B*COUT*NSP
    if (idx >= BB * COUT * NSP) return;
    int n = idx % NSP;
    int c = (idx / NSP) % COUT;
    int b = idx / (NSP * COUT);
    float M = -1e30f;
    #pragma unroll
    for (int j = 0; j < SPLITS; ++j)
        M = fmaxf(M, pm[((size_t)b * SPLITS + j) * NSP + n]);
    float L = 0.f, O = 0.f;
    #pragma unroll
    for (int j = 0; j < SPLITS; ++j) {
        size_t base = (size_t)b * SPLITS + j;
        float wgt = __expf(pm[base * NSP + n] - M);
        L += pl[base * NSP + n] * wgt;
        O += pacc[(base * COUT + c) * NSP + n] * wgt;
    }
    out[idx] = O / L;
}

// ---------------- launch ----------------
extern "C" void kernel_launch(void* const* d_in, const int* in_sizes, int n_in,
                              void* d_out, int out_size, void* d_ws, size_t ws_size,
                              hipStream_t stream) {
    const float* x      = (const float*)d_in[0];
    const float* conv_w = (const float*)d_in[1];
    const float* conv_b = (const float*)d_in[2];
    const float* gamma  = (const float*)d_in[3];
    const float* beta   = (const float*)d_in[4];
    const float* wq     = (const float*)d_in[5];
    const float* bq     = (const float*)d_in[6];
    const float* wk     = (const float*)d_in[7];
    const float* bk     = (const float*)d_in[8];
    const float* wv     = (const float*)d_in[9];
    const float* bv     = (const float*)d_in[10];
    float* out = (float*)d_out;

    const int ELEMS = BB * COUT * NSP;      // 1,024,000
    char* w8 = (char*)d_ws;
    float*  y    = (float*)w8;                          // 4,096,000 B
    float2* part = (float2*)(w8 + 4096000);             // 4,096 B
    unsigned short* Qfh = (unsigned short*)(w8 + 4100096);
    unsigned short* Qfl = Qfh + (size_t)ELEMS;          // each 2,048,000 B
    unsigned short* Kfh = Qfl + (size_t)ELEMS;
    unsigned short* Vf  = Kfh + (size_t)ELEMS;
    float* pm   = (float*)(Vf + (size_t)ELEMS);
    float* pl   = pm + (size_t)BB * SPLITS * NSP;       // 640,000 B each
    float* pacc = pl + (size_t)BB * SPLITS * NSP;       // 40,960,000 B
    // xpad aliases pacc: xpad live only before conv3d_k; pacc only after qkv_k
    float* xpad = pacc;                                 // needs 2,725,888 B

    pad_k<<<(BB * CIN * PSP + 255) / 256, 256, 0, stream>>>(x, xpad);
    conv3d_k<<<BB * 16 * 32, 256, 0, stream>>>(xpad, conv_w, conv_b, y);
    instnorm_part_k<<<BB * COUT * 4, 256, 0, stream>>>(y, part);
    qkv_k<<<BB * 8 * 32, 256, 0, stream>>>(y, part, gamma, beta,
                                           wq, bq, wk, bk, wv, bv,
                                           Qfh, Qfl, Kfh, Vf);
    attn_pass1_mfma<<<SPLITS * BB * QUADS, 256, 0, stream>>>(Qfh, Qfl, Kfh, Vf,
                                                             pm, pl, pacc);
    attn_combine_k<<<(ELEMS + 255) / 256, 256, 0, stream>>>(pm, pl, pacc, out);
}

// Round 11
// 156.680 us; speedup vs baseline: 1.8769x; 1.0010x over previous
//
#include <hip/hip_runtime.h>
#include <math.h>

#define CIN   32
#define COUT  64
#define DD    20
#define PD    22        // padded dim
#define PSP   (PD*PD*PD)   // 10648
#define NSP   8000      // 20*20*20
#define BB    2
#define EPSN  1e-5f
#define SLOPE 0.01f

#define NT     250              // 32-row k/q tiles per batch
#define SPLITS 10
#define NKT    (NT / SPLITS)    // 25 k-tiles per split
#define QUADS  63               // ceil(250/4) q-tiles, 4 per block

#define COG 4                   // conv: output channels per thread (4 -> 1024 blocks)
#define OG  8                   // qkv: output channels per thread

typedef float  f32x16 __attribute__((ext_vector_type(16)));
typedef short  short8 __attribute__((ext_vector_type(8)));

__device__ __forceinline__ unsigned short f2bf_rne(float x) {
    unsigned u = __float_as_uint(x);
    unsigned r = (u + 0x7FFFu + ((u >> 16) & 1u)) >> 16;
    return (unsigned short)r;
}
__device__ __forceinline__ float bf2f(unsigned short h) {
    return __uint_as_float(((unsigned)h) << 16);
}
__device__ __forceinline__ short8 ld_frag(const unsigned short* p) {
    uint4 t = *reinterpret_cast<const uint4*>(p);
    return __builtin_bit_cast(short8, t);
}
// async global->LDS, 16B per lane; LDS dest is wave-uniform base + lane*16
__device__ __forceinline__ void gload_lds16(const void* gsrc, void* ldst) {
    typedef __attribute__((address_space(1))) const unsigned int GU;
    typedef __attribute__((address_space(3))) unsigned int LU;
    __builtin_amdgcn_global_load_lds((GU*)gsrc, (LU*)ldst, 16, 0, 0);
}

// ---------------- zero-pad x into [B][CIN][22][22][22] ----------------
__global__ void pad_k(const float* __restrict__ x, float* __restrict__ xp) {
    int idx = blockIdx.x * blockDim.x + threadIdx.x;
    if (idx >= BB * CIN * PSP) return;
    int pw = idx % PD;
    int ph = (idx / PD) % PD;
    int pd = (idx / (PD * PD)) % PD;
    int bc = idx / PSP;
    float v = 0.f;
    if (pw >= 1 && pw <= DD && ph >= 1 && ph <= DD && pd >= 1 && pd <= DD)
        v = x[(size_t)bc * NSP + ((size_t)(pd - 1) * DD + (ph - 1)) * DD + (pw - 1)];
    xp[idx] = v;
}

// ---------------- Conv3d k=3 s=1 SAME + bias (padded input, reg-blocked) ----------------
// grid: b * 16 co-groups * 32 voxel-blocks ; thread = 1 voxel, COG=4 output channels
__global__ __launch_bounds__(256) void conv3d_k(const float* __restrict__ xp,
                                                const float* __restrict__ w,
                                                const float* __restrict__ bias,
                                                float* __restrict__ y) {
    int blk = blockIdx.x;
    int vb  = blk & 31;
    int cg  = (blk >> 5) & 15;      // uniform co-group (of 4)
    int b   = blk >> 9;
    int vox = vb * 256 + threadIdx.x;
    bool valid = vox < NSP;
    int v  = valid ? vox : 0;
    int w_ = v % DD;
    int h_ = (v / DD) % DD;
    int d_ = v / (DD * DD);
    int pvox = ((d_ + 1) * PD + (h_ + 1)) * PD + (w_ + 1);
    const float* xb = xp + (size_t)b * CIN * PSP + pvox;

    float acc[COG];
    #pragma unroll
    for (int j = 0; j < COG; ++j) acc[j] = 0.f;

    for (int ci = 0; ci < CIN; ++ci) {
        const float* xc = xb + (size_t)ci * PSP;
        float xv[27];
        #pragma unroll
        for (int kd = 0; kd < 3; ++kd)
            #pragma unroll
            for (int kh = 0; kh < 3; ++kh)
                #pragma unroll
                for (int kw = 0; kw < 3; ++kw)
                    xv[(kd * 3 + kh) * 3 + kw] =
                        xc[(kd - 1) * (PD * PD) + (kh - 1) * PD + (kw - 1)];
        #pragma unroll
        for (int j = 0; j < COG; ++j) {
            int co = cg * COG + j;                       // uniform
            const float* wr = w + ((size_t)co * CIN + ci) * 27;
            float a = acc[j];
            #pragma unroll
            for (int t = 0; t < 27; ++t) a += xv[t] * wr[t];
            acc[j] = a;
        }
    }
    if (valid) {
        #pragma unroll
        for (int j = 0; j < COG; ++j) {
            int co = cg * COG + j;
            y[((size_t)b * COUT + co) * NSP + vox] = acc[j] + bias[co];
        }
    }
}

// ---------------- InstanceNorm partial sums: 4 chunks per (b,c) -> 512 blocks ----------------
__global__ void instnorm_part_k(const float* __restrict__ y, float2* __restrict__ part) {
    int bc    = blockIdx.x >> 2;         // 0..127
    int chunk = blockIdx.x & 3;          // 0..3  (2000 elems each)
    const float* yb = y + (size_t)bc * NSP + chunk * 2000;
    float s = 0.f, ss = 0.f;
    for (int i = threadIdx.x; i < 2000; i += 256) {
        float v = yb[i];
        s += v; ss += v * v;
    }
    __shared__ float rs[256], rss[256];
    rs[threadIdx.x] = s; rss[threadIdx.x] = ss;
    __syncthreads();
    for (int off = 128; off > 0; off >>= 1) {
        if (threadIdx.x < off) {
            rs[threadIdx.x]  += rs[threadIdx.x + off];
            rss[threadIdx.x] += rss[threadIdx.x + off];
        }
        __syncthreads();
    }
    if (threadIdx.x == 0) part[blockIdx.x] = make_float2(rs[0], rss[0]);
}

// ---------------- QKV projections (stats-finalize + norm + LeakyReLU fused) ----------------
// Q (hi,lo), K (hi): [b][tile][c(4)][half(2)][row(32)][e(8)]  (4KB contiguous per tile)
// V:                 [b][tile][Y(2)][X(2)][half(2)][row(32)][e(8)]
__global__ __launch_bounds__(256) void qkv_k(const float* __restrict__ yraw,
                      const float2* __restrict__ part,
                      const float* __restrict__ gamma, const float* __restrict__ beta,
                      const float* __restrict__ wq, const float* __restrict__ bq,
                      const float* __restrict__ wk, const float* __restrict__ bk,
                      const float* __restrict__ wv, const float* __restrict__ bv,
                      unsigned short* __restrict__ Qfh, unsigned short* __restrict__ Qfl,
                      unsigned short* __restrict__ Kfh,
                      unsigned short* __restrict__ Vf) {
    int blk = blockIdx.x;
    int vb  = blk & 31;
    int og  = (blk >> 5) & 7;       // uniform o-group
    int b   = blk >> 8;
    int n   = vb * 256 + threadIdx.x;
    bool valid = n < NSP;
    int nn  = valid ? n : 0;
    const float* fb = yraw + (size_t)b * COUT * NSP + nn;

    // finalize instance-norm stats (deterministic 4-way sum per channel)
    __shared__ float smean[COUT], srstd[COUT];
    if (threadIdx.x < COUT) {
        int c = threadIdx.x;
        float s = 0.f, ss = 0.f;
        #pragma unroll
        for (int ch = 0; ch < 4; ++ch) {
            float2 p = part[(b * COUT + c) * 4 + ch];
            s += p.x; ss += p.y;
        }
        float mean = s * (1.f / NSP);
        smean[c] = mean;
        srstd[c] = rsqrtf(ss * (1.f / NSP) - mean * mean + EPSN);
    }
    __syncthreads();

    float aq[OG], ak[OG], av[OG];
    #pragma unroll
    for (int j = 0; j < OG; ++j) {
        int o = og * OG + j;
        aq[j] = bq[o]; ak[j] = bk[o]; av[j] = bv[o];
    }
    for (int c = 0; c < COUT; ++c) {
        float fc = (fb[(size_t)c * NSP] - smean[c]) * srstd[c] * gamma[c] + beta[c];
        fc = fc >= 0.f ? fc : SLOPE * fc;            // LeakyReLU fused
        #pragma unroll
        for (int j = 0; j < OG; ++j) {
            int o = og * OG + j;                         // uniform
            aq[j] += wq[o * COUT + c] * fc;
            ak[j] += wk[o * COUT + c] * fc;
            av[j] += wv[o * COUT + c] * fc;
        }
    }
    if (!valid) return;

    int t  = n >> 5;                // tile
    int kk = n & 31;                // row within tile
    unsigned short qh[OG], ql[OG], kh[OG];
    #pragma unroll
    for (int j = 0; j < OG; ++j) {
        qh[j] = f2bf_rne(aq[j]); ql[j] = f2bf_rne(aq[j] - bf2f(qh[j]));
        kh[j] = f2bf_rne(ak[j]);
    }
    // Q/K store: c = og>>1, half = og&1
    size_t qko = ((size_t)((b * NT + t) * 4 + (og >> 1)) * 2 + (og & 1)) * 256 + kk * 8;
    *reinterpret_cast<uint4*>(Qfh + qko) = *reinterpret_cast<const uint4*>(qh);
    *reinterpret_cast<uint4*>(Qfl + qko) = *reinterpret_cast<const uint4*>(ql);
    *reinterpret_cast<uint4*>(Kfh + qko) = *reinterpret_cast<const uint4*>(kh);
    // V store: Y=kk>>4, half=(kk>>3)&1, e=kk&7 ; X=og>>2, row=(og&3)*8+j
    {
        int Y = kk >> 4, hf = (kk >> 3) & 1, e = kk & 7;
        size_t vbase = ((size_t)((b * NT + t) * 2 + Y) * 2 + (og >> 2)) * 512
                     + hf * 256 + e;
        #pragma unroll
        for (int j = 0; j < OG; ++j)
            Vf[vbase + ((og & 3) * 8 + j) * 8] = f2bf_rne(av[j]);
    }
}

// ---------------- flash attention pass 1: MFMA + distance-2 LDS pipeline ----------------
// Single QK accumulator chain (reg diet: total unified regs must fit <=128 for
// 16 waves/CU — the m69 cliff; sA/sB split was pushing past it).
__global__ __launch_bounds__(256, 4) void attn_pass1_mfma(
        const unsigned short* __restrict__ Qfh, const unsigned short* __restrict__ Qfl,
        const unsigned short* __restrict__ Kfh,
        const unsigned short* __restrict__ Vf,
        float* __restrict__ pm, float* __restrict__ pl, float* __restrict__ pacc) {
    int bid   = blockIdx.x;
    int split = bid / (BB * QUADS);         // split-major: co-resident share K/V window
    int rem   = bid % (BB * QUADS);
    int b     = rem / QUADS;
    int quad  = rem % QUADS;
    int wave  = threadIdx.x >> 6;
    int lane  = threadIdx.x & 63;
    int col   = lane & 31;
    int half  = lane >> 5;
    int qt    = quad * 4 + wave;
    bool qvalid = qt < NT;
    int qtc   = qvalid ? qt : NT - 1;
    int bNT   = b * NT;

    __shared__ __align__(16) char ldsbuf[3][8192];   // [Kh 4K | V 4K] x3

    // Q fragments: contiguous 1KB per c-chunk
    short8 qfh[4], qfl[4];
    {
        const unsigned short* qp  = Qfh + (size_t)(bNT + qtc) * 2048 + lane * 8;
        const unsigned short* qp2 = Qfl + (size_t)(bNT + qtc) * 2048 + lane * 8;
        #pragma unroll
        for (int c = 0; c < 4; ++c) {
            qfh[c] = ld_frag(qp  + c * 512);
            qfl[c] = ld_frag(qp2 + c * 512);
        }
    }

    int wo = wave * 1024;           // this wave's 1KB slice of each 4KB chunk
    int go = wo + lane * 16;        // byte offset into the tile's 4KB chunk

    auto STAGE = [&](int bufi, int tg) {
        size_t tb = (size_t)(bNT + tg) * 2048;     // elements (=4096 B)
        char* l = &ldsbuf[bufi][0];
        gload_lds16((const char*)(Kfh + tb) + go, l + wo);
        gload_lds16((const char*)(Vf  + tb) + go, l + 4096 + wo);
    };

    f32x16 oacc0 = {};
    f32x16 oacc1 = {};
    float m = -3e38f, lsum = 0.f;

    int t0g = split * NKT;
    STAGE(0, t0g);                   // prologue: stage tiles 0 and 1
    STAGE(1, t0g + 1);

    for (int t = 0; t < NKT; ++t) {
        // wait for stage(t): 2 newer loads (stage(t+1)) may stay in flight
        if (t == NKT - 1) { asm volatile("s_waitcnt vmcnt(0)" ::: "memory"); }
        else              { asm volatile("s_waitcnt vmcnt(2)" ::: "memory"); }
        __builtin_amdgcn_sched_barrier(0);
        __builtin_amdgcn_s_barrier();          // raw: no implicit vmcnt drain
        __builtin_amdgcn_sched_barrier(0);
        if (t + 2 < NKT) STAGE((t + 2) % 3, t0g + t + 2);

        const unsigned short* lk = (const unsigned short*)&ldsbuf[t % 3][0];
        const unsigned short* lv = (const unsigned short*)&ldsbuf[t % 3][4096];

        // QK^T: S^T = Kh.(Qh+Ql)^T — single accumulator chain (reg diet)
        f32x16 s = {};
        __builtin_amdgcn_s_setprio(1);
        #pragma unroll
        for (int c = 0; c < 4; ++c) {
            short8 kfh = ld_frag(lk + c * 512 + lane * 8);
            s = __builtin_amdgcn_mfma_f32_32x32x16_bf16(kfh, qfh[c], s, 0, 0, 0);
            s = __builtin_amdgcn_mfma_f32_32x32x16_bf16(kfh, qfl[c], s, 0, 0, 0);
        }
        __builtin_amdgcn_s_setprio(0);

        // tree max over 16 + cross-half
        float t8[8];
        #pragma unroll
        for (int r = 0; r < 8; ++r) t8[r] = fmaxf(s[r], s[r + 8]);
        float t4a = fmaxf(t8[0], t8[1]), t4b = fmaxf(t8[2], t8[3]);
        float t4c = fmaxf(t8[4], t8[5]), t4d = fmaxf(t8[6], t8[7]);
        float tmax = fmaxf(fmaxf(t4a, t4b), fmaxf(t4c, t4d));
        tmax = fmaxf(tmax, __shfl_xor(tmax, 32, 64));
        // T13 defer-rescale
        if (__any(tmax > m + 8.f)) {
            float newm  = fmaxf(m, tmax);
            float scale = __expf(m - newm);
            lsum *= scale;
            #pragma unroll
            for (int r = 0; r < 16; ++r) { oacc0[r] *= scale; oacc1[r] *= scale; }
            m = newm;
        }
        // P in two groups of 8 (regs) -> bf16 B-fragments via cvt_pk + half-exchange
        short8 pf0, pf1;
        float ls;
        {
            float p[8];
            #pragma unroll
            for (int r = 0; r < 8; ++r) p[r] = __expf(s[r] - m);
            ls = ((p[0] + p[1]) + (p[2] + p[3])) + ((p[4] + p[5]) + (p[6] + p[7]));
            unsigned W[4], X[4];
            #pragma unroll
            for (int j = 0; j < 4; ++j)
                asm("v_cvt_pk_bf16_f32 %0, %1, %2" : "=v"(W[j]) : "v"(p[2 * j]), "v"(p[2 * j + 1]));
            #pragma unroll
            for (int j = 0; j < 4; ++j) X[j] = (unsigned)__shfl_xor((int)W[j], 32, 64);
            uint4 u = half ? make_uint4(X[2], X[3], W[2], W[3])
                           : make_uint4(W[0], W[1], X[0], X[1]);
            pf0 = __builtin_bit_cast(short8, u);
        }
        {
            float p[8];
            #pragma unroll
            for (int r = 0; r < 8; ++r) p[r] = __expf(s[r + 8] - m);
            ls += ((p[0] + p[1]) + (p[2] + p[3])) + ((p[4] + p[5]) + (p[6] + p[7]));
            unsigned W[4], X[4];
            #pragma unroll
            for (int j = 0; j < 4; ++j)
                asm("v_cvt_pk_bf16_f32 %0, %1, %2" : "=v"(W[j]) : "v"(p[2 * j]), "v"(p[2 * j + 1]));
            #pragma unroll
            for (int j = 0; j < 4; ++j) X[j] = (unsigned)__shfl_xor((int)W[j], 32, 64);
            uint4 u = half ? make_uint4(X[2], X[3], W[2], W[3])
                           : make_uint4(W[0], W[1], X[0], X[1]);
            pf1 = __builtin_bit_cast(short8, u);
        }
        lsum += ls;
        // PV: O^T = V^T.P^T  (X -> oacc, Y -> pf)
        {
            short8 v00 = ld_frag(lv + 0 * 512 + lane * 8);   // Y0 X0
            short8 v10 = ld_frag(lv + 1 * 512 + lane * 8);   // Y0 X1
            __builtin_amdgcn_s_setprio(1);
            oacc0 = __builtin_amdgcn_mfma_f32_32x32x16_bf16(v00, pf0, oacc0, 0, 0, 0);
            oacc1 = __builtin_amdgcn_mfma_f32_32x32x16_bf16(v10, pf0, oacc1, 0, 0, 0);
            __builtin_amdgcn_s_setprio(0);
            short8 v01 = ld_frag(lv + 2 * 512 + lane * 8);   // Y1 X0
            short8 v11 = ld_frag(lv + 3 * 512 + lane * 8);   // Y1 X1
            __builtin_amdgcn_s_setprio(1);
            oacc0 = __builtin_amdgcn_mfma_f32_32x32x16_bf16(v01, pf1, oacc0, 0, 0, 0);
            oacc1 = __builtin_amdgcn_mfma_f32_32x32x16_bf16(v11, pf1, oacc1, 0, 0, 0);
            __builtin_amdgcn_s_setprio(0);
        }
    }

    if (!qvalid) return;
    int q0 = qt * 32;
    float lfull = lsum + __shfl_xor(lsum, 32, 64);
    size_t base = (size_t)b * SPLITS + split;
    if (lane < 32) {
        pm[base * NSP + q0 + col] = m;
        pl[base * NSP + q0 + col] = lfull;
    }
    float* pa = pacc + base * (size_t)(COUT * NSP) + q0 + col;
    #pragma unroll
    for (int r = 0; r < 16; ++r) {
        int crow = (r & 3) + 8 * (r >> 2) + 4 * half;
        pa[(size_t)crow * NSP]        = oacc0[r];
        pa[(size_t)(crow + 32) * NSP] = oacc1[r];
    }
}

// ---------------- combine split-K partials ----------------
__global__ void attn_combine_k(const float* __restrict__ pm, const float* __restrict__ pl,
                               const float* __restrict__ pacc, float* __restrict__ out) {
    int idx = blockIdx.x * blockDim.x + threadIdx.x;   // over B*COUT*NSP
    if (idx >= BB * COUT * NSP) return;
    int n = idx % NSP;
    int c = (idx / NSP) % COUT;
    int b = idx / (NSP * COUT);
    float M = -1e30f;
    #pragma unroll
    for (int j = 0; j < SPLITS; ++j)
        M = fmaxf(M, pm[((size_t)b * SPLITS + j) * NSP + n]);
    float L = 0.f, O = 0.f;
    #pragma unroll
    for (int j = 0; j < SPLITS; ++j) {
        size_t base = (size_t)b * SPLITS + j;
        float wgt = __expf(pm[base * NSP + n] - M);
        L += pl[base * NSP + n] * wgt;
        O += pacc[(base * COUT + c) * NSP + n] * wgt;
    }
    out[idx] = O / L;
}

// ---------------- launch ----------------
extern "C" void kernel_launch(void* const* d_in, const int* in_sizes, int n_in,
                              void* d_out, int out_size, void* d_ws, size_t ws_size,
                              hipStream_t stream) {
    const float* x      = (const float*)d_in[0];
    const float* conv_w = (const float*)d_in[1];
    const float* conv_b = (const float*)d_in[2];
    const float* gamma  = (const float*)d_in[3];
    const float* beta   = (const float*)d_in[4];
    const float* wq     = (const float*)d_in[5];
    const float* bq     = (const float*)d_in[6];
    const float* wk     = (const float*)d_in[7];
    const float* bk     = (const float*)d_in[8];
    const float* wv     = (const float*)d_in[9];
    const float* bv     = (const float*)d_in[10];
    float* out = (float*)d_out;

    const int ELEMS = BB * COUT * NSP;      // 1,024,000
    char* w8 = (char*)d_ws;
    float*  y    = (float*)w8;                          // 4,096,000 B
    float2* part = (float2*)(w8 + 4096000);             // 4,096 B
    unsigned short* Qfh = (unsigned short*)(w8 + 4100096);
    unsigned short* Qfl = Qfh + (size_t)ELEMS;          // each 2,048,000 B
    unsigned short* Kfh = Qfl + (size_t)ELEMS;
    unsigned short* Vf  = Kfh + (size_t)ELEMS;
    float* pm   = (float*)(Vf + (size_t)ELEMS);
    float* pl   = pm + (size_t)BB * SPLITS * NSP;       // 640,000 B each
    float* pacc = pl + (size_t)BB * SPLITS * NSP;       // 40,960,000 B
    // xpad aliases pacc: xpad live only before conv3d_k; pacc only after qkv_k
    float* xpad = pacc;                                 // needs 2,725,888 B

    pad_k<<<(BB * CIN * PSP + 255) / 256, 256, 0, stream>>>(x, xpad);
    conv3d_k<<<BB * 16 * 32, 256, 0, stream>>>(xpad, conv_w, conv_b, y);
    instnorm_part_k<<<BB * COUT * 4, 256, 0, stream>>>(y, part);
    qkv_k<<<BB * 8 * 32, 256, 0, stream>>>(y, part, gamma, beta,
                                           wq, bq, wk, bk, wv, bv,
                                           Qfh, Qfl, Kfh, Vf);
    attn_pass1_mfma<<<SPLITS * BB * QUADS, 256, 0, stream>>>(Qfh, Qfl, Kfh, Vf,
                                                             pm, pl, pacc);
    attn_combine_k<<<(ELEMS + 255) / 256, 256, 0, stream>>>(pm, pl, pacc, out);
}

// Round 12
// 151.561 us; speedup vs baseline: 1.9403x; 1.0338x over previous
//
#include <hip/hip_runtime.h>
#include <math.h>

#define CIN   32
#define COUT  64
#define DD    20
#define PD    22        // padded dim
#define PSP   (PD*PD*PD)   // 10648
#define NSP   8000      // 20*20*20
#define BB    2
#define EPSN  1e-5f
#define SLOPE 0.01f

#define NT     250              // 32-row k/q tiles per batch
#define SPLITS 8                // 8x2x63 = 1008 blocks ~= 4-blocks/CU capacity (one round)
#define QUADS  63               // ceil(250/4) q-tiles, 4 per block

#define COG 4                   // conv: output channels per thread (4 -> 1024 blocks)
#define OG  8                   // qkv: output channels per thread

typedef float  f32x16 __attribute__((ext_vector_type(16)));
typedef short  short8 __attribute__((ext_vector_type(8)));

__device__ __forceinline__ unsigned short f2bf_rne(float x) {
    unsigned u = __float_as_uint(x);
    unsigned r = (u + 0x7FFFu + ((u >> 16) & 1u)) >> 16;
    return (unsigned short)r;
}
__device__ __forceinline__ float bf2f(unsigned short h) {
    return __uint_as_float(((unsigned)h) << 16);
}
__device__ __forceinline__ short8 ld_frag(const unsigned short* p) {
    uint4 t = *reinterpret_cast<const uint4*>(p);
    return __builtin_bit_cast(short8, t);
}
// async global->LDS, 16B per lane; LDS dest is wave-uniform base + lane*16
__device__ __forceinline__ void gload_lds16(const void* gsrc, void* ldst) {
    typedef __attribute__((address_space(1))) const unsigned int GU;
    typedef __attribute__((address_space(3))) unsigned int LU;
    __builtin_amdgcn_global_load_lds((GU*)gsrc, (LU*)ldst, 16, 0, 0);
}

// ---------------- zero-pad x into [B][CIN][22][22][22] ----------------
__global__ void pad_k(const float* __restrict__ x, float* __restrict__ xp) {
    int idx = blockIdx.x * blockDim.x + threadIdx.x;
    if (idx >= BB * CIN * PSP) return;
    int pw = idx % PD;
    int ph = (idx / PD) % PD;
    int pd = (idx / (PD * PD)) % PD;
    int bc = idx / PSP;
    float v = 0.f;
    if (pw >= 1 && pw <= DD && ph >= 1 && ph <= DD && pd >= 1 && pd <= DD)
        v = x[(size_t)bc * NSP + ((size_t)(pd - 1) * DD + (ph - 1)) * DD + (pw - 1)];
    xp[idx] = v;
}

// ---------------- Conv3d k=3 s=1 SAME + bias (padded input, reg-blocked) ----------------
// grid: b * 16 co-groups * 32 voxel-blocks ; thread = 1 voxel, COG=4 output channels
__global__ __launch_bounds__(256) void conv3d_k(const float* __restrict__ xp,
                                                const float* __restrict__ w,
                                                const float* __restrict__ bias,
                                                float* __restrict__ y) {
    int blk = blockIdx.x;
    int vb  = blk & 31;
    int cg  = (blk >> 5) & 15;      // uniform co-group (of 4)
    int b   = blk >> 9;
    int vox = vb * 256 + threadIdx.x;
    bool valid = vox < NSP;
    int v  = valid ? vox : 0;
    int w_ = v % DD;
    int h_ = (v / DD) % DD;
    int d_ = v / (DD * DD);
    int pvox = ((d_ + 1) * PD + (h_ + 1)) * PD + (w_ + 1);
    const float* xb = xp + (size_t)b * CIN * PSP + pvox;

    float acc[COG];
    #pragma unroll
    for (int j = 0; j < COG; ++j) acc[j] = 0.f;

    for (int ci = 0; ci < CIN; ++ci) {
        const float* xc = xb + (size_t)ci * PSP;
        float xv[27];
        #pragma unroll
        for (int kd = 0; kd < 3; ++kd)
            #pragma unroll
            for (int kh = 0; kh < 3; ++kh)
                #pragma unroll
                for (int kw = 0; kw < 3; ++kw)
                    xv[(kd * 3 + kh) * 3 + kw] =
                        xc[(kd - 1) * (PD * PD) + (kh - 1) * PD + (kw - 1)];
        #pragma unroll
        for (int j = 0; j < COG; ++j) {
            int co = cg * COG + j;                       // uniform
            const float* wr = w + ((size_t)co * CIN + ci) * 27;
            float a = acc[j];
            #pragma unroll
            for (int t = 0; t < 27; ++t) a += xv[t] * wr[t];
            acc[j] = a;
        }
    }
    if (valid) {
        #pragma unroll
        for (int j = 0; j < COG; ++j) {
            int co = cg * COG + j;
            y[((size_t)b * COUT + co) * NSP + vox] = acc[j] + bias[co];
        }
    }
}

// ---------------- InstanceNorm partial sums: 4 chunks per (b,c) -> 512 blocks ----------------
__global__ void instnorm_part_k(const float* __restrict__ y, float2* __restrict__ part) {
    int bc    = blockIdx.x >> 2;         // 0..127
    int chunk = blockIdx.x & 3;          // 0..3  (2000 elems each)
    const float* yb = y + (size_t)bc * NSP + chunk * 2000;
    float s = 0.f, ss = 0.f;
    for (int i = threadIdx.x; i < 2000; i += 256) {
        float v = yb[i];
        s += v; ss += v * v;
    }
    __shared__ float rs[256], rss[256];
    rs[threadIdx.x] = s; rss[threadIdx.x] = ss;
    __syncthreads();
    for (int off = 128; off > 0; off >>= 1) {
        if (threadIdx.x < off) {
            rs[threadIdx.x]  += rs[threadIdx.x + off];
            rss[threadIdx.x] += rss[threadIdx.x + off];
        }
        __syncthreads();
    }
    if (threadIdx.x == 0) part[blockIdx.x] = make_float2(rs[0], rss[0]);
}

// ---------------- QKV projections (stats-finalize + norm + LeakyReLU fused) ----------------
// Q (hi,lo), K (hi): [b][tile][c(4)][half(2)][row(32)][e(8)]  (4KB contiguous per tile)
// V:                 [b][tile][Y(2)][X(2)][half(2)][row(32)][e(8)]
__global__ __launch_bounds__(256) void qkv_k(const float* __restrict__ yraw,
                      const float2* __restrict__ part,
                      const float* __restrict__ gamma, const float* __restrict__ beta,
                      const float* __restrict__ wq, const float* __restrict__ bq,
                      const float* __restrict__ wk, const float* __restrict__ bk,
                      const float* __restrict__ wv, const float* __restrict__ bv,
                      unsigned short* __restrict__ Qfh, unsigned short* __restrict__ Qfl,
                      unsigned short* __restrict__ Kfh,
                      unsigned short* __restrict__ Vf) {
    int blk = blockIdx.x;
    int vb  = blk & 31;
    int og  = (blk >> 5) & 7;       // uniform o-group
    int b   = blk >> 8;
    int n   = vb * 256 + threadIdx.x;
    bool valid = n < NSP;
    int nn  = valid ? n : 0;
    const float* fb = yraw + (size_t)b * COUT * NSP + nn;

    // finalize instance-norm stats (deterministic 4-way sum per channel)
    __shared__ float smean[COUT], srstd[COUT];
    if (threadIdx.x < COUT) {
        int c = threadIdx.x;
        float s = 0.f, ss = 0.f;
        #pragma unroll
        for (int ch = 0; ch < 4; ++ch) {
            float2 p = part[(b * COUT + c) * 4 + ch];
            s += p.x; ss += p.y;
        }
        float mean = s * (1.f / NSP);
        smean[c] = mean;
        srstd[c] = rsqrtf(ss * (1.f / NSP) - mean * mean + EPSN);
    }
    __syncthreads();

    float aq[OG], ak[OG], av[OG];
    #pragma unroll
    for (int j = 0; j < OG; ++j) {
        int o = og * OG + j;
        aq[j] = bq[o]; ak[j] = bk[o]; av[j] = bv[o];
    }
    for (int c = 0; c < COUT; ++c) {
        float fc = (fb[(size_t)c * NSP] - smean[c]) * srstd[c] * gamma[c] + beta[c];
        fc = fc >= 0.f ? fc : SLOPE * fc;            // LeakyReLU fused
        #pragma unroll
        for (int j = 0; j < OG; ++j) {
            int o = og * OG + j;                         // uniform
            aq[j] += wq[o * COUT + c] * fc;
            ak[j] += wk[o * COUT + c] * fc;
            av[j] += wv[o * COUT + c] * fc;
        }
    }
    if (!valid) return;

    int t  = n >> 5;                // tile
    int kk = n & 31;                // row within tile
    unsigned short qh[OG], ql[OG], kh[OG];
    #pragma unroll
    for (int j = 0; j < OG; ++j) {
        qh[j] = f2bf_rne(aq[j]); ql[j] = f2bf_rne(aq[j] - bf2f(qh[j]));
        kh[j] = f2bf_rne(ak[j]);
    }
    // Q/K store: c = og>>1, half = og&1
    size_t qko = ((size_t)((b * NT + t) * 4 + (og >> 1)) * 2 + (og & 1)) * 256 + kk * 8;
    *reinterpret_cast<uint4*>(Qfh + qko) = *reinterpret_cast<const uint4*>(qh);
    *reinterpret_cast<uint4*>(Qfl + qko) = *reinterpret_cast<const uint4*>(ql);
    *reinterpret_cast<uint4*>(Kfh + qko) = *reinterpret_cast<const uint4*>(kh);
    // V store: Y=kk>>4, half=(kk>>3)&1, e=kk&7 ; X=og>>2, row=(og&3)*8+j
    {
        int Y = kk >> 4, hf = (kk >> 3) & 1, e = kk & 7;
        size_t vbase = ((size_t)((b * NT + t) * 2 + Y) * 2 + (og >> 2)) * 512
                     + hf * 256 + e;
        #pragma unroll
        for (int j = 0; j < OG; ++j)
            Vf[vbase + ((og & 3) * 8 + j) * 8] = f2bf_rne(av[j]);
    }
}

// ---------------- flash attention pass 1: MFMA + distance-2 LDS pipeline ----------------
// SPLITS=8 -> 1008 blocks ~= one full residency round (4 blocks/CU at ~120 unified regs).
// Split s covers tiles [s*NT/8, (s+1)*NT/8) — 31 or 32 tiles.
__global__ __launch_bounds__(256, 4) void attn_pass1_mfma(
        const unsigned short* __restrict__ Qfh, const unsigned short* __restrict__ Qfl,
        const unsigned short* __restrict__ Kfh,
        const unsigned short* __restrict__ Vf,
        float* __restrict__ pm, float* __restrict__ pl, float* __restrict__ pacc) {
    int bid   = blockIdx.x;
    int split = bid / (BB * QUADS);         // split-major: co-resident share K/V window
    int rem   = bid % (BB * QUADS);
    int b     = rem / QUADS;
    int quad  = rem % QUADS;
    int wave  = threadIdx.x >> 6;
    int lane  = threadIdx.x & 63;
    int col   = lane & 31;
    int half  = lane >> 5;
    int qt    = quad * 4 + wave;
    bool qvalid = qt < NT;
    int qtc   = qvalid ? qt : NT - 1;
    int bNT   = b * NT;

    int tstart = (split * NT) / SPLITS;
    int tend   = ((split + 1) * NT) / SPLITS;
    int nkt    = tend - tstart;             // 31 or 32

    __shared__ __align__(16) char ldsbuf[3][8192];   // [Kh 4K | V 4K] x3

    // Q fragments: contiguous 1KB per c-chunk
    short8 qfh[4], qfl[4];
    {
        const unsigned short* qp  = Qfh + (size_t)(bNT + qtc) * 2048 + lane * 8;
        const unsigned short* qp2 = Qfl + (size_t)(bNT + qtc) * 2048 + lane * 8;
        #pragma unroll
        for (int c = 0; c < 4; ++c) {
            qfh[c] = ld_frag(qp  + c * 512);
            qfl[c] = ld_frag(qp2 + c * 512);
        }
    }

    int wo = wave * 1024;           // this wave's 1KB slice of each 4KB chunk
    int go = wo + lane * 16;        // byte offset into the tile's 4KB chunk

    auto STAGE = [&](int bufi, int tg) {
        size_t tb = (size_t)(bNT + tg) * 2048;     // elements (=4096 B)
        char* l = &ldsbuf[bufi][0];
        gload_lds16((const char*)(Kfh + tb) + go, l + wo);
        gload_lds16((const char*)(Vf  + tb) + go, l + 4096 + wo);
    };

    f32x16 oacc0 = {};
    f32x16 oacc1 = {};
    float m = -3e38f, lsum = 0.f;

    STAGE(0, tstart);                // prologue: stage tiles 0 and 1
    STAGE(1, tstart + 1);

    for (int t = 0; t < nkt; ++t) {
        // wait for stage(t): 2 newer loads (stage(t+1)) may stay in flight
        if (t == nkt - 1) { asm volatile("s_waitcnt vmcnt(0)" ::: "memory"); }
        else              { asm volatile("s_waitcnt vmcnt(2)" ::: "memory"); }
        __builtin_amdgcn_sched_barrier(0);
        __builtin_amdgcn_s_barrier();          // raw: no implicit vmcnt drain
        __builtin_amdgcn_sched_barrier(0);
        if (t + 2 < nkt) STAGE((t + 2) % 3, tstart + t + 2);

        const unsigned short* lk = (const unsigned short*)&ldsbuf[t % 3][0];
        const unsigned short* lv = (const unsigned short*)&ldsbuf[t % 3][4096];

        // QK^T: S^T = Kh.(Qh+Ql)^T — single accumulator chain (reg diet)
        f32x16 s = {};
        __builtin_amdgcn_s_setprio(1);
        #pragma unroll
        for (int c = 0; c < 4; ++c) {
            short8 kfh = ld_frag(lk + c * 512 + lane * 8);
            s = __builtin_amdgcn_mfma_f32_32x32x16_bf16(kfh, qfh[c], s, 0, 0, 0);
            s = __builtin_amdgcn_mfma_f32_32x32x16_bf16(kfh, qfl[c], s, 0, 0, 0);
        }
        __builtin_amdgcn_s_setprio(0);

        // tree max over 16 + cross-half
        float t8[8];
        #pragma unroll
        for (int r = 0; r < 8; ++r) t8[r] = fmaxf(s[r], s[r + 8]);
        float t4a = fmaxf(t8[0], t8[1]), t4b = fmaxf(t8[2], t8[3]);
        float t4c = fmaxf(t8[4], t8[5]), t4d = fmaxf(t8[6], t8[7]);
        float tmax = fmaxf(fmaxf(t4a, t4b), fmaxf(t4c, t4d));
        tmax = fmaxf(tmax, __shfl_xor(tmax, 32, 64));
        // T13 defer-rescale
        if (__any(tmax > m + 8.f)) {
            float newm  = fmaxf(m, tmax);
            float scale = __expf(m - newm);
            lsum *= scale;
            #pragma unroll
            for (int r = 0; r < 16; ++r) { oacc0[r] *= scale; oacc1[r] *= scale; }
            m = newm;
        }
        // P in two groups of 8 (regs) -> bf16 B-fragments via cvt_pk + half-exchange
        short8 pf0, pf1;
        float ls;
        {
            float p[8];
            #pragma unroll
            for (int r = 0; r < 8; ++r) p[r] = __expf(s[r] - m);
            ls = ((p[0] + p[1]) + (p[2] + p[3])) + ((p[4] + p[5]) + (p[6] + p[7]));
            unsigned W[4], X[4];
            #pragma unroll
            for (int j = 0; j < 4; ++j)
                asm("v_cvt_pk_bf16_f32 %0, %1, %2" : "=v"(W[j]) : "v"(p[2 * j]), "v"(p[2 * j + 1]));
            #pragma unroll
            for (int j = 0; j < 4; ++j) X[j] = (unsigned)__shfl_xor((int)W[j], 32, 64);
            uint4 u = half ? make_uint4(X[2], X[3], W[2], W[3])
                           : make_uint4(W[0], W[1], X[0], X[1]);
            pf0 = __builtin_bit_cast(short8, u);
        }
        {
            float p[8];
            #pragma unroll
            for (int r = 0; r < 8; ++r) p[r] = __expf(s[r + 8] - m);
            ls += ((p[0] + p[1]) + (p[2] + p[3])) + ((p[4] + p[5]) + (p[6] + p[7]));
            unsigned W[4], X[4];
            #pragma unroll
            for (int j = 0; j < 4; ++j)
                asm("v_cvt_pk_bf16_f32 %0, %1, %2" : "=v"(W[j]) : "v"(p[2 * j]), "v"(p[2 * j + 1]));
            #pragma unroll
            for (int j = 0; j < 4; ++j) X[j] = (unsigned)__shfl_xor((int)W[j], 32, 64);
            uint4 u = half ? make_uint4(X[2], X[3], W[2], W[3])
                           : make_uint4(W[0], W[1], X[0], X[1]);
            pf1 = __builtin_bit_cast(short8, u);
        }
        lsum += ls;
        // PV: O^T = V^T.P^T  (X -> oacc, Y -> pf)
        {
            short8 v00 = ld_frag(lv + 0 * 512 + lane * 8);   // Y0 X0
            short8 v10 = ld_frag(lv + 1 * 512 + lane * 8);   // Y0 X1
            __builtin_amdgcn_s_setprio(1);
            oacc0 = __builtin_amdgcn_mfma_f32_32x32x16_bf16(v00, pf0, oacc0, 0, 0, 0);
            oacc1 = __builtin_amdgcn_mfma_f32_32x32x16_bf16(v10, pf0, oacc1, 0, 0, 0);
            __builtin_amdgcn_s_setprio(0);
            short8 v01 = ld_frag(lv + 2 * 512 + lane * 8);   // Y1 X0
            short8 v11 = ld_frag(lv + 3 * 512 + lane * 8);   // Y1 X1
            __builtin_amdgcn_s_setprio(1);
            oacc0 = __builtin_amdgcn_mfma_f32_32x32x16_bf16(v01, pf1, oacc0, 0, 0, 0);
            oacc1 = __builtin_amdgcn_mfma_f32_32x32x16_bf16(v11, pf1, oacc1, 0, 0, 0);
            __builtin_amdgcn_s_setprio(0);
        }
    }

    if (!qvalid) return;
    int q0 = qt * 32;
    float lfull = lsum + __shfl_xor(lsum, 32, 64);
    size_t base = (size_t)b * SPLITS + split;
    if (lane < 32) {
        pm[base * NSP + q0 + col] = m;
        pl[base * NSP + q0 + col] = lfull;
    }
    float* pa = pacc + base * (size_t)(COUT * NSP) + q0 + col;
    #pragma unroll
    for (int r = 0; r < 16; ++r) {
        int crow = (r & 3) + 8 * (r >> 2) + 4 * half;
        pa[(size_t)crow * NSP]        = oacc0[r];
        pa[(size_t)(crow + 32) * NSP] = oacc1[r];
    }
}

// ---------------- combine split-K partials ----------------
__global__ void attn_combine_k(const float* __restrict__ pm, const float* __restrict__ pl,
                               const float* __restrict__ pacc, float* __restrict__ out) {
    int idx = blockIdx.x * blockDim.x + threadIdx.x;   // over B*COUT*NSP
    if (idx >= BB * COUT * NSP) return;
    int n = idx % NSP;
    int c = (idx / NSP) % COUT;
    int b = idx / (NSP * COUT);
    float M = -1e30f;
    #pragma unroll
    for (int j = 0; j < SPLITS; ++j)
        M = fmaxf(M, pm[((size_t)b * SPLITS + j) * NSP + n]);
    float L = 0.f, O = 0.f;
    #pragma unroll
    for (int j = 0; j < SPLITS; ++j) {
        size_t base = (size_t)b * SPLITS + j;
        float wgt = __expf(pm[base * NSP + n] - M);
        L += pl[base * NSP + n] * wgt;
        O += pacc[(base * COUT + c) * NSP + n] * wgt;
    }
    out[idx] = O / L;
}

// ---------------- launch ----------------
extern "C" void kernel_launch(void* const* d_in, const int* in_sizes, int n_in,
                              void* d_out, int out_size, void* d_ws, size_t ws_size,
                              hipStream_t stream) {
    const float* x      = (const float*)d_in[0];
    const float* conv_w = (const float*)d_in[1];
    const float* conv_b = (const float*)d_in[2];
    const float* gamma  = (const float*)d_in[3];
    const float* beta   = (const float*)d_in[4];
    const float* wq     = (const float*)d_in[5];
    const float* bq     = (const float*)d_in[6];
    const float* wk     = (const float*)d_in[7];
    const float* bk     = (const float*)d_in[8];
    const float* wv     = (const float*)d_in[9];
    const float* bv     = (const float*)d_in[10];
    float* out = (float*)d_out;

    const int ELEMS = BB * COUT * NSP;      // 1,024,000
    char* w8 = (char*)d_ws;
    float*  y    = (float*)w8;                          // 4,096,000 B
    float2* part = (float2*)(w8 + 4096000);             // 4,096 B
    unsigned short* Qfh = (unsigned short*)(w8 + 4100096);
    unsigned short* Qfl = Qfh + (size_t)ELEMS;          // each 2,048,000 B
    unsigned short* Kfh = Qfl + (size_t)ELEMS;
    unsigned short* Vf  = Kfh + (size_t)ELEMS;
    float* pm   = (float*)(Vf + (size_t)ELEMS);
    float* pl   = pm + (size_t)BB * SPLITS * NSP;       // 512,000 B each
    float* pacc = pl + (size_t)BB * SPLITS * NSP;       // 32,768,000 B
    // xpad aliases pacc: xpad live only before conv3d_k; pacc only after qkv_k
    float* xpad = pacc;                                 // needs 2,725,888 B

    pad_k<<<(BB * CIN * PSP + 255) / 256, 256, 0, stream>>>(x, xpad);
    conv3d_k<<<BB * 16 * 32, 256, 0, stream>>>(xpad, conv_w, conv_b, y);
    instnorm_part_k<<<BB * COUT * 4, 256, 0, stream>>>(y, part);
    qkv_k<<<BB * 8 * 32, 256, 0, stream>>>(y, part, gamma, beta,
                                           wq, bq, wk, bk, wv, bv,
                                           Qfh, Qfl, Kfh, Vf);
    attn_pass1_mfma<<<SPLITS * BB * QUADS, 256, 0, stream>>>(Qfh, Qfl, Kfh, Vf,
                                                             pm, pl, pacc);
    attn_combine_k<<<(ELEMS + 255) / 256, 256, 0, stream>>>(pm, pl, pacc, out);
}

// Round 13
// 146.463 us; speedup vs baseline: 2.0078x; 1.0348x over previous
//
#include <hip/hip_runtime.h>
#include <math.h>

#define CIN   32
#define COUT  64
#define DD    20
#define PD    22        // padded dim
#define PSP   (PD*PD*PD)   // 10648
#define NSP   8000      // 20*20*20
#define BB    2
#define EPSN  1e-5f
#define SLOPE 0.01f
#define LOG2E 1.4426950408889634f

#define NT     250              // 32-row k/q tiles per batch
#define SPLITS 8                // 1008 blocks ~= one residency round
#define QUADS  63               // ceil(250/4) q-tiles, 4 per block

#define COG 4                   // conv: output channels per thread
#define OG  8                   // qkv: output channels per thread

typedef float  f32x16 __attribute__((ext_vector_type(16)));
typedef short  short8 __attribute__((ext_vector_type(8)));

__device__ __forceinline__ unsigned short f2bf_rne(float x) {
    unsigned u = __float_as_uint(x);
    unsigned r = (u + 0x7FFFu + ((u >> 16) & 1u)) >> 16;
    return (unsigned short)r;
}
__device__ __forceinline__ float bf2f(unsigned short h) {
    return __uint_as_float(((unsigned)h) << 16);
}
__device__ __forceinline__ short8 ld_frag(const unsigned short* p) {
    uint4 t = *reinterpret_cast<const uint4*>(p);
    return __builtin_bit_cast(short8, t);
}
// async global->LDS, 16B per lane; LDS dest is wave-uniform base + lane*16
__device__ __forceinline__ void gload_lds16(const void* gsrc, void* ldst) {
    typedef __attribute__((address_space(1))) const unsigned int GU;
    typedef __attribute__((address_space(3))) unsigned int LU;
    __builtin_amdgcn_global_load_lds((GU*)gsrc, (LU*)ldst, 16, 0, 0);
}
// raw 2^x (v_exp_f32); inputs here are <= 0 and well in range
__device__ __forceinline__ float exp2_fast(float x) {
    float r;
    asm("v_exp_f32 %0, %1" : "=v"(r) : "v"(x));
    return r;
}
// full-wave sum via xor-shuffle butterfly (deterministic)
__device__ __forceinline__ float wsum(float x) {
    #pragma unroll
    for (int off = 1; off < 64; off <<= 1) x += __shfl_xor(x, off, 64);
    return x;
}

// ---------------- zero-pad x into [B][CIN][22][22][22] ----------------
__global__ void pad_k(const float* __restrict__ x, float* __restrict__ xp) {
    int idx = blockIdx.x * blockDim.x + threadIdx.x;
    if (idx >= BB * CIN * PSP) return;
    int pw = idx % PD;
    int ph = (idx / PD) % PD;
    int pd = (idx / (PD * PD)) % PD;
    int bc = idx / PSP;
    float v = 0.f;
    if (pw >= 1 && pw <= DD && ph >= 1 && ph <= DD && pd >= 1 && pd <= DD)
        v = x[(size_t)bc * NSP + ((size_t)(pd - 1) * DD + (ph - 1)) * DD + (pw - 1)];
    xp[idx] = v;
}

// ---------------- Conv3d k=3 s=1 SAME + bias + fused instance-norm partials ----------------
// grid: b * 16 co-groups * 32 voxel-blocks ; thread = 1 voxel, COG=4 output channels.
// Epilogue: deterministic per-block (b,c,vb) sum/sumsq partials via wave-shfl reduce.
__global__ __launch_bounds__(256) void conv3d_k(const float* __restrict__ xp,
                                                const float* __restrict__ w,
                                                const float* __restrict__ bias,
                                                float* __restrict__ y,
                                                float2* __restrict__ part) {
    int blk = blockIdx.x;
    int vb  = blk & 31;
    int cg  = (blk >> 5) & 15;      // uniform co-group (of 4)
    int b   = blk >> 9;
    int vox = vb * 256 + threadIdx.x;
    bool valid = vox < NSP;
    int v  = valid ? vox : 0;
    int w_ = v % DD;
    int h_ = (v / DD) % DD;
    int d_ = v / (DD * DD);
    int pvox = ((d_ + 1) * PD + (h_ + 1)) * PD + (w_ + 1);
    const float* xb = xp + (size_t)b * CIN * PSP + pvox;

    float acc[COG];
    #pragma unroll
    for (int j = 0; j < COG; ++j) acc[j] = 0.f;

    for (int ci = 0; ci < CIN; ++ci) {
        const float* xc = xb + (size_t)ci * PSP;
        float xv[27];
        #pragma unroll
        for (int kd = 0; kd < 3; ++kd)
            #pragma unroll
            for (int kh = 0; kh < 3; ++kh)
                #pragma unroll
                for (int kw = 0; kw < 3; ++kw)
                    xv[(kd * 3 + kh) * 3 + kw] =
                        xc[(kd - 1) * (PD * PD) + (kh - 1) * PD + (kw - 1)];
        #pragma unroll
        for (int j = 0; j < COG; ++j) {
            int co = cg * COG + j;                       // uniform
            const float* wr = w + ((size_t)co * CIN + ci) * 27;
            float a = acc[j];
            #pragma unroll
            for (int t = 0; t < 27; ++t) a += xv[t] * wr[t];
            acc[j] = a;
        }
    }

    __shared__ float2 wred[4][COG];
    int wv = threadIdx.x >> 6;
    int ln = threadIdx.x & 63;
    #pragma unroll
    for (int j = 0; j < COG; ++j) {
        int co = cg * COG + j;
        float val = valid ? acc[j] + bias[co] : 0.f;
        if (valid) y[((size_t)b * COUT + co) * NSP + vox] = val;
        float s  = wsum(val);
        float ss = wsum(val * val);
        if (ln == 0) wred[wv][j] = make_float2(s, ss);
    }
    __syncthreads();
    if (threadIdx.x < COG) {
        int j = threadIdx.x;
        float s = 0.f, ss = 0.f;
        #pragma unroll
        for (int w2 = 0; w2 < 4; ++w2) { s += wred[w2][j].x; ss += wred[w2][j].y; }
        part[((size_t)(b * COUT + cg * COG + j)) * 32 + vb] = make_float2(s, ss);
    }
}

// ---------------- QKV projections (stats-finalize + norm + LeakyReLU fused) ----------------
// Q scaled by LOG2E (softmax runs in log2 domain).
// Q (hi,lo), K (hi): [b][tile][c(4)][half(2)][row(32)][e(8)]  (4KB contiguous per tile)
// V:                 [b][tile][Y(2)][X(2)][half(2)][row(32)][e(8)]
__global__ __launch_bounds__(256) void qkv_k(const float* __restrict__ yraw,
                      const float2* __restrict__ part,
                      const float* __restrict__ gamma, const float* __restrict__ beta,
                      const float* __restrict__ wq, const float* __restrict__ bq,
                      const float* __restrict__ wk, const float* __restrict__ bk,
                      const float* __restrict__ wv, const float* __restrict__ bv,
                      unsigned short* __restrict__ Qfh, unsigned short* __restrict__ Qfl,
                      unsigned short* __restrict__ Kfh,
                      unsigned short* __restrict__ Vf) {
    int blk = blockIdx.x;
    int vb  = blk & 31;
    int og  = (blk >> 5) & 7;       // uniform o-group
    int b   = blk >> 8;
    int n   = vb * 256 + threadIdx.x;
    bool valid = n < NSP;
    int nn  = valid ? n : 0;
    const float* fb = yraw + (size_t)b * COUT * NSP + nn;

    // finalize instance-norm stats (deterministic 32-way chunk sum per channel)
    __shared__ float smean[COUT], srstd[COUT];
    if (threadIdx.x < COUT) {
        int c = threadIdx.x;
        float s = 0.f, ss = 0.f;
        #pragma unroll 8
        for (int ch = 0; ch < 32; ++ch) {
            float2 p = part[(size_t)(b * COUT + c) * 32 + ch];
            s += p.x; ss += p.y;
        }
        float mean = s * (1.f / NSP);
        smean[c] = mean;
        srstd[c] = rsqrtf(ss * (1.f / NSP) - mean * mean + EPSN);
    }
    __syncthreads();

    float aq[OG], ak[OG], av[OG];
    #pragma unroll
    for (int j = 0; j < OG; ++j) {
        int o = og * OG + j;
        aq[j] = bq[o]; ak[j] = bk[o]; av[j] = bv[o];
    }
    for (int c = 0; c < COUT; ++c) {
        float fc = (fb[(size_t)c * NSP] - smean[c]) * srstd[c] * gamma[c] + beta[c];
        fc = fc >= 0.f ? fc : SLOPE * fc;            // LeakyReLU fused
        #pragma unroll
        for (int j = 0; j < OG; ++j) {
            int o = og * OG + j;                         // uniform
            aq[j] += wq[o * COUT + c] * fc;
            ak[j] += wk[o * COUT + c] * fc;
            av[j] += wv[o * COUT + c] * fc;
        }
    }
    if (!valid) return;

    int t  = n >> 5;                // tile
    int kk = n & 31;                // row within tile
    unsigned short qh[OG], ql[OG], kh[OG];
    #pragma unroll
    for (int j = 0; j < OG; ++j) {
        float q2 = aq[j] * LOG2E;   // log2-domain logits
        qh[j] = f2bf_rne(q2); ql[j] = f2bf_rne(q2 - bf2f(qh[j]));
        kh[j] = f2bf_rne(ak[j]);
    }
    // Q/K store: c = og>>1, half = og&1
    size_t qko = ((size_t)((b * NT + t) * 4 + (og >> 1)) * 2 + (og & 1)) * 256 + kk * 8;
    *reinterpret_cast<uint4*>(Qfh + qko) = *reinterpret_cast<const uint4*>(qh);
    *reinterpret_cast<uint4*>(Qfl + qko) = *reinterpret_cast<const uint4*>(ql);
    *reinterpret_cast<uint4*>(Kfh + qko) = *reinterpret_cast<const uint4*>(kh);
    // V store: Y=kk>>4, half=(kk>>3)&1, e=kk&7 ; X=og>>2, row=(og&3)*8+j
    {
        int Y = kk >> 4, hf = (kk >> 3) & 1, e = kk & 7;
        size_t vbase = ((size_t)((b * NT + t) * 2 + Y) * 2 + (og >> 2)) * 512
                     + hf * 256 + e;
        #pragma unroll
        for (int j = 0; j < OG; ++j)
            Vf[vbase + ((og & 3) * 8 + j) * 8] = f2bf_rne(av[j]);
    }
}

// ---------------- flash attention pass 1: MFMA + distance-2 LDS pipeline ----------------
// log2-domain softmax: p = 2^(s-m) via raw v_exp_f32 (no log2e muls in the loop).
__global__ __launch_bounds__(256, 4) void attn_pass1_mfma(
        const unsigned short* __restrict__ Qfh, const unsigned short* __restrict__ Qfl,
        const unsigned short* __restrict__ Kfh,
        const unsigned short* __restrict__ Vf,
        float* __restrict__ pm, float* __restrict__ pl, float* __restrict__ pacc) {
    int bid   = blockIdx.x;
    int split = bid / (BB * QUADS);         // split-major: co-resident share K/V window
    int rem   = bid % (BB * QUADS);
    int b     = rem / QUADS;
    int quad  = rem % QUADS;
    int wave  = threadIdx.x >> 6;
    int lane  = threadIdx.x & 63;
    int col   = lane & 31;
    int half  = lane >> 5;
    int qt    = quad * 4 + wave;
    bool qvalid = qt < NT;
    int qtc   = qvalid ? qt : NT - 1;
    int bNT   = b * NT;

    int tstart = (split * NT) / SPLITS;
    int tend   = ((split + 1) * NT) / SPLITS;
    int nkt    = tend - tstart;             // 31 or 32

    __shared__ __align__(16) char ldsbuf[3][8192];   // [Kh 4K | V 4K] x3

    // Q fragments: contiguous 1KB per c-chunk
    short8 qfh[4], qfl[4];
    {
        const unsigned short* qp  = Qfh + (size_t)(bNT + qtc) * 2048 + lane * 8;
        const unsigned short* qp2 = Qfl + (size_t)(bNT + qtc) * 2048 + lane * 8;
        #pragma unroll
        for (int c = 0; c < 4; ++c) {
            qfh[c] = ld_frag(qp  + c * 512);
            qfl[c] = ld_frag(qp2 + c * 512);
        }
    }

    int wo = wave * 1024;           // this wave's 1KB slice of each 4KB chunk
    int go = wo + lane * 16;        // byte offset into the tile's 4KB chunk

    auto STAGE = [&](int bufi, int tg) {
        size_t tb = (size_t)(bNT + tg) * 2048;     // elements (=4096 B)
        char* l = &ldsbuf[bufi][0];
        gload_lds16((const char*)(Kfh + tb) + go, l + wo);
        gload_lds16((const char*)(Vf  + tb) + go, l + 4096 + wo);
    };

    f32x16 oacc0 = {};
    f32x16 oacc1 = {};
    float m = -3e38f, lsum = 0.f;

    STAGE(0, tstart);                // prologue: stage tiles 0 and 1
    STAGE(1, tstart + 1);

    for (int t = 0; t < nkt; ++t) {
        // wait for stage(t): 2 newer loads (stage(t+1)) may stay in flight
        if (t == nkt - 1) { asm volatile("s_waitcnt vmcnt(0)" ::: "memory"); }
        else              { asm volatile("s_waitcnt vmcnt(2)" ::: "memory"); }
        __builtin_amdgcn_sched_barrier(0);
        __builtin_amdgcn_s_barrier();          // raw: no implicit vmcnt drain
        __builtin_amdgcn_sched_barrier(0);
        if (t + 2 < nkt) STAGE((t + 2) % 3, tstart + t + 2);

        const unsigned short* lk = (const unsigned short*)&ldsbuf[t % 3][0];
        const unsigned short* lv = (const unsigned short*)&ldsbuf[t % 3][4096];

        // QK^T: S^T = Kh.(Qh+Ql)^T — single accumulator chain
        f32x16 s = {};
        __builtin_amdgcn_s_setprio(1);
        #pragma unroll
        for (int c = 0; c < 4; ++c) {
            short8 kfh = ld_frag(lk + c * 512 + lane * 8);
            s = __builtin_amdgcn_mfma_f32_32x32x16_bf16(kfh, qfh[c], s, 0, 0, 0);
            s = __builtin_amdgcn_mfma_f32_32x32x16_bf16(kfh, qfl[c], s, 0, 0, 0);
        }
        __builtin_amdgcn_s_setprio(0);

        // max in triples (v_max3) + cross-half
        float a0 = fmaxf(fmaxf(s[0],  s[1]),  s[2]);
        float a1 = fmaxf(fmaxf(s[3],  s[4]),  s[5]);
        float a2 = fmaxf(fmaxf(s[6],  s[7]),  s[8]);
        float a3 = fmaxf(fmaxf(s[9],  s[10]), s[11]);
        float a4 = fmaxf(fmaxf(s[12], s[13]), s[14]);
        float tmax = fmaxf(fmaxf(fmaxf(a0, a1), a2), fmaxf(fmaxf(a3, a4), s[15]));
        tmax = fmaxf(tmax, __shfl_xor(tmax, 32, 64));
        // T13 defer-rescale (log2 units: e^8 ~= 2^11.5)
        if (__any(tmax > m + 11.5f)) {
            float newm  = fmaxf(m, tmax);
            float scale = exp2_fast(m - newm);
            lsum *= scale;
            #pragma unroll
            for (int r = 0; r < 16; ++r) { oacc0[r] *= scale; oacc1[r] *= scale; }
            m = newm;
        }
        // P in two groups of 8 (regs) -> bf16 B-fragments via cvt_pk + half-exchange
        short8 pf0, pf1;
        float ls;
        {
            float p[8];
            #pragma unroll
            for (int r = 0; r < 8; ++r) p[r] = exp2_fast(s[r] - m);
            ls = ((p[0] + p[1]) + (p[2] + p[3])) + ((p[4] + p[5]) + (p[6] + p[7]));
            unsigned W[4], X[4];
            #pragma unroll
            for (int j = 0; j < 4; ++j)
                asm("v_cvt_pk_bf16_f32 %0, %1, %2" : "=v"(W[j]) : "v"(p[2 * j]), "v"(p[2 * j + 1]));
            #pragma unroll
            for (int j = 0; j < 4; ++j) X[j] = (unsigned)__shfl_xor((int)W[j], 32, 64);
            uint4 u = half ? make_uint4(X[2], X[3], W[2], W[3])
                           : make_uint4(W[0], W[1], X[0], X[1]);
            pf0 = __builtin_bit_cast(short8, u);
        }
        {
            float p[8];
            #pragma unroll
            for (int r = 0; r < 8; ++r) p[r] = exp2_fast(s[r + 8] - m);
            ls += ((p[0] + p[1]) + (p[2] + p[3])) + ((p[4] + p[5]) + (p[6] + p[7]));
            unsigned W[4], X[4];
            #pragma unroll
            for (int j = 0; j < 4; ++j)
                asm("v_cvt_pk_bf16_f32 %0, %1, %2" : "=v"(W[j]) : "v"(p[2 * j]), "v"(p[2 * j + 1]));
            #pragma unroll
            for (int j = 0; j < 4; ++j) X[j] = (unsigned)__shfl_xor((int)W[j], 32, 64);
            uint4 u = half ? make_uint4(X[2], X[3], W[2], W[3])
                           : make_uint4(W[0], W[1], X[0], X[1]);
            pf1 = __builtin_bit_cast(short8, u);
        }
        lsum += ls;
        // PV: O^T = V^T.P^T  (X -> oacc, Y -> pf)
        {
            short8 v00 = ld_frag(lv + 0 * 512 + lane * 8);   // Y0 X0
            short8 v10 = ld_frag(lv + 1 * 512 + lane * 8);   // Y0 X1
            __builtin_amdgcn_s_setprio(1);
            oacc0 = __builtin_amdgcn_mfma_f32_32x32x16_bf16(v00, pf0, oacc0, 0, 0, 0);
            oacc1 = __builtin_amdgcn_mfma_f32_32x32x16_bf16(v10, pf0, oacc1, 0, 0, 0);
            __builtin_amdgcn_s_setprio(0);
            short8 v01 = ld_frag(lv + 2 * 512 + lane * 8);   // Y1 X0
            short8 v11 = ld_frag(lv + 3 * 512 + lane * 8);   // Y1 X1
            __builtin_amdgcn_s_setprio(1);
            oacc0 = __builtin_amdgcn_mfma_f32_32x32x16_bf16(v01, pf1, oacc0, 0, 0, 0);
            oacc1 = __builtin_amdgcn_mfma_f32_32x32x16_bf16(v11, pf1, oacc1, 0, 0, 0);
            __builtin_amdgcn_s_setprio(0);
        }
    }

    if (!qvalid) return;
    int q0 = qt * 32;
    float lfull = lsum + __shfl_xor(lsum, 32, 64);
    size_t base = (size_t)b * SPLITS + split;
    if (lane < 32) {
        pm[base * NSP + q0 + col] = m;     // log2-domain running max
        pl[base * NSP + q0 + col] = lfull;
    }
    float* pa = pacc + base * (size_t)(COUT * NSP) + q0 + col;
    #pragma unroll
    for (int r = 0; r < 16; ++r) {
        int crow = (r & 3) + 8 * (r >> 2) + 4 * half;
        pa[(size_t)crow * NSP]        = oacc0[r];
        pa[(size_t)(crow + 32) * NSP] = oacc1[r];
    }
}

// ---------------- combine split-K partials (log2-domain weights) ----------------
__global__ void attn_combine_k(const float* __restrict__ pm, const float* __restrict__ pl,
                               const float* __restrict__ pacc, float* __restrict__ out) {
    int idx = blockIdx.x * blockDim.x + threadIdx.x;   // over B*COUT*NSP
    if (idx >= BB * COUT * NSP) return;
    int n = idx % NSP;
    int c = (idx / NSP) % COUT;
    int b = idx / (NSP * COUT);
    float M = -1e30f;
    #pragma unroll
    for (int j = 0; j < SPLITS; ++j)
        M = fmaxf(M, pm[((size_t)b * SPLITS + j) * NSP + n]);
    float L = 0.f, O = 0.f;
    #pragma unroll
    for (int j = 0; j < SPLITS; ++j) {
        size_t base = (size_t)b * SPLITS + j;
        float d = pm[base * NSP + n] - M;
        float wgt;
        asm("v_exp_f32 %0, %1" : "=v"(wgt) : "v"(d));  // 2^d
        L += pl[base * NSP + n] * wgt;
        O += pacc[(base * COUT + c) * NSP + n] * wgt;
    }
    out[idx] = O / L;
}

// ---------------- launch ----------------
extern "C" void kernel_launch(void* const* d_in, const int* in_sizes, int n_in,
                              void* d_out, int out_size, void* d_ws, size_t ws_size,
                              hipStream_t stream) {
    const float* x      = (const float*)d_in[0];
    const float* conv_w = (const float*)d_in[1];
    const float* conv_b = (const float*)d_in[2];
    const float* gamma  = (const float*)d_in[3];
    const float* beta   = (const float*)d_in[4];
    const float* wq     = (const float*)d_in[5];
    const float* bq     = (const float*)d_in[6];
    const float* wk     = (const float*)d_in[7];
    const float* bk     = (const float*)d_in[8];
    const float* wv     = (const float*)d_in[9];
    const float* bv     = (const float*)d_in[10];
    float* out = (float*)d_out;

    const int ELEMS = BB * COUT * NSP;      // 1,024,000
    char* w8 = (char*)d_ws;
    float*  y    = (float*)w8;                          // 4,096,000 B
    float2* part = (float2*)(w8 + 4096000);             // 128*32 float2 = 32,768 B
    unsigned short* Qfh = (unsigned short*)(w8 + 4128768);
    unsigned short* Qfl = Qfh + (size_t)ELEMS;          // each 2,048,000 B
    unsigned short* Kfh = Qfl + (size_t)ELEMS;
    unsigned short* Vf  = Kfh + (size_t)ELEMS;
    float* pm   = (float*)(Vf + (size_t)ELEMS);
    float* pl   = pm + (size_t)BB * SPLITS * NSP;       // 512,000 B each
    float* pacc = pl + (size_t)BB * SPLITS * NSP;       // 32,768,000 B
    // xpad aliases pacc: xpad live only before conv3d_k; pacc only after qkv_k
    float* xpad = pacc;                                 // needs 2,725,888 B

    pad_k<<<(BB * CIN * PSP + 255) / 256, 256, 0, stream>>>(x, xpad);
    conv3d_k<<<BB * 16 * 32, 256, 0, stream>>>(xpad, conv_w, conv_b, y, part);
    qkv_k<<<BB * 8 * 32, 256, 0, stream>>>(y, part, gamma, beta,
                                           wq, bq, wk, bk, wv, bv,
                                           Qfh, Qfl, Kfh, Vf);
    attn_pass1_mfma<<<SPLITS * BB * QUADS, 256, 0, stream>>>(Qfh, Qfl, Kfh, Vf,
                                                             pm, pl, pacc);
    attn_combine_k<<<(ELEMS + 255) / 256, 256, 0, stream>>>(pm, pl, pacc, out);
}

// Round 14
// 134.625 us; speedup vs baseline: 2.1844x; 1.0879x over previous
//
#include <hip/hip_runtime.h>
#include <math.h>

#define CIN   32
#define COUT  64
#define DD    20
#define PD    22        // padded dim
#define PSP   (PD*PD*PD)   // 10648
#define NSP   8000      // 20*20*20
#define BB    2
#define EPSN  1e-5f
#define SLOPE 0.01f
#define LOG2E 1.4426950408889634f

#define NT     250              // 32-row k/q tiles per batch
#define SPLITS 8                // 1008 blocks ~= one residency round
#define QUADS  63               // ceil(250/4) q-tiles, 4 per block

#define COG 4                   // conv: output channels per thread
#define OG  8                   // qkv: output channels per thread

typedef float  f32x16 __attribute__((ext_vector_type(16)));
typedef short  short8 __attribute__((ext_vector_type(8)));

__device__ __forceinline__ unsigned short f2bf_rne(float x) {
    unsigned u = __float_as_uint(x);
    unsigned r = (u + 0x7FFFu + ((u >> 16) & 1u)) >> 16;
    return (unsigned short)r;
}
__device__ __forceinline__ float bf2f(unsigned short h) {
    return __uint_as_float(((unsigned)h) << 16);
}
__device__ __forceinline__ short8 ld_frag(const unsigned short* p) {
    uint4 t = *reinterpret_cast<const uint4*>(p);
    return __builtin_bit_cast(short8, t);
}
// async global->LDS, 16B per lane; LDS dest is wave-uniform base + lane*16
__device__ __forceinline__ void gload_lds16(const void* gsrc, void* ldst) {
    typedef __attribute__((address_space(1))) const unsigned int GU;
    typedef __attribute__((address_space(3))) unsigned int LU;
    __builtin_amdgcn_global_load_lds((GU*)gsrc, (LU*)ldst, 16, 0, 0);
}
// raw 2^x (v_exp_f32); inputs here are <= 0 and well in range
__device__ __forceinline__ float exp2_fast(float x) {
    float r;
    asm("v_exp_f32 %0, %1" : "=v"(r) : "v"(x));
    return r;
}
// full-wave sum via xor-shuffle butterfly (deterministic)
__device__ __forceinline__ float wsum(float x) {
    #pragma unroll
    for (int off = 1; off < 64; off <<= 1) x += __shfl_xor(x, off, 64);
    return x;
}

// ---------------- zero-pad x into [B][CIN][22][22][22] ----------------
__global__ void pad_k(const float* __restrict__ x, float* __restrict__ xp) {
    int idx = blockIdx.x * blockDim.x + threadIdx.x;
    if (idx >= BB * CIN * PSP) return;
    int pw = idx % PD;
    int ph = (idx / PD) % PD;
    int pd = (idx / (PD * PD)) % PD;
    int bc = idx / PSP;
    float v = 0.f;
    if (pw >= 1 && pw <= DD && ph >= 1 && ph <= DD && pd >= 1 && pd <= DD)
        v = x[(size_t)bc * NSP + ((size_t)(pd - 1) * DD + (ph - 1)) * DD + (pw - 1)];
    xp[idx] = v;
}

// ---------------- Conv3d k=3 s=1 SAME + bias + fused instance-norm partials ----------------
__global__ __launch_bounds__(256) void conv3d_k(const float* __restrict__ xp,
                                                const float* __restrict__ w,
                                                const float* __restrict__ bias,
                                                float* __restrict__ y,
                                                float2* __restrict__ part) {
    int blk = blockIdx.x;
    int vb  = blk & 31;
    int cg  = (blk >> 5) & 15;      // uniform co-group (of 4)
    int b   = blk >> 9;
    int vox = vb * 256 + threadIdx.x;
    bool valid = vox < NSP;
    int v  = valid ? vox : 0;
    int w_ = v % DD;
    int h_ = (v / DD) % DD;
    int d_ = v / (DD * DD);
    int pvox = ((d_ + 1) * PD + (h_ + 1)) * PD + (w_ + 1);
    const float* xb = xp + (size_t)b * CIN * PSP + pvox;

    float acc[COG];
    #pragma unroll
    for (int j = 0; j < COG; ++j) acc[j] = 0.f;

    for (int ci = 0; ci < CIN; ++ci) {
        const float* xc = xb + (size_t)ci * PSP;
        float xv[27];
        #pragma unroll
        for (int kd = 0; kd < 3; ++kd)
            #pragma unroll
            for (int kh = 0; kh < 3; ++kh)
                #pragma unroll
                for (int kw = 0; kw < 3; ++kw)
                    xv[(kd * 3 + kh) * 3 + kw] =
                        xc[(kd - 1) * (PD * PD) + (kh - 1) * PD + (kw - 1)];
        #pragma unroll
        for (int j = 0; j < COG; ++j) {
            int co = cg * COG + j;                       // uniform
            const float* wr = w + ((size_t)co * CIN + ci) * 27;
            float a = acc[j];
            #pragma unroll
            for (int t = 0; t < 27; ++t) a += xv[t] * wr[t];
            acc[j] = a;
        }
    }

    __shared__ float2 wred[4][COG];
    int wv = threadIdx.x >> 6;
    int ln = threadIdx.x & 63;
    #pragma unroll
    for (int j = 0; j < COG; ++j) {
        int co = cg * COG + j;
        float val = valid ? acc[j] + bias[co] : 0.f;
        if (valid) y[((size_t)b * COUT + co) * NSP + vox] = val;
        float s  = wsum(val);
        float ss = wsum(val * val);
        if (ln == 0) wred[wv][j] = make_float2(s, ss);
    }
    __syncthreads();
    if (threadIdx.x < COG) {
        int j = threadIdx.x;
        float s = 0.f, ss = 0.f;
        #pragma unroll
        for (int w2 = 0; w2 < 4; ++w2) { s += wred[w2][j].x; ss += wred[w2][j].y; }
        part[((size_t)(b * COUT + cg * COG + j)) * 32 + vb] = make_float2(s, ss);
    }
}

// ---------------- QKV projections (stats-finalize + norm + LeakyReLU fused) ----------------
// Q (single bf16, scaled by LOG2E), K (hi): [b][tile][c(4)][half(2)][row(32)][e(8)]
// V: [b][tile][Y(2)][X(2)][half(2)][row(32)][e(8)]
__global__ __launch_bounds__(256) void qkv_k(const float* __restrict__ yraw,
                      const float2* __restrict__ part,
                      const float* __restrict__ gamma, const float* __restrict__ beta,
                      const float* __restrict__ wq, const float* __restrict__ bq,
                      const float* __restrict__ wk, const float* __restrict__ bk,
                      const float* __restrict__ wv, const float* __restrict__ bv,
                      unsigned short* __restrict__ Qfh,
                      unsigned short* __restrict__ Kfh,
                      unsigned short* __restrict__ Vf) {
    int blk = blockIdx.x;
    int vb  = blk & 31;
    int og  = (blk >> 5) & 7;       // uniform o-group
    int b   = blk >> 8;
    int n   = vb * 256 + threadIdx.x;
    bool valid = n < NSP;
    int nn  = valid ? n : 0;
    const float* fb = yraw + (size_t)b * COUT * NSP + nn;

    // finalize instance-norm stats (deterministic 32-way chunk sum per channel)
    __shared__ float smean[COUT], srstd[COUT];
    if (threadIdx.x < COUT) {
        int c = threadIdx.x;
        float s = 0.f, ss = 0.f;
        #pragma unroll 8
        for (int ch = 0; ch < 32; ++ch) {
            float2 p = part[(size_t)(b * COUT + c) * 32 + ch];
            s += p.x; ss += p.y;
        }
        float mean = s * (1.f / NSP);
        smean[c] = mean;
        srstd[c] = rsqrtf(ss * (1.f / NSP) - mean * mean + EPSN);
    }
    __syncthreads();

    float aq[OG], ak[OG], av[OG];
    #pragma unroll
    for (int j = 0; j < OG; ++j) {
        int o = og * OG + j;
        aq[j] = bq[o]; ak[j] = bk[o]; av[j] = bv[o];
    }
    for (int c = 0; c < COUT; ++c) {
        float fc = (fb[(size_t)c * NSP] - smean[c]) * srstd[c] * gamma[c] + beta[c];
        fc = fc >= 0.f ? fc : SLOPE * fc;            // LeakyReLU fused
        #pragma unroll
        for (int j = 0; j < OG; ++j) {
            int o = og * OG + j;                         // uniform
            aq[j] += wq[o * COUT + c] * fc;
            ak[j] += wk[o * COUT + c] * fc;
            av[j] += wv[o * COUT + c] * fc;
        }
    }
    if (!valid) return;

    int t  = n >> 5;                // tile
    int kk = n & 31;                // row within tile
    unsigned short qh[OG], kh[OG];
    #pragma unroll
    for (int j = 0; j < OG; ++j) {
        qh[j] = f2bf_rne(aq[j] * LOG2E);   // log2-domain logits, single bf16
        kh[j] = f2bf_rne(ak[j]);
    }
    // Q/K store: c = og>>1, half = og&1
    size_t qko = ((size_t)((b * NT + t) * 4 + (og >> 1)) * 2 + (og & 1)) * 256 + kk * 8;
    *reinterpret_cast<uint4*>(Qfh + qko) = *reinterpret_cast<const uint4*>(qh);
    *reinterpret_cast<uint4*>(Kfh + qko) = *reinterpret_cast<const uint4*>(kh);
    // V store: Y=kk>>4, half=(kk>>3)&1, e=kk&7 ; X=og>>2, row=(og&3)*8+j
    {
        int Y = kk >> 4, hf = (kk >> 3) & 1, e = kk & 7;
        size_t vbase = ((size_t)((b * NT + t) * 2 + Y) * 2 + (og >> 2)) * 512
                     + hf * 256 + e;
        #pragma unroll
        for (int j = 0; j < OG; ++j)
            Vf[vbase + ((og & 3) * 8 + j) * 8] = f2bf_rne(av[j]);
    }
}

// ---------------- flash attention pass 1: MFMA + distance-2 LDS pipeline ----------------
// Single-bf16 QK (4 MFMAs/tile); reg diet targets the 4-waves/SIMD cliff.
__global__ __launch_bounds__(256, 4) void attn_pass1_mfma(
        const unsigned short* __restrict__ Qfh,
        const unsigned short* __restrict__ Kfh,
        const unsigned short* __restrict__ Vf,
        float* __restrict__ pm, float* __restrict__ pl, float* __restrict__ pacc) {
    int bid   = blockIdx.x;
    int split = bid / (BB * QUADS);         // split-major: co-resident share K/V window
    int rem   = bid % (BB * QUADS);
    int b     = rem / QUADS;
    int quad  = rem % QUADS;
    int wave  = threadIdx.x >> 6;
    int lane  = threadIdx.x & 63;
    int col   = lane & 31;
    int half  = lane >> 5;
    int qt    = quad * 4 + wave;
    bool qvalid = qt < NT;
    int qtc   = qvalid ? qt : NT - 1;
    int bNT   = b * NT;

    int tstart = (split * NT) / SPLITS;
    int tend   = ((split + 1) * NT) / SPLITS;
    int nkt    = tend - tstart;             // 31 or 32

    __shared__ __align__(16) char ldsbuf[3][8192];   // [Kh 4K | V 4K] x3

    // Q fragments: contiguous 1KB per c-chunk
    short8 qfh[4];
    {
        const unsigned short* qp = Qfh + (size_t)(bNT + qtc) * 2048 + lane * 8;
        #pragma unroll
        for (int c = 0; c < 4; ++c) qfh[c] = ld_frag(qp + c * 512);
    }

    int wo = wave * 1024;           // this wave's 1KB slice of each 4KB chunk
    int go = wo + lane * 16;        // byte offset into the tile's 4KB chunk

    auto STAGE = [&](int bufi, int tg) {
        size_t tb = (size_t)(bNT + tg) * 2048;     // elements (=4096 B)
        char* l = &ldsbuf[bufi][0];
        gload_lds16((const char*)(Kfh + tb) + go, l + wo);
        gload_lds16((const char*)(Vf  + tb) + go, l + 4096 + wo);
    };

    f32x16 oacc0 = {};
    f32x16 oacc1 = {};
    float m = -3e38f, lsum = 0.f;

    STAGE(0, tstart);                // prologue: stage tiles 0 and 1
    STAGE(1, tstart + 1);

    for (int t = 0; t < nkt; ++t) {
        // wait for stage(t): 2 newer loads (stage(t+1)) may stay in flight
        if (t == nkt - 1) { asm volatile("s_waitcnt vmcnt(0)" ::: "memory"); }
        else              { asm volatile("s_waitcnt vmcnt(2)" ::: "memory"); }
        __builtin_amdgcn_sched_barrier(0);
        __builtin_amdgcn_s_barrier();          // raw: no implicit vmcnt drain
        __builtin_amdgcn_sched_barrier(0);
        if (t + 2 < nkt) STAGE((t + 2) % 3, tstart + t + 2);

        const unsigned short* lk = (const unsigned short*)&ldsbuf[t % 3][0];
        const unsigned short* lv = (const unsigned short*)&ldsbuf[t % 3][4096];

        // QK^T: S^T = Kh.Qh^T — 4 MFMAs
        f32x16 s = {};
        __builtin_amdgcn_s_setprio(1);
        #pragma unroll
        for (int c = 0; c < 4; ++c) {
            short8 kfh = ld_frag(lk + c * 512 + lane * 8);
            s = __builtin_amdgcn_mfma_f32_32x32x16_bf16(kfh, qfh[c], s, 0, 0, 0);
        }
        __builtin_amdgcn_s_setprio(0);

        // max in triples (v_max3) + cross-half
        float a0 = fmaxf(fmaxf(s[0],  s[1]),  s[2]);
        float a1 = fmaxf(fmaxf(s[3],  s[4]),  s[5]);
        float a2 = fmaxf(fmaxf(s[6],  s[7]),  s[8]);
        float a3 = fmaxf(fmaxf(s[9],  s[10]), s[11]);
        float a4 = fmaxf(fmaxf(s[12], s[13]), s[14]);
        float tmax = fmaxf(fmaxf(fmaxf(a0, a1), a2), fmaxf(fmaxf(a3, a4), s[15]));
        tmax = fmaxf(tmax, __shfl_xor(tmax, 32, 64));
        // T13 defer-rescale (log2 units: e^8 ~= 2^11.5)
        if (__any(tmax > m + 11.5f)) {
            float newm  = fmaxf(m, tmax);
            float scale = exp2_fast(m - newm);
            lsum *= scale;
            #pragma unroll
            for (int r = 0; r < 16; ++r) { oacc0[r] *= scale; oacc1[r] *= scale; }
            m = newm;
        }
        // P in two groups of 8 (regs) -> bf16 B-fragments via cvt_pk + half-exchange
        short8 pf0, pf1;
        float ls;
        {
            float p[8];
            #pragma unroll
            for (int r = 0; r < 8; ++r) p[r] = exp2_fast(s[r] - m);
            ls = ((p[0] + p[1]) + (p[2] + p[3])) + ((p[4] + p[5]) + (p[6] + p[7]));
            unsigned W[4], X[4];
            #pragma unroll
            for (int j = 0; j < 4; ++j)
                asm("v_cvt_pk_bf16_f32 %0, %1, %2" : "=v"(W[j]) : "v"(p[2 * j]), "v"(p[2 * j + 1]));
            #pragma unroll
            for (int j = 0; j < 4; ++j) X[j] = (unsigned)__shfl_xor((int)W[j], 32, 64);
            uint4 u = half ? make_uint4(X[2], X[3], W[2], W[3])
                           : make_uint4(W[0], W[1], X[0], X[1]);
            pf0 = __builtin_bit_cast(short8, u);
        }
        {
            float p[8];
            #pragma unroll
            for (int r = 0; r < 8; ++r) p[r] = exp2_fast(s[r + 8] - m);
            ls += ((p[0] + p[1]) + (p[2] + p[3])) + ((p[4] + p[5]) + (p[6] + p[7]));
            unsigned W[4], X[4];
            #pragma unroll
            for (int j = 0; j < 4; ++j)
                asm("v_cvt_pk_bf16_f32 %0, %1, %2" : "=v"(W[j]) : "v"(p[2 * j]), "v"(p[2 * j + 1]));
            #pragma unroll
            for (int j = 0; j < 4; ++j) X[j] = (unsigned)__shfl_xor((int)W[j], 32, 64);
            uint4 u = half ? make_uint4(X[2], X[3], W[2], W[3])
                           : make_uint4(W[0], W[1], X[0], X[1]);
            pf1 = __builtin_bit_cast(short8, u);
        }
        lsum += ls;
        // PV: O^T = V^T.P^T  (X -> oacc, Y -> pf)
        {
            short8 v00 = ld_frag(lv + 0 * 512 + lane * 8);   // Y0 X0
            short8 v10 = ld_frag(lv + 1 * 512 + lane * 8);   // Y0 X1
            __builtin_amdgcn_s_setprio(1);
            oacc0 = __builtin_amdgcn_mfma_f32_32x32x16_bf16(v00, pf0, oacc0, 0, 0, 0);
            oacc1 = __builtin_amdgcn_mfma_f32_32x32x16_bf16(v10, pf0, oacc1, 0, 0, 0);
            __builtin_amdgcn_s_setprio(0);
            short8 v01 = ld_frag(lv + 2 * 512 + lane * 8);   // Y1 X0
            short8 v11 = ld_frag(lv + 3 * 512 + lane * 8);   // Y1 X1
            __builtin_amdgcn_s_setprio(1);
            oacc0 = __builtin_amdgcn_mfma_f32_32x32x16_bf16(v01, pf1, oacc0, 0, 0, 0);
            oacc1 = __builtin_amdgcn_mfma_f32_32x32x16_bf16(v11, pf1, oacc1, 0, 0, 0);
            __builtin_amdgcn_s_setprio(0);
        }
    }

    if (!qvalid) return;
    int q0 = qt * 32;
    float lfull = lsum + __shfl_xor(lsum, 32, 64);
    size_t base = (size_t)b * SPLITS + split;
    if (lane < 32) {
        pm[base * NSP + q0 + col] = m;     // log2-domain running max
        pl[base * NSP + q0 + col] = lfull;
    }
    float* pa = pacc + base * (size_t)(COUT * NSP) + q0 + col;
    #pragma unroll
    for (int r = 0; r < 16; ++r) {
        int crow = (r & 3) + 8 * (r >> 2) + 4 * half;
        pa[(size_t)crow * NSP]        = oacc0[r];
        pa[(size_t)(crow + 32) * NSP] = oacc1[r];
    }
}

// ---------------- combine split-K partials (log2-domain, float4-vectorized) ----------------
__global__ void attn_combine_k(const float* __restrict__ pm, const float* __restrict__ pl,
                               const float* __restrict__ pacc, float* __restrict__ out) {
    int idx = blockIdx.x * blockDim.x + threadIdx.x;   // over B*COUT*NSP/4
    const int N4 = NSP / 4;
    if (idx >= BB * COUT * N4) return;
    int n4 = idx % N4;
    int c  = (idx / N4) % COUT;
    int b  = idx / (N4 * COUT);
    int n  = n4 * 4;

    float4 M = make_float4(-1e30f, -1e30f, -1e30f, -1e30f);
    #pragma unroll
    for (int j = 0; j < SPLITS; ++j) {
        float4 v = *reinterpret_cast<const float4*>(&pm[((size_t)b * SPLITS + j) * NSP + n]);
        M.x = fmaxf(M.x, v.x); M.y = fmaxf(M.y, v.y);
        M.z = fmaxf(M.z, v.z); M.w = fmaxf(M.w, v.w);
    }
    float4 L = make_float4(0.f, 0.f, 0.f, 0.f);
    float4 O = make_float4(0.f, 0.f, 0.f, 0.f);
    #pragma unroll
    for (int j = 0; j < SPLITS; ++j) {
        size_t base = (size_t)b * SPLITS + j;
        float4 pmv = *reinterpret_cast<const float4*>(&pm[base * NSP + n]);
        float4 plv = *reinterpret_cast<const float4*>(&pl[base * NSP + n]);
        float4 pav = *reinterpret_cast<const float4*>(&pacc[(base * COUT + c) * NSP + n]);
        float4 wgt;
        wgt.x = exp2_fast(pmv.x - M.x); wgt.y = exp2_fast(pmv.y - M.y);
        wgt.z = exp2_fast(pmv.z - M.z); wgt.w = exp2_fast(pmv.w - M.w);
        L.x += plv.x * wgt.x; L.y += plv.y * wgt.y;
        L.z += plv.z * wgt.z; L.w += plv.w * wgt.w;
        O.x += pav.x * wgt.x; O.y += pav.y * wgt.y;
        O.z += pav.z * wgt.z; O.w += pav.w * wgt.w;
    }
    float4 r;
    r.x = O.x / L.x; r.y = O.y / L.y; r.z = O.z / L.z; r.w = O.w / L.w;
    *reinterpret_cast<float4*>(&out[((size_t)(b * COUT + c)) * NSP + n]) = r;
}

// ---------------- launch ----------------
extern "C" void kernel_launch(void* const* d_in, const int* in_sizes, int n_in,
                              void* d_out, int out_size, void* d_ws, size_t ws_size,
                              hipStream_t stream) {
    const float* x      = (const float*)d_in[0];
    const float* conv_w = (const float*)d_in[1];
    const float* conv_b = (const float*)d_in[2];
    const float* gamma  = (const float*)d_in[3];
    const float* beta   = (const float*)d_in[4];
    const float* wq     = (const float*)d_in[5];
    const float* bq     = (const float*)d_in[6];
    const float* wk     = (const float*)d_in[7];
    const float* bk     = (const float*)d_in[8];
    const float* wv     = (const float*)d_in[9];
    const float* bv     = (const float*)d_in[10];
    float* out = (float*)d_out;

    const int ELEMS = BB * COUT * NSP;      // 1,024,000
    char* w8 = (char*)d_ws;
    float*  y    = (float*)w8;                          // 4,096,000 B
    float2* part = (float2*)(w8 + 4096000);             // 128*32 float2 = 32,768 B
    unsigned short* Qfh = (unsigned short*)(w8 + 4128768);
    unsigned short* Kfh = Qfh + (size_t)ELEMS;          // each 2,048,000 B
    unsigned short* Vf  = Kfh + (size_t)ELEMS;
    float* pm   = (float*)(Vf + (size_t)ELEMS);
    float* pl   = pm + (size_t)BB * SPLITS * NSP;       // 512,000 B each
    float* pacc = pl + (size_t)BB * SPLITS * NSP;       // 32,768,000 B
    // xpad aliases pacc: xpad live only before conv3d_k; pacc only after qkv_k
    float* xpad = pacc;                                 // needs 2,725,888 B

    pad_k<<<(BB * CIN * PSP + 255) / 256, 256, 0, stream>>>(x, xpad);
    conv3d_k<<<BB * 16 * 32, 256, 0, stream>>>(xpad, conv_w, conv_b, y, part);
    qkv_k<<<BB * 8 * 32, 256, 0, stream>>>(y, part, gamma, beta,
                                           wq, bq, wk, bk, wv, bv,
                                           Qfh, Kfh, Vf);
    attn_pass1_mfma<<<SPLITS * BB * QUADS, 256, 0, stream>>>(Qfh, Kfh, Vf,
                                                             pm, pl, pacc);
    attn_combine_k<<<(BB * COUT * (NSP / 4) + 255) / 256, 256, 0, stream>>>(pm, pl, pacc, out);
}

// Round 15
// 133.129 us; speedup vs baseline: 2.2089x; 1.0112x over previous
//
#include <hip/hip_runtime.h>
#include <math.h>

#define CIN   32
#define COUT  64
#define DD    20
#define PD    22        // padded dim
#define PSP   (PD*PD*PD)   // 10648
#define NSP   8000      // 20*20*20
#define BB    2
#define EPSN  1e-5f
#define SLOPE 0.01f
#define LOG2E 1.4426950408889634f

#define NT     250              // 32-row k/q tiles per batch
#define SPLITS 8                // 1008 blocks ~= one residency round
#define QUADS  63               // ceil(250/4) q-tiles, 4 per block

#define COG 4                   // conv: output channels per thread
#define OG  8                   // qkv: output channels per thread

typedef float  f32x16 __attribute__((ext_vector_type(16)));
typedef short  short8 __attribute__((ext_vector_type(8)));

__device__ __forceinline__ unsigned short f2bf_rne(float x) {
    unsigned u = __float_as_uint(x);
    unsigned r = (u + 0x7FFFu + ((u >> 16) & 1u)) >> 16;
    return (unsigned short)r;
}
__device__ __forceinline__ float bf2f(unsigned short h) {
    return __uint_as_float(((unsigned)h) << 16);
}
__device__ __forceinline__ short8 ld_frag(const unsigned short* p) {
    uint4 t = *reinterpret_cast<const uint4*>(p);
    return __builtin_bit_cast(short8, t);
}
// async global->LDS, 16B per lane; LDS dest is wave-uniform base + lane*16
__device__ __forceinline__ void gload_lds16(const void* gsrc, void* ldst) {
    typedef __attribute__((address_space(1))) const unsigned int GU;
    typedef __attribute__((address_space(3))) unsigned int LU;
    __builtin_amdgcn_global_load_lds((GU*)gsrc, (LU*)ldst, 16, 0, 0);
}
// raw 2^x (v_exp_f32); inputs here are <= 0 and well in range
__device__ __forceinline__ float exp2_fast(float x) {
    float r;
    asm("v_exp_f32 %0, %1" : "=v"(r) : "v"(x));
    return r;
}
// full-wave sum via xor-shuffle butterfly (deterministic)
__device__ __forceinline__ float wsum(float x) {
    #pragma unroll
    for (int off = 1; off < 64; off <<= 1) x += __shfl_xor(x, off, 64);
    return x;
}

// ---------------- zero-pad x into [B][CIN][22][22][22] ----------------
__global__ void pad_k(const float* __restrict__ x, float* __restrict__ xp) {
    int idx = blockIdx.x * blockDim.x + threadIdx.x;
    if (idx >= BB * CIN * PSP) return;
    int pw = idx % PD;
    int ph = (idx / PD) % PD;
    int pd = (idx / (PD * PD)) % PD;
    int bc = idx / PSP;
    float v = 0.f;
    if (pw >= 1 && pw <= DD && ph >= 1 && ph <= DD && pd >= 1 && pd <= DD)
        v = x[(size_t)bc * NSP + ((size_t)(pd - 1) * DD + (ph - 1)) * DD + (pw - 1)];
    xp[idx] = v;
}

// ---------------- Conv3d k=3 s=1 SAME + bias + fused instance-norm partials ----------------
__global__ __launch_bounds__(256) void conv3d_k(const float* __restrict__ xp,
                                                const float* __restrict__ w,
                                                const float* __restrict__ bias,
                                                float* __restrict__ y,
                                                float2* __restrict__ part) {
    int blk = blockIdx.x;
    int vb  = blk & 31;
    int cg  = (blk >> 5) & 15;      // uniform co-group (of 4)
    int b   = blk >> 9;
    int vox = vb * 256 + threadIdx.x;
    bool valid = vox < NSP;
    int v  = valid ? vox : 0;
    int w_ = v % DD;
    int h_ = (v / DD) % DD;
    int d_ = v / (DD * DD);
    int pvox = ((d_ + 1) * PD + (h_ + 1)) * PD + (w_ + 1);
    const float* xb = xp + (size_t)b * CIN * PSP + pvox;

    float acc[COG];
    #pragma unroll
    for (int j = 0; j < COG; ++j) acc[j] = 0.f;

    for (int ci = 0; ci < CIN; ++ci) {
        const float* xc = xb + (size_t)ci * PSP;
        float xv[27];
        #pragma unroll
        for (int kd = 0; kd < 3; ++kd)
            #pragma unroll
            for (int kh = 0; kh < 3; ++kh)
                #pragma unroll
                for (int kw = 0; kw < 3; ++kw)
                    xv[(kd * 3 + kh) * 3 + kw] =
                        xc[(kd - 1) * (PD * PD) + (kh - 1) * PD + (kw - 1)];
        #pragma unroll
        for (int j = 0; j < COG; ++j) {
            int co = cg * COG + j;                       // uniform
            const float* wr = w + ((size_t)co * CIN + ci) * 27;
            float a = acc[j];
            #pragma unroll
            for (int t = 0; t < 27; ++t) a += xv[t] * wr[t];
            acc[j] = a;
        }
    }

    __shared__ float2 wred[4][COG];
    int wv = threadIdx.x >> 6;
    int ln = threadIdx.x & 63;
    #pragma unroll
    for (int j = 0; j < COG; ++j) {
        int co = cg * COG + j;
        float val = valid ? acc[j] + bias[co] : 0.f;
        if (valid) y[((size_t)b * COUT + co) * NSP + vox] = val;
        float s  = wsum(val);
        float ss = wsum(val * val);
        if (ln == 0) wred[wv][j] = make_float2(s, ss);
    }
    __syncthreads();
    if (threadIdx.x < COG) {
        int j = threadIdx.x;
        float s = 0.f, ss = 0.f;
        #pragma unroll
        for (int w2 = 0; w2 < 4; ++w2) { s += wred[w2][j].x; ss += wred[w2][j].y; }
        part[((size_t)(b * COUT + cg * COG + j)) * 32 + vb] = make_float2(s, ss);
    }
}

// ---------------- QKV projections (stats-finalize + norm + LeakyReLU fused) ----------------
// Q (single bf16, scaled by LOG2E), K (hi): [b][tile][c(4)][half(2)][row(32)][e(8)]
// V: [b][tile][Y(2)][X(2)][half(2)][row(32)][e(8)]
__global__ __launch_bounds__(256) void qkv_k(const float* __restrict__ yraw,
                      const float2* __restrict__ part,
                      const float* __restrict__ gamma, const float* __restrict__ beta,
                      const float* __restrict__ wq, const float* __restrict__ bq,
                      const float* __restrict__ wk, const float* __restrict__ bk,
                      const float* __restrict__ wv, const float* __restrict__ bv,
                      unsigned short* __restrict__ Qfh,
                      unsigned short* __restrict__ Kfh,
                      unsigned short* __restrict__ Vf) {
    int blk = blockIdx.x;
    int vb  = blk & 31;
    int og  = (blk >> 5) & 7;       // uniform o-group
    int b   = blk >> 8;
    int n   = vb * 256 + threadIdx.x;
    bool valid = n < NSP;
    int nn  = valid ? n : 0;
    const float* fb = yraw + (size_t)b * COUT * NSP + nn;

    // finalize instance-norm stats (deterministic 32-way chunk sum per channel)
    __shared__ float smean[COUT], srstd[COUT];
    if (threadIdx.x < COUT) {
        int c = threadIdx.x;
        float s = 0.f, ss = 0.f;
        #pragma unroll 8
        for (int ch = 0; ch < 32; ++ch) {
            float2 p = part[(size_t)(b * COUT + c) * 32 + ch];
            s += p.x; ss += p.y;
        }
        float mean = s * (1.f / NSP);
        smean[c] = mean;
        srstd[c] = rsqrtf(ss * (1.f / NSP) - mean * mean + EPSN);
    }
    __syncthreads();

    float aq[OG], ak[OG], av[OG];
    #pragma unroll
    for (int j = 0; j < OG; ++j) {
        int o = og * OG + j;
        aq[j] = bq[o]; ak[j] = bk[o]; av[j] = bv[o];
    }
    for (int c = 0; c < COUT; ++c) {
        float fc = (fb[(size_t)c * NSP] - smean[c]) * srstd[c] * gamma[c] + beta[c];
        fc = fc >= 0.f ? fc : SLOPE * fc;            // LeakyReLU fused
        #pragma unroll
        for (int j = 0; j < OG; ++j) {
            int o = og * OG + j;                         // uniform
            aq[j] += wq[o * COUT + c] * fc;
            ak[j] += wk[o * COUT + c] * fc;
            av[j] += wv[o * COUT + c] * fc;
        }
    }
    if (!valid) return;

    int t  = n >> 5;                // tile
    int kk = n & 31;                // row within tile
    unsigned short qh[OG], kh[OG];
    #pragma unroll
    for (int j = 0; j < OG; ++j) {
        qh[j] = f2bf_rne(aq[j] * LOG2E);   // log2-domain logits, single bf16
        kh[j] = f2bf_rne(ak[j]);
    }
    // Q/K store: c = og>>1, half = og&1
    size_t qko = ((size_t)((b * NT + t) * 4 + (og >> 1)) * 2 + (og & 1)) * 256 + kk * 8;
    *reinterpret_cast<uint4*>(Qfh + qko) = *reinterpret_cast<const uint4*>(qh);
    *reinterpret_cast<uint4*>(Kfh + qko) = *reinterpret_cast<const uint4*>(kh);
    // V store: Y=kk>>4, half=(kk>>3)&1, e=kk&7 ; X=og>>2, row=(og&3)*8+j
    {
        int Y = kk >> 4, hf = (kk >> 3) & 1, e = kk & 7;
        size_t vbase = ((size_t)((b * NT + t) * 2 + Y) * 2 + (og >> 2)) * 512
                     + hf * 256 + e;
        #pragma unroll
        for (int j = 0; j < OG; ++j)
            Vf[vbase + ((og & 3) * 8 + j) * 8] = f2bf_rne(av[j]);
    }
}

// ---------------- flash attention pass 1: MFMA, pair-ILP (2 k-tiles per barrier) ----------------
// Phase order QK0,QK1 -> SM0 -> PV0 -> SM1 -> PV1: QK1/PV0 MFMAs overlap SM0/SM1 VALU.
// 2 LDS pair-buffers (16KB each), distance-1; pair-compute (~1300cyc) hides stage latency.
__global__ __launch_bounds__(256, 4) void attn_pass1_mfma(
        const unsigned short* __restrict__ Qfh,
        const unsigned short* __restrict__ Kfh,
        const unsigned short* __restrict__ Vf,
        float* __restrict__ pm, float* __restrict__ pl, float* __restrict__ pacc) {
    int bid   = blockIdx.x;
    int split = bid / (BB * QUADS);         // split-major: co-resident share K/V window
    int rem   = bid % (BB * QUADS);
    int b     = rem / QUADS;
    int quad  = rem % QUADS;
    int wave  = threadIdx.x >> 6;
    int lane  = threadIdx.x & 63;
    int col   = lane & 31;
    int half  = lane >> 5;
    int qt    = quad * 4 + wave;
    bool qvalid = qt < NT;
    int qtc   = qvalid ? qt : NT - 1;
    int bNT   = b * NT;

    int tstart = (split * NT) / SPLITS;
    int tend   = ((split + 1) * NT) / SPLITS;
    int nkt    = tend - tstart;             // 31 or 32
    int npair  = nkt >> 1;
    int odd    = nkt & 1;

    __shared__ __align__(16) char ldsbuf[2][16384];  // pair: [Kh0 4K|V0 4K|Kh1 4K|V1 4K]

    // Q fragments: contiguous 1KB per c-chunk
    short8 qfh[4];
    {
        const unsigned short* qp = Qfh + (size_t)(bNT + qtc) * 2048 + lane * 8;
        #pragma unroll
        for (int c = 0; c < 4; ++c) qfh[c] = ld_frag(qp + c * 512);
    }

    int wo = wave * 1024;           // this wave's 1KB slice of each 4KB chunk
    int go = wo + lane * 16;        // byte offset into the tile's 4KB chunk

    // stage one tile (Kh 4KB + V 4KB) into slot (0/1) of pair buffer bufi
    auto STAGET = [&](int bufi, int slot, int tg) {
        size_t tb = (size_t)(bNT + tg) * 2048;     // elements (=4096 B)
        char* l = &ldsbuf[bufi][slot * 8192];
        gload_lds16((const char*)(Kfh + tb) + go, l + wo);
        gload_lds16((const char*)(Vf  + tb) + go, l + 4096 + wo);
    };

    f32x16 oacc0 = {};
    f32x16 oacc1 = {};
    float m = -3e38f, lsum = 0.f;

    // softmax + PV for one tile's scores s against its V (lv)
    auto SM_PV = [&](const f32x16& s, const unsigned short* lv) {
        float a0 = fmaxf(fmaxf(s[0],  s[1]),  s[2]);
        float a1 = fmaxf(fmaxf(s[3],  s[4]),  s[5]);
        float a2 = fmaxf(fmaxf(s[6],  s[7]),  s[8]);
        float a3 = fmaxf(fmaxf(s[9],  s[10]), s[11]);
        float a4 = fmaxf(fmaxf(s[12], s[13]), s[14]);
        float tmax = fmaxf(fmaxf(fmaxf(a0, a1), a2), fmaxf(fmaxf(a3, a4), s[15]));
        tmax = fmaxf(tmax, __shfl_xor(tmax, 32, 64));
        // T13 defer-rescale (log2 units: e^8 ~= 2^11.5)
        if (__any(tmax > m + 11.5f)) {
            float newm  = fmaxf(m, tmax);
            float scale = exp2_fast(m - newm);
            lsum *= scale;
            #pragma unroll
            for (int r = 0; r < 16; ++r) { oacc0[r] *= scale; oacc1[r] *= scale; }
            m = newm;
        }
        short8 pf0, pf1;
        float ls;
        {
            float p[8];
            #pragma unroll
            for (int r = 0; r < 8; ++r) p[r] = exp2_fast(s[r] - m);
            ls = ((p[0] + p[1]) + (p[2] + p[3])) + ((p[4] + p[5]) + (p[6] + p[7]));
            unsigned W[4], X[4];
            #pragma unroll
            for (int j = 0; j < 4; ++j)
                asm("v_cvt_pk_bf16_f32 %0, %1, %2" : "=v"(W[j]) : "v"(p[2 * j]), "v"(p[2 * j + 1]));
            #pragma unroll
            for (int j = 0; j < 4; ++j) X[j] = (unsigned)__shfl_xor((int)W[j], 32, 64);
            uint4 u = half ? make_uint4(X[2], X[3], W[2], W[3])
                           : make_uint4(W[0], W[1], X[0], X[1]);
            pf0 = __builtin_bit_cast(short8, u);
        }
        {
            float p[8];
            #pragma unroll
            for (int r = 0; r < 8; ++r) p[r] = exp2_fast(s[r + 8] - m);
            ls += ((p[0] + p[1]) + (p[2] + p[3])) + ((p[4] + p[5]) + (p[6] + p[7]));
            unsigned W[4], X[4];
            #pragma unroll
            for (int j = 0; j < 4; ++j)
                asm("v_cvt_pk_bf16_f32 %0, %1, %2" : "=v"(W[j]) : "v"(p[2 * j]), "v"(p[2 * j + 1]));
            #pragma unroll
            for (int j = 0; j < 4; ++j) X[j] = (unsigned)__shfl_xor((int)W[j], 32, 64);
            uint4 u = half ? make_uint4(X[2], X[3], W[2], W[3])
                           : make_uint4(W[0], W[1], X[0], X[1]);
            pf1 = __builtin_bit_cast(short8, u);
        }
        lsum += ls;
        short8 v00 = ld_frag(lv + 0 * 512 + lane * 8);   // Y0 X0
        short8 v10 = ld_frag(lv + 1 * 512 + lane * 8);   // Y0 X1
        __builtin_amdgcn_s_setprio(1);
        oacc0 = __builtin_amdgcn_mfma_f32_32x32x16_bf16(v00, pf0, oacc0, 0, 0, 0);
        oacc1 = __builtin_amdgcn_mfma_f32_32x32x16_bf16(v10, pf0, oacc1, 0, 0, 0);
        __builtin_amdgcn_s_setprio(0);
        short8 v01 = ld_frag(lv + 2 * 512 + lane * 8);   // Y1 X0
        short8 v11 = ld_frag(lv + 3 * 512 + lane * 8);   // Y1 X1
        __builtin_amdgcn_s_setprio(1);
        oacc0 = __builtin_amdgcn_mfma_f32_32x32x16_bf16(v01, pf1, oacc0, 0, 0, 0);
        oacc1 = __builtin_amdgcn_mfma_f32_32x32x16_bf16(v11, pf1, oacc1, 0, 0, 0);
        __builtin_amdgcn_s_setprio(0);
    };

    STAGET(0, 0, tstart);
    STAGET(0, 1, tstart + 1);

    for (int p = 0; p < npair; ++p) {
        __syncthreads();             // drains own pair's stage; prev buffer now free
        int nb = (p + 1) & 1;
        if (p + 1 < npair) {
            STAGET(nb, 0, tstart + 2 * p + 2);
            STAGET(nb, 1, tstart + 2 * p + 3);
        } else if (odd) {
            STAGET(nb, 0, tstart + 2 * p + 2);
        }
        const unsigned short* base = (const unsigned short*)&ldsbuf[p & 1][0];
        const unsigned short* lk0 = base;
        const unsigned short* lv0 = base + 2048;
        const unsigned short* lk1 = base + 4096;
        const unsigned short* lv1 = base + 6144;

        // QK for both tiles first: independent chains, feeds MFMA pipe through SM0
        f32x16 s0 = {}, s1 = {};
        __builtin_amdgcn_s_setprio(1);
        #pragma unroll
        for (int c = 0; c < 4; ++c) {
            short8 k0 = ld_frag(lk0 + c * 512 + lane * 8);
            s0 = __builtin_amdgcn_mfma_f32_32x32x16_bf16(k0, qfh[c], s0, 0, 0, 0);
        }
        #pragma unroll
        for (int c = 0; c < 4; ++c) {
            short8 k1 = ld_frag(lk1 + c * 512 + lane * 8);
            s1 = __builtin_amdgcn_mfma_f32_32x32x16_bf16(k1, qfh[c], s1, 0, 0, 0);
        }
        __builtin_amdgcn_s_setprio(0);

        SM_PV(s0, lv0);              // SM0 VALU overlaps tail of QK1; PV0 overlaps SM1
        SM_PV(s1, lv1);
    }
    if (odd) {
        __syncthreads();
        const unsigned short* base = (const unsigned short*)&ldsbuf[npair & 1][0];
        f32x16 s0 = {};
        __builtin_amdgcn_s_setprio(1);
        #pragma unroll
        for (int c = 0; c < 4; ++c) {
            short8 k0 = ld_frag(base + c * 512 + lane * 8);
            s0 = __builtin_amdgcn_mfma_f32_32x32x16_bf16(k0, qfh[c], s0, 0, 0, 0);
        }
        __builtin_amdgcn_s_setprio(0);
        SM_PV(s0, base + 2048);
    }

    if (!qvalid) return;
    int q0 = qt * 32;
    float lfull = lsum + __shfl_xor(lsum, 32, 64);
    size_t base = (size_t)b * SPLITS + split;
    if (lane < 32) {
        pm[base * NSP + q0 + col] = m;     // log2-domain running max
        pl[base * NSP + q0 + col] = lfull;
    }
    float* pa = pacc + base * (size_t)(COUT * NSP) + q0 + col;
    #pragma unroll
    for (int r = 0; r < 16; ++r) {
        int crow = (r & 3) + 8 * (r >> 2) + 4 * half;
        pa[(size_t)crow * NSP]        = oacc0[r];
        pa[(size_t)(crow + 32) * NSP] = oacc1[r];
    }
}

// ---------------- combine split-K partials (log2-domain, float4-vectorized) ----------------
__global__ void attn_combine_k(const float* __restrict__ pm, const float* __restrict__ pl,
                               const float* __restrict__ pacc, float* __restrict__ out) {
    int idx = blockIdx.x * blockDim.x + threadIdx.x;   // over B*COUT*NSP/4
    const int N4 = NSP / 4;
    if (idx >= BB * COUT * N4) return;
    int n4 = idx % N4;
    int c  = (idx / N4) % COUT;
    int b  = idx / (N4 * COUT);
    int n  = n4 * 4;

    float4 M = make_float4(-1e30f, -1e30f, -1e30f, -1e30f);
    #pragma unroll
    for (int j = 0; j < SPLITS; ++j) {
        float4 v = *reinterpret_cast<const float4*>(&pm[((size_t)b * SPLITS + j) * NSP + n]);
        M.x = fmaxf(M.x, v.x); M.y = fmaxf(M.y, v.y);
        M.z = fmaxf(M.z, v.z); M.w = fmaxf(M.w, v.w);
    }
    float4 L = make_float4(0.f, 0.f, 0.f, 0.f);
    float4 O = make_float4(0.f, 0.f, 0.f, 0.f);
    #pragma unroll
    for (int j = 0; j < SPLITS; ++j) {
        size_t base = (size_t)b * SPLITS + j;
        float4 pmv = *reinterpret_cast<const float4*>(&pm[base * NSP + n]);
        float4 plv = *reinterpret_cast<const float4*>(&pl[base * NSP + n]);
        float4 pav = *reinterpret_cast<const float4*>(&pacc[(base * COUT + c) * NSP + n]);
        float4 wgt;
        wgt.x = exp2_fast(pmv.x - M.x); wgt.y = exp2_fast(pmv.y - M.y);
        wgt.z = exp2_fast(pmv.z - M.z); wgt.w = exp2_fast(pmv.w - M.w);
        L.x += plv.x * wgt.x; L.y += plv.y * wgt.y;
        L.z += plv.z * wgt.z; L.w += plv.w * wgt.w;
        O.x += pav.x * wgt.x; O.y += pav.y * wgt.y;
        O.z += pav.z * wgt.z; O.w += pav.w * wgt.w;
    }
    float4 r;
    r.x = O.x / L.x; r.y = O.y / L.y; r.z = O.z / L.z; r.w = O.w / L.w;
    *reinterpret_cast<float4*>(&out[((size_t)(b * COUT + c)) * NSP + n]) = r;
}

// ---------------- launch ----------------
extern "C" void kernel_launch(void* const* d_in, const int* in_sizes, int n_in,
                              void* d_out, int out_size, void* d_ws, size_t ws_size,
                              hipStream_t stream) {
    const float* x      = (const float*)d_in[0];
    const float* conv_w = (const float*)d_in[1];
    const float* conv_b = (const float*)d_in[2];
    const float* gamma  = (const float*)d_in[3];
    const float* beta   = (const float*)d_in[4];
    const float* wq     = (const float*)d_in[5];
    const float* bq     = (const float*)d_in[6];
    const float* wk     = (const float*)d_in[7];
    const float* bk     = (const float*)d_in[8];
    const float* wv     = (const float*)d_in[9];
    const float* bv     = (const float*)d_in[10];
    float* out = (float*)d_out;

    const int ELEMS = BB * COUT * NSP;      // 1,024,000
    char* w8 = (char*)d_ws;
    float*  y    = (float*)w8;                          // 4,096,000 B
    float2* part = (float2*)(w8 + 4096000);             // 128*32 float2 = 32,768 B
    unsigned short* Qfh = (unsigned short*)(w8 + 4128768);
    unsigned short* Kfh = Qfh + (size_t)ELEMS;          // each 2,048,000 B
    unsigned short* Vf  = Kfh + (size_t)ELEMS;
    float* pm   = (float*)(Vf + (size_t)ELEMS);
    float* pl   = pm + (size_t)BB * SPLITS * NSP;       // 512,000 B each
    float* pacc = pl + (size_t)BB * SPLITS * NSP;       // 32,768,000 B
    // xpad aliases pacc: xpad live only before conv3d_k; pacc only after qkv_k
    float* xpad = pacc;                                 // needs 2,725,888 B

    pad_k<<<(BB * CIN * PSP + 255) / 256, 256, 0, stream>>>(x, xpad);
    conv3d_k<<<BB * 16 * 32, 256, 0, stream>>>(xpad, conv_w, conv_b, y, part);
    qkv_k<<<BB * 8 * 32, 256, 0, stream>>>(y, part, gamma, beta,
                                           wq, bq, wk, bk, wv, bv,
                                           Qfh, Kfh, Vf);
    attn_pass1_mfma<<<SPLITS * BB * QUADS, 256, 0, stream>>>(Qfh, Kfh, Vf,
                                                             pm, pl, pacc);
    attn_combine_k<<<(BB * COUT * (NSP / 4) + 255) / 256, 256, 0, stream>>>(pm, pl, pacc, out);
}